// Round 1
// baseline (521.586 us; speedup 1.0000x reference)
//
#include <hip/hip_runtime.h>
#include <math.h>

// Problem constants (from reference setup_inputs)
#define B_    2
#define N_    5000
#define C_    128
#define E_    65536
#define T_    4
#define TWO_N 10000

// edge types: (src_node_type, dst_node_type) = (0,0),(1,1),(0,1),(1,0)
// s_t = et & 1 ; d_t = ((et+1)>>1) & 1
// node-type nt receives from edge types: nt=0 -> {0,3}, nt=1 -> {1,2}  (et0=nt, et1=3-nt)

constexpr int GROWS = 20;  // 5000 % 20 == 0 -> no tail blocks

// ---------------------------------------------------------------------------
// Generic register-tile GEMM core: C[M,128] = A[M,K] @ W[K,128] (+bias)(+act)
// A addresses are wave-uniform -> compiler emits scalar (s_load) broadcasts;
// W loads are fully coalesced (thread c owns output column c).
// act: 0=none, 1=tanh(relu(x)), 2=tanh(x)
// ---------------------------------------------------------------------------
template <int K, int ROWS>
__device__ __forceinline__ void gemm_core(const float* __restrict__ A,
                                          const float* __restrict__ W,
                                          const float* __restrict__ bias,
                                          float* __restrict__ Cout,
                                          float* __restrict__ colsum,
                                          int row0, int act)
{
    const int c = threadIdx.x;  // 0..127
    float acc[ROWS];
#pragma unroll
    for (int r = 0; r < ROWS; ++r) acc[r] = 0.f;
    const float* Ab = A + (size_t)row0 * K;
#pragma unroll 4
    for (int k = 0; k < K; ++k) {
        float w = W[k * C_ + c];
#pragma unroll
        for (int r = 0; r < ROWS; ++r)
            acc[r] = fmaf(Ab[(size_t)r * K + k], w, acc[r]);
    }
    float bv = bias ? bias[c] : 0.f;
    float csum = 0.f;
#pragma unroll
    for (int r = 0; r < ROWS; ++r) {
        float v = acc[r] + bv;
        if (act == 1) v = (v > 0.f) ? tanhf(v) : 0.f;
        else if (act == 2) v = tanhf(v);
        if (Cout) Cout[(size_t)(row0 + r) * C_ + c] = v;
        csum += v;
    }
    if (colsum) atomicAdd(&colsum[c], csum);
}

// xn[b][nt] = x[b, nt*N:(nt+1)*N] @ proj_w[nt] + proj_b[nt]
__global__ __launch_bounds__(128) void proj_kernel(const float* __restrict__ x,
                                                   const float* __restrict__ proj_w,
                                                   const float* __restrict__ proj_b,
                                                   float* __restrict__ xn)
{
    int row0 = blockIdx.x * GROWS;
    int nt = blockIdx.y, b = blockIdx.z;
    const float* A = x + ((size_t)b * TWO_N + (size_t)nt * N_) * C_;
    gemm_core<128, GROWS>(A, proj_w + (size_t)nt * C_ * C_, proj_b + nt * C_,
                          xn + (size_t)(b * 2 + nt) * N_ * C_, nullptr, row0, 0);
}

// v1[et] = eproj_w[et] @ We_block ; bias_i[et] = att_b[et] + eproj_b[et] @ We_block
__global__ void prep_kernel(const float* __restrict__ eproj_w,
                            const float* __restrict__ eproj_b,
                            const float* __restrict__ att_w,
                            const float* __restrict__ att_b,
                            float* __restrict__ v1, float* __restrict__ bias_i)
{
    int et = blockIdx.x, c = threadIdx.x;
    float s1 = 0.f, s0 = 0.f;
    for (int k = 0; k < 128; ++k) {
        float wv = att_w[(size_t)et * 384 * C_ + (size_t)(256 + k) * C_ + c];
        s1 = fmaf(eproj_w[et * C_ + k], wv, s1);
        s0 = fmaf(eproj_b[et * C_ + k], wv, s0);
    }
    v1[et * C_ + c] = s1;
    bias_i[et * C_ + c] = att_b[et * C_ + c] + s0;
}

// Yj[b][et] = xn[b][s_t] @ att_w[et][0:128] ; Yi[b][et] = xn[b][d_t] @ att_w[et][128:256] + bias_i[et]
__global__ __launch_bounds__(128) void yji_kernel(const float* __restrict__ xn,
                                                  const float* __restrict__ att_w,
                                                  const float* __restrict__ bias_i,
                                                  float* __restrict__ Yj,
                                                  float* __restrict__ Yi)
{
    int row0 = blockIdx.x * GROWS;
    int et = blockIdx.y >> 1, role = blockIdx.y & 1, b = blockIdx.z;
    int s_t = et & 1, d_t = ((et + 1) >> 1) & 1;
    size_t seg = (size_t)(b * T_ + et) * N_ * C_;
    if (role == 0) {
        const float* A = xn + (size_t)(b * 2 + s_t) * N_ * C_;
        gemm_core<128, GROWS>(A, att_w + (size_t)et * 384 * C_, nullptr,
                              Yj + seg, nullptr, row0, 0);
    } else {
        const float* A = xn + (size_t)(b * 2 + d_t) * N_ * C_;
        gemm_core<128, GROWS>(A, att_w + (size_t)et * 384 * C_ + (size_t)128 * C_,
                              bias_i + et * C_, Yi + seg, nullptr, row0, 0);
    }
}

// asrc[b][et][n] = dot(xn[b][s_t][n], lin_src[et]) ; adst analogous
__global__ void nodedot_kernel(const float* __restrict__ xn,
                               const float* __restrict__ lin_src,
                               const float* __restrict__ lin_dst,
                               float* __restrict__ asrc, float* __restrict__ adst)
{
    int n = blockIdx.x * blockDim.x + threadIdx.x;
    if (n >= N_) return;
    int et = blockIdx.y >> 1, role = blockIdx.y & 1, b = blockIdx.z;
    int s_t = et & 1, d_t = ((et + 1) >> 1) & 1;
    int ntsel = role ? d_t : s_t;
    const float* lin = (role ? lin_dst : lin_src) + et * C_;
    const float* row = xn + ((size_t)(b * 2 + ntsel) * N_ + n) * C_;
    float s = 0.f;
#pragma unroll 4
    for (int i = 0; i < C_; ++i) s = fmaf(row[i], lin[i], s);
    float* dstp = role ? adst : asrc;
    dstp[(size_t)(b * T_ + et) * N_ + n] = s;
}

__global__ void count_kernel(const int* __restrict__ eidx, int* __restrict__ count)
{
    int e = blockIdx.x * blockDim.x + threadIdx.x;
    int et = blockIdx.y, b = blockIdx.z;
    int dst = eidx[(((size_t)et * B_ + b) * 2 + 1) * E_ + e];
    atomicAdd(&count[(size_t)(b * T_ + et) * N_ + dst], 1);
}

__global__ __launch_bounds__(256) void scan_kernel(const int* __restrict__ count,
                                                   int* __restrict__ offs)
{
    int be = blockIdx.x;  // 0..7 = b*T+et
    const int* cnt = count + (size_t)be * N_;
    int* off = offs + (size_t)be * (N_ + 1);
    __shared__ int sums[256];
    int tid = threadIdx.x;
    const int chunk = (N_ + 255) / 256;  // 20
    int lo = tid * chunk, hi = min(lo + chunk, N_);
    int s = 0;
    for (int i = lo; i < hi; ++i) s += cnt[i];
    sums[tid] = s;
    __syncthreads();
    for (int d = 1; d < 256; d <<= 1) {
        int v = (tid >= d) ? sums[tid - d] : 0;
        __syncthreads();
        sums[tid] += v;
        __syncthreads();
    }
    int run = (tid > 0) ? sums[tid - 1] : 0;
    for (int i = lo; i < hi; ++i) { off[i] = run; run += cnt[i]; }
    if (tid == 255) off[N_] = sums[255];
}

__global__ void scatter_kernel(const int* __restrict__ eidx, const float* __restrict__ ew,
                               const int* __restrict__ offs, int* __restrict__ cursor,
                               int* __restrict__ ssrc, float* __restrict__ sew)
{
    int e = blockIdx.x * blockDim.x + threadIdx.x;
    int et = blockIdx.y, b = blockIdx.z;
    size_t ebase = ((size_t)et * B_ + b) * 2 * E_;
    int src = eidx[ebase + e];
    int dst = eidx[ebase + E_ + e];
    int be = b * T_ + et;
    int pos = offs[(size_t)be * (N_ + 1) + dst] + atomicAdd(&cursor[(size_t)be * N_ + dst], 1);
    ssrc[(size_t)be * E_ + pos] = src;
    sew[(size_t)be * E_ + pos] = ew[((size_t)et * B_ + b) * E_ + e];
}

// One block per (dst node, et, b): segment softmax + weighted aggregation.
// aggrcat[b][et][n] = [ aggr (128) | xn[d_t][n] (128) ]
__global__ __launch_bounds__(128) void aggregate_kernel(
    const float* __restrict__ xn, const float* __restrict__ Yj,
    const float* __restrict__ Yi, const float* __restrict__ asrc,
    const float* __restrict__ adst, const float* __restrict__ v1,
    const int* __restrict__ offs, const int* __restrict__ ssrc,
    const float* __restrict__ sew, float* __restrict__ aggrcat)
{
    int n = blockIdx.x, et = blockIdx.y, b = blockIdx.z;
    int s_t = et & 1, d_t = ((et + 1) >> 1) & 1;
    int be = b * T_ + et;
    int tid = threadIdx.x;
    const float* xs = xn + (size_t)(b * 2 + s_t) * N_ * C_;
    const float* xd = xn + (size_t)(b * 2 + d_t) * N_ * C_;
    const float* Yjp = Yj + (size_t)be * N_ * C_;
    const float* Yip = Yi + (size_t)be * N_ * C_;
    const float* asp = asrc + (size_t)be * N_;
    float adn = adst[(size_t)be * N_ + n];
    int beg = offs[(size_t)be * (N_ + 1) + n];
    int end = offs[(size_t)be * (N_ + 1) + n + 1];
    int deg = end - beg;
    const int* sp = ssrc + (size_t)be * E_ + beg;
    const float* wp = sew + (size_t)be * E_ + beg;

    // phase 1: segment max of leaky_relu(asrc[src]+adst[n])
    __shared__ float red[128];
    float lmax = -1e30f;
    for (int i = tid; i < deg; i += 128) {
        float al = asp[sp[i]] + adn;
        al = (al > 0.f) ? al : 0.2f * al;
        lmax = fmaxf(lmax, al);
    }
    red[tid] = lmax;
    __syncthreads();
    for (int sft = 64; sft > 0; sft >>= 1) {
        if (tid < sft) red[tid] = fmaxf(red[tid], red[tid + sft]);
        __syncthreads();
    }
    float m = red[0];

    // phase 2: thread c accumulates channel c; denominator computed redundantly
    int c = tid;
    float yic = Yip[(size_t)n * C_ + c];
    float v1c = v1[et * C_ + c];
    float acc = 0.f, denom = 0.f;
    for (int i = 0; i < deg; ++i) {
        int s = sp[i];          // broadcast (wave-uniform)
        float wei = wp[i];
        float al = asp[s] + adn;
        al = (al > 0.f) ? al : 0.2f * al;
        float p = __expf(al - m);
        denom += p;
        float att = Yjp[(size_t)s * C_ + c] + yic + wei * v1c;
        acc = fmaf(p * xs[(size_t)s * C_ + c], att, acc);
    }
    float outv = (deg > 0) ? acc / denom : 0.f;
    float* orow = aggrcat + ((size_t)be * N_ + n) * 256;
    orow[c] = outv;
    orow[128 + c] = xd[(size_t)n * C_ + c];
}

// outs[b][et] = tanh(relu(aggrcat[b][et] @ agg_w[et] + agg_b[et]))
__global__ __launch_bounds__(128) void agggemm_kernel(const float* __restrict__ aggrcat,
                                                      const float* __restrict__ agg_w,
                                                      const float* __restrict__ agg_b,
                                                      float* __restrict__ outs)
{
    int row0 = blockIdx.x * GROWS;
    int et = blockIdx.y, b = blockIdx.z;
    const float* A = aggrcat + (size_t)(b * T_ + et) * N_ * 256;
    gemm_core<256, GROWS>(A, agg_w + (size_t)et * 256 * C_, agg_b + et * C_,
                          outs + (size_t)(b * T_ + et) * N_ * C_, nullptr, row0, 1);
}

// colsum[b][nt][t][c] = sum_n tanh(outs[b][et(nt,t)] @ klin_w[nt] + klin_b[nt])[n,c]
__global__ __launch_bounds__(128) void klin_kernel(const float* __restrict__ outs,
                                                   const float* __restrict__ klin_w,
                                                   const float* __restrict__ klin_b,
                                                   float* __restrict__ colsum)
{
    int row0 = blockIdx.x * GROWS;
    int nt = blockIdx.y >> 1, t = blockIdx.y & 1, b = blockIdx.z;
    int et = (t == 0) ? nt : 3 - nt;
    const float* A = outs + (size_t)(b * T_ + et) * N_ * C_;
    gemm_core<128, GROWS>(A, klin_w + (size_t)nt * C_ * C_, klin_b + nt * C_,
                          nullptr, colsum + (size_t)((b * 2 + nt) * 2 + t) * C_, row0, 2);
}

__global__ __launch_bounds__(128) void score_kernel(const float* __restrict__ colsum,
                                                    const float* __restrict__ q,
                                                    float* __restrict__ attn)
{
    int bnt = blockIdx.x;  // b*2+nt
    int nt = bnt & 1;
    int c = threadIdx.x;
    __shared__ float r0[128], r1[128];
    float qc = q[nt * C_ + c];
    r0[c] = qc * colsum[(size_t)(bnt * 2 + 0) * C_ + c];
    r1[c] = qc * colsum[(size_t)(bnt * 2 + 1) * C_ + c];
    __syncthreads();
    for (int s = 64; s > 0; s >>= 1) {
        if (c < s) { r0[c] += r0[c + s]; r1[c] += r1[c + s]; }
        __syncthreads();
    }
    if (c == 0) {
        float s0 = r0[0] / (float)N_, s1 = r1[0] / (float)N_;
        float mx = fmaxf(s0, s1);
        float e0 = __expf(s0 - mx), e1 = __expf(s1 - mx);
        float inv = 1.f / (e0 + e1);
        attn[bnt * 2 + 0] = e0 * inv;
        attn[bnt * 2 + 1] = e1 * inv;
    }
}

__global__ void output_kernel(const float* __restrict__ outs,
                              const float* __restrict__ attn,
                              float* __restrict__ out)
{
    int idx = blockIdx.x * blockDim.x + threadIdx.x;  // float4 index; total 640000
    int c4 = idx & 31;   // 32 float4 per 128-col row
    int row = idx >> 5;  // 0..19999
    int b = row / TWO_N;
    int r = row % TWO_N;
    int nt = (r >= N_) ? 1 : 0;
    int n = r - nt * N_;
    int et0 = nt, et1 = 3 - nt;
    float a0 = attn[(b * 2 + nt) * 2 + 0];
    float a1 = attn[(b * 2 + nt) * 2 + 1];
    const float4* o0 = (const float4*)(outs + ((size_t)(b * T_ + et0) * N_ + n) * C_);
    const float4* o1 = (const float4*)(outs + ((size_t)(b * T_ + et1) * N_ + n) * C_);
    float4 v0 = o0[c4], v1 = o1[c4], o;
    o.x = a0 * v0.x + a1 * v1.x;
    o.y = a0 * v0.y + a1 * v1.y;
    o.z = a0 * v0.z + a1 * v1.z;
    o.w = a0 * v0.w + a1 * v1.w;
    ((float4*)out)[idx] = o;
}

extern "C" void kernel_launch(void* const* d_in, const int* in_sizes, int n_in,
                              void* d_out, int out_size, void* d_ws, size_t ws_size,
                              hipStream_t stream)
{
    const float* x       = (const float*)d_in[0];
    const int*   eidx    = (const int*)d_in[1];
    const float* ew      = (const float*)d_in[2];
    const float* proj_w  = (const float*)d_in[3];
    const float* proj_b  = (const float*)d_in[4];
    const float* q       = (const float*)d_in[5];
    const float* klin_w  = (const float*)d_in[6];
    const float* klin_b  = (const float*)d_in[7];
    const float* lin_src = (const float*)d_in[8];
    const float* lin_dst = (const float*)d_in[9];
    const float* eproj_w = (const float*)d_in[10];
    const float* eproj_b = (const float*)d_in[11];
    const float* agg_w   = (const float*)d_in[12];
    const float* agg_b   = (const float*)d_in[13];
    const float* att_w   = (const float*)d_in[14];
    const float* att_b   = (const float*)d_in[15];

    float* ws = (float*)d_ws;
    size_t o = 0;
    float* xn      = ws + o; o += (size_t)B_ * 2 * N_ * C_;        // 2,560,000
    float* Yj      = ws + o; o += (size_t)B_ * T_ * N_ * C_;       // 5,120,000
    float* Yi      = ws + o; o += (size_t)B_ * T_ * N_ * C_;       // 5,120,000
    float* aggrcat = ws + o; o += (size_t)B_ * T_ * N_ * 256;      // 10,240,000
    float* outsb   = ws + o; o += (size_t)B_ * T_ * N_ * C_;       // 5,120,000
    float* asrc    = ws + o; o += (size_t)B_ * T_ * N_;            // 40,000
    float* adst    = ws + o; o += (size_t)B_ * T_ * N_;            // 40,000
    float* v1      = ws + o; o += T_ * C_;                         // 512
    float* bias_i  = ws + o; o += T_ * C_;                         // 512
    float* sew     = ws + o; o += (size_t)B_ * T_ * E_;            // 524,288
    float* attn    = ws + o; o += 16;
    // zero-init region (contiguous): count, cursor, colsum
    int*   count   = (int*)(ws + o); o += (size_t)B_ * T_ * N_;    // 40,000
    int*   cursor  = (int*)(ws + o); o += (size_t)B_ * T_ * N_;    // 40,000
    float* colsum  = ws + o; o += (size_t)B_ * 2 * 2 * C_;         // 1,024
    int*   offs    = (int*)(ws + o); o += (size_t)B_ * T_ * (N_ + 1); // 40,008
    int*   ssrc    = (int*)(ws + o); o += (size_t)B_ * T_ * E_;    // 524,288
    // total ~29.42M floats (~118 MB)

    hipMemsetAsync(count, 0, (size_t)(40000 + 40000 + 1024) * 4, stream);

    prep_kernel<<<dim3(T_), 128, 0, stream>>>(eproj_w, eproj_b, att_w, att_b, v1, bias_i);
    proj_kernel<<<dim3(N_ / GROWS, 2, B_), 128, 0, stream>>>(x, proj_w, proj_b, xn);
    nodedot_kernel<<<dim3((N_ + 255) / 256, T_ * 2, B_), 256, 0, stream>>>(xn, lin_src, lin_dst, asrc, adst);
    count_kernel<<<dim3(E_ / 256, T_, B_), 256, 0, stream>>>(eidx, count);
    scan_kernel<<<dim3(B_ * T_), 256, 0, stream>>>(count, offs);
    scatter_kernel<<<dim3(E_ / 256, T_, B_), 256, 0, stream>>>(eidx, ew, offs, cursor, ssrc, sew);
    yji_kernel<<<dim3(N_ / GROWS, T_ * 2, B_), 128, 0, stream>>>(xn, att_w, bias_i, Yj, Yi);
    aggregate_kernel<<<dim3(N_, T_, B_), 128, 0, stream>>>(xn, Yj, Yi, asrc, adst, v1,
                                                           offs, ssrc, sew, aggrcat);
    agggemm_kernel<<<dim3(N_ / GROWS, T_, B_), 128, 0, stream>>>(aggrcat, agg_w, agg_b, outsb);
    klin_kernel<<<dim3(N_ / GROWS, 2 * 2, B_), 128, 0, stream>>>(outsb, klin_w, klin_b, colsum);
    score_kernel<<<dim3(B_ * 2), 128, 0, stream>>>(colsum, q, attn);
    output_kernel<<<dim3((size_t)B_ * TWO_N * C_ / 4 / 256), 256, 0, stream>>>(outsb, attn, (float*)d_out);
}

// Round 2
// 390.498 us; speedup vs baseline: 1.3357x; 1.3357x over previous
//
#include <hip/hip_runtime.h>
#include <math.h>

// Problem constants (from reference setup_inputs)
#define B_    2
#define N_    5000
#define C_    128
#define E_    65536
#define T_    4
#define TWO_N 10000

// edge types: (src_node_type, dst_node_type) = (0,0),(1,1),(0,1),(1,0)
// s_t = et & 1 ; d_t = ((et+1)>>1) & 1
// node-type nt receives from edge types: nt=0 -> {0,3}, nt=1 -> {1,2}

// ---------------------------------------------------------------------------
// bf16 split helpers: a = hi + lo with ~2^-16 relative representation error.
// ---------------------------------------------------------------------------
__device__ __forceinline__ unsigned short f2bf(float f) {
    unsigned u = __float_as_uint(f);
    u += 0x7fffu + ((u >> 16) & 1u);   // round-to-nearest-even
    return (unsigned short)(u >> 16);
}
__device__ __forceinline__ float bf2f(unsigned short h) {
    return __uint_as_float(((unsigned)h) << 16);
}

typedef __attribute__((ext_vector_type(8))) short bfrag;   // 8 bf16 (4 VGPRs)
typedef __attribute__((ext_vector_type(4))) float ffrag;   // 4 fp32 acc

// Packed-weight slot offsets (in elements; each K*128):
//   proj(2,K=128)@0 ; yji(8,K=128)@32768 ; agg(4,K=256)@163840 ; klin(2,K=128)@294912
#define WOFF_PROJ 0
#define WOFF_YJI  32768
#define WOFF_AGG  163840
#define WOFF_KLIN 294912

// ---------------------------------------------------------------------------
// MFMA split-bf16 GEMM core. Block = 256 threads = 4 waves; block tile M=128
// (32 rows/wave), N=128 (8 n-tiles of 16), fp32 accumulate.
// A hi/lo: row-major [M][K] bf16.  W packed: [K/32][8][64][8] bf16.
// mfma_f32_16x16x32_bf16 layouts: A[m=lane&15][k=quad*8+j];
// B[k=quad*8+j][n=lane&15]; C/D col=lane&15, row=quad*4+reg.
// ---------------------------------------------------------------------------
template <int K>
__device__ __forceinline__ void mfma_core(const unsigned short* __restrict__ Ahi,
                                          const unsigned short* __restrict__ Alo,
                                          const unsigned short* __restrict__ Whi,
                                          const unsigned short* __restrict__ Wlo,
                                          int Mlim, ffrag (&acc)[2][8])
{
    const int wave = threadIdx.x >> 6, lane = threadIdx.x & 63;
    const int mloc = lane & 15, quad = lane >> 4;
    const int row0w = blockIdx.x * 128 + wave * 32;
    int r0 = row0w + mloc;
    int r1 = row0w + 16 + mloc;
    if (r0 >= Mlim) r0 = Mlim - 1;   // clamp; stores are guarded by row index
    if (r1 >= Mlim) r1 = Mlim - 1;
    const unsigned short* pA0h = Ahi + (size_t)r0 * K + quad * 8;
    const unsigned short* pA0l = Alo + (size_t)r0 * K + quad * 8;
    const unsigned short* pA1h = Ahi + (size_t)r1 * K + quad * 8;
    const unsigned short* pA1l = Alo + (size_t)r1 * K + quad * 8;
#pragma unroll
    for (int s = 0; s < K / 32; ++s) {
        bfrag a0h = *(const bfrag*)(pA0h + s * 32);
        bfrag a0l = *(const bfrag*)(pA0l + s * 32);
        bfrag a1h = *(const bfrag*)(pA1h + s * 32);
        bfrag a1l = *(const bfrag*)(pA1l + s * 32);
        const unsigned short* pBh = Whi + ((size_t)s * 512 + lane) * 8;
        const unsigned short* pBl = Wlo + ((size_t)s * 512 + lane) * 8;
#pragma unroll
        for (int t = 0; t < 8; ++t) {
            bfrag bh = *(const bfrag*)(pBh + (size_t)t * 512);
            bfrag bl = *(const bfrag*)(pBl + (size_t)t * 512);
            acc[0][t] = __builtin_amdgcn_mfma_f32_16x16x32_bf16(a0h, bh, acc[0][t], 0, 0, 0);
            acc[0][t] = __builtin_amdgcn_mfma_f32_16x16x32_bf16(a0l, bh, acc[0][t], 0, 0, 0);
            acc[0][t] = __builtin_amdgcn_mfma_f32_16x16x32_bf16(a0h, bl, acc[0][t], 0, 0, 0);
            acc[1][t] = __builtin_amdgcn_mfma_f32_16x16x32_bf16(a1h, bh, acc[1][t], 0, 0, 0);
            acc[1][t] = __builtin_amdgcn_mfma_f32_16x16x32_bf16(a1l, bh, acc[1][t], 0, 0, 0);
            acc[1][t] = __builtin_amdgcn_mfma_f32_16x16x32_bf16(a1h, bl, acc[1][t], 0, 0, 0);
        }
    }
}

// Epilogue: +bias, optional tanh(relu()), store fp32 (+ optional bf16 hi/lo copy).
template <int ACT>  // 0 = none, 1 = tanh(relu(x))
__device__ __forceinline__ void store_tile(ffrag (&acc)[2][8],
                                           const float* __restrict__ bias,
                                           float* __restrict__ out,
                                           unsigned short* __restrict__ ohi,
                                           unsigned short* __restrict__ olo, int Mlim)
{
    const int wave = threadIdx.x >> 6, lane = threadIdx.x & 63;
    const int mloc = lane & 15, quad = lane >> 4;
    const int rbase = blockIdx.x * 128 + wave * 32 + quad * 4;
#pragma unroll
    for (int h = 0; h < 2; ++h) {
#pragma unroll
        for (int r = 0; r < 4; ++r) {
            int row = rbase + h * 16 + r;
            if (row >= Mlim) continue;
#pragma unroll
            for (int t = 0; t < 8; ++t) {
                int col = t * 16 + mloc;
                float v = acc[h][t][r] + (bias ? bias[col] : 0.f);
                if (ACT == 1) v = (v > 0.f) ? tanhf(v) : 0.f;
                out[(size_t)row * C_ + col] = v;
                if (ohi) {
                    unsigned short hh = f2bf(v);
                    ohi[(size_t)row * C_ + col] = hh;
                    olo[(size_t)row * C_ + col] = f2bf(v - bf2f(hh));
                }
            }
        }
    }
}

// fp32 -> (hi, lo) bf16 elementwise (for input x)
__global__ void convert_x_kernel(const float* __restrict__ x,
                                 unsigned short* __restrict__ xh,
                                 unsigned short* __restrict__ xl, int n)
{
    int i = blockIdx.x * 256 + threadIdx.x;
    if (i >= n) return;
    float v = x[i];
    unsigned short h = f2bf(v);
    xh[i] = h;
    xl[i] = f2bf(v - bf2f(h));
}

// Pack all weight matrices into B-fragment layout, hi/lo bf16.
__global__ __launch_bounds__(64) void pack_w_kernel(const float* __restrict__ proj_w,
                                                    const float* __restrict__ att_w,
                                                    const float* __restrict__ agg_w,
                                                    const float* __restrict__ klin_w,
                                                    unsigned short* __restrict__ wh,
                                                    unsigned short* __restrict__ wl)
{
    int st = blockIdx.x;         // s*8 + t  (s<8, t<8)
    int s = st >> 3, t = st & 7;
    int id = blockIdx.y;         // 0..15
    const float* src;
    int K;
    size_t doff;
    if (id < 2)       { src = proj_w + (size_t)id * 16384; K = 128; doff = WOFF_PROJ + (size_t)id * 16384; }
    else if (id < 10) { int m = id - 2, et = m >> 1, role = m & 1;
                        src = att_w + ((size_t)et * 384 + (size_t)role * 128) * 128;
                        K = 128; doff = WOFF_YJI + (size_t)m * 16384; }
    else if (id < 14) { int et = id - 10; src = agg_w + (size_t)et * 256 * 128;
                        K = 256; doff = WOFF_AGG + (size_t)et * 32768; }
    else              { int nt = id - 14; src = klin_w + (size_t)nt * 16384;
                        K = 128; doff = WOFF_KLIN + (size_t)nt * 16384; }
    if (s >= K / 32) return;
    int lane = threadIdx.x, mloc = lane & 15, quad = lane >> 4;
    size_t dbase = doff + ((size_t)(s * 8 + t) * 64 + lane) * 8;
#pragma unroll
    for (int j = 0; j < 8; ++j) {
        float v = src[(size_t)(s * 32 + quad * 8 + j) * 128 + t * 16 + mloc];
        unsigned short h = f2bf(v);
        wh[dbase + j] = h;
        wl[dbase + j] = f2bf(v - bf2f(h));
    }
}

// xn = x @ proj_w + proj_b  (also emits hi/lo bf16 of xn)
__global__ __launch_bounds__(256) void proj_mfma(const unsigned short* __restrict__ xh,
                                                 const unsigned short* __restrict__ xl,
                                                 const unsigned short* __restrict__ wph,
                                                 const unsigned short* __restrict__ wpl,
                                                 const float* __restrict__ proj_b,
                                                 float* __restrict__ xn,
                                                 unsigned short* __restrict__ xnh,
                                                 unsigned short* __restrict__ xnl)
{
    int nt = blockIdx.y, b = blockIdx.z;
    size_t abase = (size_t)(b * TWO_N + nt * N_) * C_;
    ffrag acc[2][8];
#pragma unroll
    for (int h = 0; h < 2; ++h)
#pragma unroll
        for (int t = 0; t < 8; ++t) acc[h][t] = (ffrag){0.f, 0.f, 0.f, 0.f};
    size_t woff = WOFF_PROJ + (size_t)nt * 16384;
    mfma_core<128>(xh + abase, xl + abase, wph + woff, wpl + woff, N_, acc);
    size_t obase = (size_t)(b * 2 + nt) * N_ * C_;
    store_tile<0>(acc, proj_b + nt * C_, xn + obase, xnh + obase, xnl + obase, N_);
}

// Yj = xn[s_t] @ Wj ; Yi = xn[d_t] @ Wi + bias_i
__global__ __launch_bounds__(256) void yji_mfma(const unsigned short* __restrict__ xnh,
                                                const unsigned short* __restrict__ xnl,
                                                const unsigned short* __restrict__ wph,
                                                const unsigned short* __restrict__ wpl,
                                                const float* __restrict__ bias_i,
                                                float* __restrict__ Yj,
                                                float* __restrict__ Yi)
{
    int m = blockIdx.y, b = blockIdx.z;  // m = et*2+role
    int et = m >> 1, role = m & 1;
    int s_t = et & 1, d_t = ((et + 1) >> 1) & 1;
    int ntsel = role ? d_t : s_t;
    size_t abase = (size_t)(b * 2 + ntsel) * N_ * C_;
    ffrag acc[2][8];
#pragma unroll
    for (int h = 0; h < 2; ++h)
#pragma unroll
        for (int t = 0; t < 8; ++t) acc[h][t] = (ffrag){0.f, 0.f, 0.f, 0.f};
    size_t woff = WOFF_YJI + (size_t)m * 16384;
    mfma_core<128>(xnh + abase, xnl + abase, wph + woff, wpl + woff, N_, acc);
    size_t obase = (size_t)(b * T_ + et) * N_ * C_;
    if (role == 0)
        store_tile<0>(acc, nullptr, Yj + obase, nullptr, nullptr, N_);
    else
        store_tile<0>(acc, bias_i + et * C_, Yi + obase, nullptr, nullptr, N_);
}

// outs = tanh(relu(aggrcat @ agg_w + agg_b))  (K=256), emits fp32 + hi/lo
__global__ __launch_bounds__(256) void agg_mfma(const unsigned short* __restrict__ achi,
                                                const unsigned short* __restrict__ aclo,
                                                const unsigned short* __restrict__ wph,
                                                const unsigned short* __restrict__ wpl,
                                                const float* __restrict__ agg_b,
                                                float* __restrict__ outs,
                                                unsigned short* __restrict__ outsh,
                                                unsigned short* __restrict__ outsl)
{
    int et = blockIdx.y, b = blockIdx.z;
    size_t abase = (size_t)(b * T_ + et) * N_ * 256;
    ffrag acc[2][8];
#pragma unroll
    for (int h = 0; h < 2; ++h)
#pragma unroll
        for (int t = 0; t < 8; ++t) acc[h][t] = (ffrag){0.f, 0.f, 0.f, 0.f};
    size_t woff = WOFF_AGG + (size_t)et * 32768;
    mfma_core<256>(achi + abase, aclo + abase, wph + woff, wpl + woff, N_, acc);
    size_t obase = (size_t)(b * T_ + et) * N_ * C_;
    store_tile<1>(acc, agg_b + et * C_, outs + obase, outsh + obase, outsl + obase, N_);
}

// colsum[b][nt][t] += sum_n tanh(outs[et] @ klin_w[nt] + klin_b[nt])
__global__ __launch_bounds__(256) void klin_mfma(const unsigned short* __restrict__ outsh,
                                                 const unsigned short* __restrict__ outsl,
                                                 const unsigned short* __restrict__ wph,
                                                 const unsigned short* __restrict__ wpl,
                                                 const float* __restrict__ klin_b,
                                                 float* __restrict__ colsum)
{
    int g = blockIdx.y, b = blockIdx.z;  // g = nt*2 + t
    int nt = g >> 1, tt = g & 1;
    int et = (tt == 0) ? nt : 3 - nt;
    size_t abase = (size_t)(b * T_ + et) * N_ * C_;
    ffrag acc[2][8];
#pragma unroll
    for (int h = 0; h < 2; ++h)
#pragma unroll
        for (int t = 0; t < 8; ++t) acc[h][t] = (ffrag){0.f, 0.f, 0.f, 0.f};
    size_t woff = WOFF_KLIN + (size_t)nt * 16384;
    mfma_core<128>(outsh + abase, outsl + abase, wph + woff, wpl + woff, N_, acc);

    __shared__ float cs[128];
    if (threadIdx.x < 128) cs[threadIdx.x] = 0.f;
    __syncthreads();
    const int wave = threadIdx.x >> 6, lane = threadIdx.x & 63;
    const int mloc = lane & 15, quad = lane >> 4;
    const int rbase = blockIdx.x * 128 + wave * 32 + quad * 4;
#pragma unroll
    for (int t = 0; t < 8; ++t) {
        int col = t * 16 + mloc;
        float bv = klin_b[nt * C_ + col];
        float s = 0.f;
#pragma unroll
        for (int h = 0; h < 2; ++h)
#pragma unroll
            for (int r = 0; r < 4; ++r) {
                int row = rbase + h * 16 + r;
                if (row < N_) s += tanhf(acc[h][t][r] + bv);
            }
        atomicAdd(&cs[col], s);
    }
    __syncthreads();
    if (threadIdx.x < 128)
        atomicAdd(&colsum[(size_t)((b * 2 + nt) * 2 + tt) * C_ + threadIdx.x],
                  cs[threadIdx.x]);
}

// v1[et] = eproj_w[et] @ We_block ; bias_i[et] = att_b[et] + eproj_b[et] @ We_block
__global__ void prep_kernel(const float* __restrict__ eproj_w,
                            const float* __restrict__ eproj_b,
                            const float* __restrict__ att_w,
                            const float* __restrict__ att_b,
                            float* __restrict__ v1, float* __restrict__ bias_i)
{
    int et = blockIdx.x, c = threadIdx.x;
    float s1 = 0.f, s0 = 0.f;
    for (int k = 0; k < 128; ++k) {
        float wv = att_w[(size_t)et * 384 * C_ + (size_t)(256 + k) * C_ + c];
        s1 = fmaf(eproj_w[et * C_ + k], wv, s1);
        s0 = fmaf(eproj_b[et * C_ + k], wv, s0);
    }
    v1[et * C_ + c] = s1;
    bias_i[et * C_ + c] = att_b[et * C_ + c] + s0;
}

// asrc/adst node dots
__global__ void nodedot_kernel(const float* __restrict__ xn,
                               const float* __restrict__ lin_src,
                               const float* __restrict__ lin_dst,
                               float* __restrict__ asrc, float* __restrict__ adst)
{
    int n = blockIdx.x * blockDim.x + threadIdx.x;
    if (n >= N_) return;
    int et = blockIdx.y >> 1, role = blockIdx.y & 1, b = blockIdx.z;
    int s_t = et & 1, d_t = ((et + 1) >> 1) & 1;
    int ntsel = role ? d_t : s_t;
    const float* lin = (role ? lin_dst : lin_src) + et * C_;
    const float* row = xn + ((size_t)(b * 2 + ntsel) * N_ + n) * C_;
    float s = 0.f;
#pragma unroll 4
    for (int i = 0; i < C_; ++i) s = fmaf(row[i], lin[i], s);
    float* dstp = role ? adst : asrc;
    dstp[(size_t)(b * T_ + et) * N_ + n] = s;
}

__global__ void count_kernel(const int* __restrict__ eidx, int* __restrict__ count)
{
    int e = blockIdx.x * blockDim.x + threadIdx.x;
    int et = blockIdx.y, b = blockIdx.z;
    int dst = eidx[(((size_t)et * B_ + b) * 2 + 1) * E_ + e];
    atomicAdd(&count[(size_t)(b * T_ + et) * N_ + dst], 1);
}

__global__ __launch_bounds__(256) void scan_kernel(const int* __restrict__ count,
                                                   int* __restrict__ offs)
{
    int be = blockIdx.x;
    const int* cnt = count + (size_t)be * N_;
    int* off = offs + (size_t)be * (N_ + 1);
    __shared__ int sums[256];
    int tid = threadIdx.x;
    const int chunk = (N_ + 255) / 256;  // 20
    int lo = tid * chunk, hi = min(lo + chunk, N_);
    int s = 0;
    for (int i = lo; i < hi; ++i) s += cnt[i];
    sums[tid] = s;
    __syncthreads();
    for (int d = 1; d < 256; d <<= 1) {
        int v = (tid >= d) ? sums[tid - d] : 0;
        __syncthreads();
        sums[tid] += v;
        __syncthreads();
    }
    int run = (tid > 0) ? sums[tid - 1] : 0;
    for (int i = lo; i < hi; ++i) { off[i] = run; run += cnt[i]; }
    if (tid == 255) off[N_] = sums[255];
}

__global__ void scatter_kernel(const int* __restrict__ eidx, const float* __restrict__ ew,
                               const int* __restrict__ offs, int* __restrict__ cursor,
                               int* __restrict__ ssrc, float* __restrict__ sew)
{
    int e = blockIdx.x * blockDim.x + threadIdx.x;
    int et = blockIdx.y, b = blockIdx.z;
    size_t ebase = ((size_t)et * B_ + b) * 2 * E_;
    int src = eidx[ebase + e];
    int dst = eidx[ebase + E_ + e];
    int be = b * T_ + et;
    int pos = offs[(size_t)be * (N_ + 1) + dst] + atomicAdd(&cursor[(size_t)be * N_ + dst], 1);
    ssrc[(size_t)be * E_ + pos] = src;
    sew[(size_t)be * E_ + pos] = ew[((size_t)et * B_ + b) * E_ + e];
}

// Segment softmax + weighted aggregation; emits aggrcat rows as bf16 hi/lo:
// [ aggr (128) | xn[d_t][n] (128) ]
__global__ __launch_bounds__(128) void aggregate_kernel(
    const float* __restrict__ xn, const float* __restrict__ Yj,
    const float* __restrict__ Yi, const float* __restrict__ asrc,
    const float* __restrict__ adst, const float* __restrict__ v1,
    const int* __restrict__ offs, const int* __restrict__ ssrc,
    const float* __restrict__ sew,
    unsigned short* __restrict__ achi, unsigned short* __restrict__ aclo)
{
    int n = blockIdx.x, et = blockIdx.y, b = blockIdx.z;
    int s_t = et & 1, d_t = ((et + 1) >> 1) & 1;
    int be = b * T_ + et;
    int tid = threadIdx.x;
    const float* xs = xn + (size_t)(b * 2 + s_t) * N_ * C_;
    const float* xd = xn + (size_t)(b * 2 + d_t) * N_ * C_;
    const float* Yjp = Yj + (size_t)be * N_ * C_;
    const float* Yip = Yi + (size_t)be * N_ * C_;
    const float* asp = asrc + (size_t)be * N_;
    float adn = adst[(size_t)be * N_ + n];
    int beg = offs[(size_t)be * (N_ + 1) + n];
    int end = offs[(size_t)be * (N_ + 1) + n + 1];
    int deg = end - beg;
    const int* sp = ssrc + (size_t)be * E_ + beg;
    const float* wp = sew + (size_t)be * E_ + beg;

    __shared__ float red[128];
    float lmax = -1e30f;
    for (int i = tid; i < deg; i += 128) {
        float al = asp[sp[i]] + adn;
        al = (al > 0.f) ? al : 0.2f * al;
        lmax = fmaxf(lmax, al);
    }
    red[tid] = lmax;
    __syncthreads();
    for (int sft = 64; sft > 0; sft >>= 1) {
        if (tid < sft) red[tid] = fmaxf(red[tid], red[tid + sft]);
        __syncthreads();
    }
    float m = red[0];

    int c = tid;
    float yic = Yip[(size_t)n * C_ + c];
    float v1c = v1[et * C_ + c];
    float acc = 0.f, denom = 0.f;
    for (int i = 0; i < deg; ++i) {
        int s = sp[i];
        float wei = wp[i];
        float al = asp[s] + adn;
        al = (al > 0.f) ? al : 0.2f * al;
        float p = __expf(al - m);
        denom += p;
        float att = Yjp[(size_t)s * C_ + c] + yic + wei * v1c;
        acc = fmaf(p * xs[(size_t)s * C_ + c], att, acc);
    }
    float outv = (deg > 0) ? acc / denom : 0.f;
    float xdv = xd[(size_t)n * C_ + c];
    size_t ob = ((size_t)be * N_ + n) * 256;
    unsigned short hh = f2bf(outv);
    achi[ob + c] = hh;
    aclo[ob + c] = f2bf(outv - bf2f(hh));
    hh = f2bf(xdv);
    achi[ob + 128 + c] = hh;
    aclo[ob + 128 + c] = f2bf(xdv - bf2f(hh));
}

__global__ __launch_bounds__(128) void score_kernel(const float* __restrict__ colsum,
                                                    const float* __restrict__ q,
                                                    float* __restrict__ attn)
{
    int bnt = blockIdx.x;
    int nt = bnt & 1;
    int c = threadIdx.x;
    __shared__ float r0[128], r1[128];
    float qc = q[nt * C_ + c];
    r0[c] = qc * colsum[(size_t)(bnt * 2 + 0) * C_ + c];
    r1[c] = qc * colsum[(size_t)(bnt * 2 + 1) * C_ + c];
    __syncthreads();
    for (int s = 64; s > 0; s >>= 1) {
        if (c < s) { r0[c] += r0[c + s]; r1[c] += r1[c + s]; }
        __syncthreads();
    }
    if (c == 0) {
        float s0 = r0[0] / (float)N_, s1 = r1[0] / (float)N_;
        float mx = fmaxf(s0, s1);
        float e0 = __expf(s0 - mx), e1 = __expf(s1 - mx);
        float inv = 1.f / (e0 + e1);
        attn[bnt * 2 + 0] = e0 * inv;
        attn[bnt * 2 + 1] = e1 * inv;
    }
}

__global__ void output_kernel(const float* __restrict__ outs,
                              const float* __restrict__ attn,
                              float* __restrict__ out)
{
    int idx = blockIdx.x * blockDim.x + threadIdx.x;
    int c4 = idx & 31;
    int row = idx >> 5;
    int b = row / TWO_N;
    int r = row % TWO_N;
    int nt = (r >= N_) ? 1 : 0;
    int n = r - nt * N_;
    int et0 = nt, et1 = 3 - nt;
    float a0 = attn[(b * 2 + nt) * 2 + 0];
    float a1 = attn[(b * 2 + nt) * 2 + 1];
    const float4* o0 = (const float4*)(outs + ((size_t)(b * T_ + et0) * N_ + n) * C_);
    const float4* o1 = (const float4*)(outs + ((size_t)(b * T_ + et1) * N_ + n) * C_);
    float4 v0 = o0[c4], v1 = o1[c4], o;
    o.x = a0 * v0.x + a1 * v1.x;
    o.y = a0 * v0.y + a1 * v1.y;
    o.z = a0 * v0.z + a1 * v1.z;
    o.w = a0 * v0.w + a1 * v1.w;
    ((float4*)out)[idx] = o;
}

extern "C" void kernel_launch(void* const* d_in, const int* in_sizes, int n_in,
                              void* d_out, int out_size, void* d_ws, size_t ws_size,
                              hipStream_t stream)
{
    const float* x       = (const float*)d_in[0];
    const int*   eidx    = (const int*)d_in[1];
    const float* ew      = (const float*)d_in[2];
    const float* proj_w  = (const float*)d_in[3];
    const float* proj_b  = (const float*)d_in[4];
    const float* q       = (const float*)d_in[5];
    const float* klin_w  = (const float*)d_in[6];
    const float* klin_b  = (const float*)d_in[7];
    const float* lin_src = (const float*)d_in[8];
    const float* lin_dst = (const float*)d_in[9];
    const float* eproj_w = (const float*)d_in[10];
    const float* eproj_b = (const float*)d_in[11];
    const float* agg_w   = (const float*)d_in[12];
    const float* agg_b   = (const float*)d_in[13];
    const float* att_w   = (const float*)d_in[14];
    const float* att_b   = (const float*)d_in[15];

    float* ws = (float*)d_ws;
    size_t o = 0;
    float*          xn     = ws + o;                   o += 2560000;
    unsigned short* xnh    = (unsigned short*)(ws + o); o += 1280000;
    unsigned short* xnl    = (unsigned short*)(ws + o); o += 1280000;
    unsigned short* achi   = (unsigned short*)(ws + o); o += 5120000;  // 10.24M ushort
    unsigned short* aclo   = (unsigned short*)(ws + o); o += 5120000;
    float*          sew    = ws + o;                   o += 524288;
    float*          asrc   = ws + o;                   o += 40000;
    float*          adst   = ws + o;                   o += 40000;
    float*          v1     = ws + o;                   o += 512;
    float*          bias_i = ws + o;                   o += 512;
    float*          attn   = ws + o;                   o += 16;
    // zero-init block (contiguous): count, cursor, colsum
    int*            count  = (int*)(ws + o);           o += 40000;
    int*            cursor = (int*)(ws + o);           o += 40000;
    float*          colsum = ws + o;                   o += 1024;
    int*            offs   = (int*)(ws + o);           o += 40008;
    int*            ssrc   = (int*)(ws + o);           o += 524288;
    unsigned short* wph    = (unsigned short*)(ws + o); o += 163840;  // 327,680 ushort
    unsigned short* wpl    = (unsigned short*)(ws + o); o += 163840;
    // Union region Q (10,240,000 floats), lifetime-disjoint users:
    //   Q1 [convert_x .. proj]:  x_hi | x_lo
    //   Q2 [yji .. aggregate]:   Yj | Yi
    //   Q3 [agg_mfma .. output]: outs | outs_hi | outs_lo
    float* Q = ws + o;                                 o += 10240000;
    unsigned short* xh    = (unsigned short*)Q;            // 2.56M ushort
    unsigned short* xl    = (unsigned short*)Q + 2560000;
    float*          Yj    = Q;
    float*          Yi    = Q + 5120000;
    float*          outsb = Q;
    unsigned short* outsh = (unsigned short*)(Q + 5120000);
    unsigned short* outsl = (unsigned short*)(Q + 5120000) + 2560000;
    // total: 27,178,328 floats = ~108.7 MB

    hipMemsetAsync(count, 0, (size_t)(40000 + 40000 + 1024) * 4, stream);

    prep_kernel<<<dim3(T_), 128, 0, stream>>>(eproj_w, eproj_b, att_w, att_b, v1, bias_i);
    pack_w_kernel<<<dim3(64, 16), 64, 0, stream>>>(proj_w, att_w, agg_w, klin_w, wph, wpl);
    convert_x_kernel<<<dim3(10000), 256, 0, stream>>>(x, xh, xl, B_ * TWO_N * C_);

    proj_mfma<<<dim3(40, 2, B_), 256, 0, stream>>>(xh, xl, wph, wpl, proj_b, xn, xnh, xnl);
    nodedot_kernel<<<dim3(20, T_ * 2, B_), 256, 0, stream>>>(xn, lin_src, lin_dst, asrc, adst);
    count_kernel<<<dim3(E_ / 256, T_, B_), 256, 0, stream>>>(eidx, count);
    scan_kernel<<<dim3(B_ * T_), 256, 0, stream>>>(count, offs);
    scatter_kernel<<<dim3(E_ / 256, T_, B_), 256, 0, stream>>>(eidx, ew, offs, cursor, ssrc, sew);
    yji_mfma<<<dim3(40, 8, B_), 256, 0, stream>>>(xnh, xnl, wph, wpl, bias_i, Yj, Yi);
    aggregate_kernel<<<dim3(N_, T_, B_), 128, 0, stream>>>(xn, Yj, Yi, asrc, adst, v1,
                                                           offs, ssrc, sew, achi, aclo);
    agg_mfma<<<dim3(40, T_, B_), 256, 0, stream>>>(achi, aclo, wph, wpl, agg_b,
                                                   outsb, outsh, outsl);
    klin_mfma<<<dim3(40, 4, B_), 256, 0, stream>>>(outsh, outsl, wph, wpl, klin_b, colsum);
    score_kernel<<<dim3(B_ * 2), 128, 0, stream>>>(colsum, q, attn);
    output_kernel<<<dim3(2500), 256, 0, stream>>>(outsb, attn, (float*)d_out);
}

// Round 4
// 360.692 us; speedup vs baseline: 1.4461x; 1.0826x over previous
//
#include <hip/hip_runtime.h>
#include <math.h>

// Problem constants (from reference setup_inputs)
#define B_    2
#define N_    5000
#define C_    128
#define E_    65536
#define T_    4
#define TWO_N 10000
#define EP_   81920   // padded CSR capacity per (et,b): E + 4-aligned per-node pads

// edge types: (src,dst) node types = (0,0),(1,1),(0,1),(1,0)
// s_t = et & 1 ; d_t = ((et+1)>>1) & 1

__device__ __forceinline__ unsigned short f2bf(float f) {
    unsigned u = __float_as_uint(f);
    u += 0x7fffu + ((u >> 16) & 1u);   // RNE
    return (unsigned short)(u >> 16);
}
__device__ __forceinline__ float bf2f(unsigned short h) {
    return __uint_as_float(((unsigned)h) << 16);
}

typedef __attribute__((ext_vector_type(8))) short bfrag;   // 8 bf16
typedef __attribute__((ext_vector_type(4))) float ffrag;   // 4 fp32 acc

__device__ __forceinline__ void split8(const float* __restrict__ p, bfrag& hi, bfrag& lo) {
#pragma unroll
    for (int j = 0; j < 8; ++j) {
        float v = p[j];
        unsigned short h = f2bf(v);
        hi[j] = (short)h;
        lo[j] = (short)f2bf(v - bf2f(h));
    }
}

// Weight slots (each 128x128 = 16384 elements, B-fragment packed):
// 0-1: proj ; 2-5: Wj[et] ; 6-9: Wi[et] ; 10-13: W1[et] (agg rows 0-127) ;
// 14-17: W2[et] (agg rows 128-255) ; 18-19: klin[nt]
#define SLOT(i) ((size_t)(i) * 16384)

__device__ __forceinline__ void zero_acc(ffrag (&acc)[2][8]) {
#pragma unroll
    for (int h = 0; h < 2; ++h)
#pragma unroll
        for (int t = 0; t < 8; ++t) acc[h][t] = (ffrag){0.f, 0.f, 0.f, 0.f};
}

// Split-bf16 MFMA GEMM core, K=128, block=256 thr (4 waves x 32 rows), N=128.
// A: fp32 row-major [M][128], split to hi/lo bf16 in-register.
// W packed: [s<4][t<8][64 lanes][8] bf16 per hi/lo array.
__device__ __forceinline__ void mfma128(const float* __restrict__ A,
                                        const unsigned short* __restrict__ Whi,
                                        const unsigned short* __restrict__ Wlo,
                                        ffrag (&acc)[2][8])
{
    const int wave = threadIdx.x >> 6, lane = threadIdx.x & 63;
    const int mloc = lane & 15, quad = lane >> 4;
    const int row0w = blockIdx.x * 128 + wave * 32;
    int r0 = row0w + mloc;      if (r0 >= N_) r0 = N_ - 1;  // clamp, stores guarded
    int r1 = row0w + 16 + mloc; if (r1 >= N_) r1 = N_ - 1;
#pragma unroll
    for (int s = 0; s < 4; ++s) {
        bfrag a0h, a0l, a1h, a1l;
        split8(A + (size_t)r0 * C_ + s * 32 + quad * 8, a0h, a0l);
        split8(A + (size_t)r1 * C_ + s * 32 + quad * 8, a1h, a1l);
        const unsigned short* pBh = Whi + ((size_t)s * 512 + lane) * 8;
        const unsigned short* pBl = Wlo + ((size_t)s * 512 + lane) * 8;
#pragma unroll
        for (int t = 0; t < 8; ++t) {
            bfrag bh = *(const bfrag*)(pBh + (size_t)t * 512);
            bfrag bl = *(const bfrag*)(pBl + (size_t)t * 512);
            acc[0][t] = __builtin_amdgcn_mfma_f32_16x16x32_bf16(a0h, bh, acc[0][t], 0, 0, 0);
            acc[0][t] = __builtin_amdgcn_mfma_f32_16x16x32_bf16(a0l, bh, acc[0][t], 0, 0, 0);
            acc[0][t] = __builtin_amdgcn_mfma_f32_16x16x32_bf16(a0h, bl, acc[0][t], 0, 0, 0);
            acc[1][t] = __builtin_amdgcn_mfma_f32_16x16x32_bf16(a1h, bh, acc[1][t], 0, 0, 0);
            acc[1][t] = __builtin_amdgcn_mfma_f32_16x16x32_bf16(a1l, bh, acc[1][t], 0, 0, 0);
            acc[1][t] = __builtin_amdgcn_mfma_f32_16x16x32_bf16(a1h, bl, acc[1][t], 0, 0, 0);
        }
    }
}

// Pack weights into B-fragment layout, hi/lo bf16. grid (32, 20), 64 thr.
__global__ __launch_bounds__(64) void pack_w_kernel(const float* __restrict__ proj_w,
                                                    const float* __restrict__ att_w,
                                                    const float* __restrict__ agg_w,
                                                    const float* __restrict__ klin_w,
                                                    unsigned short* __restrict__ wh,
                                                    unsigned short* __restrict__ wl)
{
    int st = blockIdx.x;       // s*8 + t, s<4
    int s = st >> 3, t = st & 7;
    int id = blockIdx.y;       // slot 0..19
    const float* src;
    if (id < 2)       src = proj_w + (size_t)id * 16384;
    else if (id < 6)  src = att_w + (size_t)(id - 2) * 384 * C_;
    else if (id < 10) src = att_w + (size_t)(id - 6) * 384 * C_ + (size_t)128 * C_;
    else if (id < 14) src = agg_w + (size_t)(id - 10) * 256 * C_;
    else if (id < 18) src = agg_w + (size_t)(id - 14) * 256 * C_ + (size_t)128 * C_;
    else              src = klin_w + (size_t)(id - 18) * 16384;
    int lane = threadIdx.x, mloc = lane & 15, quad = lane >> 4;
    size_t dbase = SLOT(id) + ((size_t)(s * 8 + t) * 64 + lane) * 8;
#pragma unroll
    for (int j = 0; j < 8; ++j) {
        float v = src[(size_t)(s * 32 + quad * 8 + j) * C_ + t * 16 + mloc];
        unsigned short h = f2bf(v);
        wh[dbase + j] = h;
        wl[dbase + j] = f2bf(v - bf2f(h));
    }
}

// Pack lin_src/lin_dst into one 128x16 B tile (cols 0-3: nt=0, 4-7: nt=1, rest 0).
// col idx: 0=lin_src[nt], 1=lin_src[nt+2], 2=lin_dst[nt], 3=lin_dst[3-nt]
__global__ __launch_bounds__(64) void pack_L_kernel(const float* __restrict__ lin_src,
                                                    const float* __restrict__ lin_dst,
                                                    unsigned short* __restrict__ lph,
                                                    unsigned short* __restrict__ lpl)
{
    int s = blockIdx.x;  // 0..3
    int lane = threadIdx.x, mloc = lane & 15, quad = lane >> 4;
    const float* vec = nullptr;
    if (mloc < 8) {
        int nt = mloc >> 2, idx = mloc & 3;
        if (idx == 0)      vec = lin_src + nt * C_;
        else if (idx == 1) vec = lin_src + (nt + 2) * C_;
        else if (idx == 2) vec = lin_dst + nt * C_;
        else               vec = lin_dst + (3 - nt) * C_;
    }
    size_t dbase = ((size_t)(s * 64) + lane) * 8;
#pragma unroll
    for (int j = 0; j < 8; ++j) {
        float v = vec ? vec[s * 32 + quad * 8 + j] : 0.f;
        unsigned short h = f2bf(v);
        lph[dbase + j] = h;
        lpl[dbase + j] = f2bf(v - bf2f(h));
    }
}

// v1[et] = eproj_w[et] @ We ; bias_i[et] = att_b[et] + eproj_b[et] @ We
__global__ void prep_kernel(const float* __restrict__ eproj_w,
                            const float* __restrict__ eproj_b,
                            const float* __restrict__ att_w,
                            const float* __restrict__ att_b,
                            float* __restrict__ v1, float* __restrict__ bias_i)
{
    int et = blockIdx.x, c = threadIdx.x;
    float s1 = 0.f, s0 = 0.f;
    for (int k = 0; k < 128; ++k) {
        float wv = att_w[(size_t)et * 384 * C_ + (size_t)(256 + k) * C_ + c];
        s1 = fmaf(eproj_w[et * C_ + k], wv, s1);
        s0 = fmaf(eproj_b[et * C_ + k], wv, s0);
    }
    v1[et * C_ + c] = s1;
    bias_i[et * C_ + c] = att_b[et * C_ + c] + s0;
}

// xn = x @ proj_w + proj_b
__global__ __launch_bounds__(256) void proj_mfma(const float* __restrict__ x,
                                                 const unsigned short* __restrict__ wph,
                                                 const unsigned short* __restrict__ wpl,
                                                 const float* __restrict__ proj_b,
                                                 float* __restrict__ xn)
{
    int nt = blockIdx.y, b = blockIdx.z;
    const float* A = x + ((size_t)b * TWO_N + (size_t)nt * N_) * C_;
    ffrag acc[2][8];
    zero_acc(acc);
    mfma128(A, wph + SLOT(nt), wpl + SLOT(nt), acc);
    float* out = xn + (size_t)(b * 2 + nt) * N_ * C_;
    const float* bias = proj_b + nt * C_;
    const int wave = threadIdx.x >> 6, lane = threadIdx.x & 63;
    const int mloc = lane & 15, quad = lane >> 4;
    const int rbase = blockIdx.x * 128 + wave * 32 + quad * 4;
#pragma unroll
    for (int h = 0; h < 2; ++h)
#pragma unroll
        for (int r = 0; r < 4; ++r) {
            int row = rbase + h * 16 + r;
            if (row >= N_) continue;
#pragma unroll
            for (int t = 0; t < 8; ++t) {
                int col = t * 16 + mloc;
                out[(size_t)row * C_ + col] = acc[h][t][r] + bias[col];
            }
        }
}

// asrc/adst via MFMA against packed L tile. grid (40, 2, B), 256 thr.
__global__ __launch_bounds__(256) void nodedot_mfma(const float* __restrict__ xn,
                                                    const unsigned short* __restrict__ lph,
                                                    const unsigned short* __restrict__ lpl,
                                                    float* __restrict__ asrc,
                                                    float* __restrict__ adst)
{
    int nt = blockIdx.y, b = blockIdx.z;
    const float* A = xn + (size_t)(b * 2 + nt) * N_ * C_;
    const int wave = threadIdx.x >> 6, lane = threadIdx.x & 63;
    const int mloc = lane & 15, quad = lane >> 4;
    const int row0w = blockIdx.x * 128 + wave * 32;
    int r0 = row0w + mloc;      if (r0 >= N_) r0 = N_ - 1;
    int r1 = row0w + 16 + mloc; if (r1 >= N_) r1 = N_ - 1;
    ffrag acc0 = {0.f,0.f,0.f,0.f}, acc1 = {0.f,0.f,0.f,0.f};
#pragma unroll
    for (int s = 0; s < 4; ++s) {
        bfrag a0h, a0l, a1h, a1l;
        split8(A + (size_t)r0 * C_ + s * 32 + quad * 8, a0h, a0l);
        split8(A + (size_t)r1 * C_ + s * 32 + quad * 8, a1h, a1l);
        bfrag bh = *(const bfrag*)(lph + ((size_t)(s * 64) + lane) * 8);
        bfrag bl = *(const bfrag*)(lpl + ((size_t)(s * 64) + lane) * 8);
        acc0 = __builtin_amdgcn_mfma_f32_16x16x32_bf16(a0h, bh, acc0, 0, 0, 0);
        acc0 = __builtin_amdgcn_mfma_f32_16x16x32_bf16(a0l, bh, acc0, 0, 0, 0);
        acc0 = __builtin_amdgcn_mfma_f32_16x16x32_bf16(a0h, bl, acc0, 0, 0, 0);
        acc1 = __builtin_amdgcn_mfma_f32_16x16x32_bf16(a1h, bh, acc1, 0, 0, 0);
        acc1 = __builtin_amdgcn_mfma_f32_16x16x32_bf16(a1l, bh, acc1, 0, 0, 0);
        acc1 = __builtin_amdgcn_mfma_f32_16x16x32_bf16(a1h, bl, acc1, 0, 0, 0);
    }
    if (mloc < 8 && (mloc >> 2) == nt) {
        int idx = mloc & 3;
        int et = (idx == 0) ? nt : (idx == 1) ? nt + 2 : (idx == 2) ? nt : 3 - nt;
        float* base = ((idx < 2) ? asrc : adst) + (size_t)(b * T_ + et) * N_;
        const int rb = row0w + quad * 4;
#pragma unroll
        for (int r = 0; r < 4; ++r) {
            int row = rb + r;
            if (row < N_) base[row] = acc0[r];
            row = rb + 16 + r;
            if (row < N_) base[row] = acc1[r];
        }
    }
}

__global__ void count_kernel(const int* __restrict__ eidx, int* __restrict__ count)
{
    int e = blockIdx.x * blockDim.x + threadIdx.x;
    int et = blockIdx.y, b = blockIdx.z;
    int dst = eidx[(((size_t)et * B_ + b) * 2 + 1) * E_ + e];
    atomicAdd(&count[(size_t)(b * T_ + et) * N_ + dst], 1);
}

// Exclusive scan of 4-aligned strides -> CSR offsets.
__global__ __launch_bounds__(256) void scan_kernel(const int* __restrict__ count,
                                                   int* __restrict__ offs)
{
    int be = blockIdx.x;
    const int* cnt = count + (size_t)be * N_;
    int* off = offs + (size_t)be * (N_ + 1);
    __shared__ int sums[256];
    int tid = threadIdx.x;
    const int chunk = (N_ + 255) / 256;  // 20
    int lo = tid * chunk, hi = min(lo + chunk, N_);
    int s = 0;
    for (int i = lo; i < hi; ++i) s += (cnt[i] + 3) & ~3;
    sums[tid] = s;
    __syncthreads();
    for (int d = 1; d < 256; d <<= 1) {
        int v = (tid >= d) ? sums[tid - d] : 0;
        __syncthreads();
        sums[tid] += v;
        __syncthreads();
    }
    int run = (tid > 0) ? sums[tid - 1] : 0;
    for (int i = lo; i < hi; ++i) { off[i] = run; run += (cnt[i] + 3) & ~3; }
    if (tid == 255) off[N_] = sums[255];
}

// Scatter edges into padded CSR; precompute p = exp(leaky(asrc+adst)), q = p*ew.
__global__ void scatter_kernel(const int* __restrict__ eidx, const float* __restrict__ ew,
                               const float* __restrict__ asrc, const float* __restrict__ adst,
                               const int* __restrict__ offs, int* __restrict__ cursor,
                               int* __restrict__ ssrc, float* __restrict__ pw)
{
    int e = blockIdx.x * blockDim.x + threadIdx.x;
    int et = blockIdx.y, b = blockIdx.z;
    size_t ebase = ((size_t)et * B_ + b) * 2 * E_;
    int src = eidx[ebase + e];
    int dst = eidx[ebase + E_ + e];
    int be = b * T_ + et;
    float al = asrc[(size_t)be * N_ + src] + adst[(size_t)be * N_ + dst];
    al = (al > 0.f) ? al : 0.2f * al;
    float p = __expf(al);
    float w = ew[((size_t)et * B_ + b) * E_ + e];
    int pos = offs[(size_t)be * (N_ + 1) + dst] + atomicAdd(&cursor[(size_t)be * N_ + dst], 1);
    ssrc[(size_t)be * EP_ + pos] = src;
    float2* pwp = (float2*)pw;
    pwp[(size_t)be * EP_ + pos] = make_float2(p, p * w);
}

// yji: role 0 -> Z = xn[s_t]*(xn[s_t]@Wj) ; role 1 -> Yi = xn[d_t]@Wi + bias_i ;
//      role 2 -> P2 = xn[d_t]@W2 + agg_b.   grid (40, 12, B).
__global__ __launch_bounds__(256) void yji_mfma(const float* __restrict__ xn,
                                                const unsigned short* __restrict__ wph,
                                                const unsigned short* __restrict__ wpl,
                                                const float* __restrict__ bias_i,
                                                const float* __restrict__ agg_b,
                                                float* __restrict__ Z,
                                                float* __restrict__ Yi,
                                                float* __restrict__ P2)
{
    int m = blockIdx.y, b = blockIdx.z;
    int role = m >> 2, et = m & 3;
    int s_t = et & 1, d_t = ((et + 1) >> 1) & 1;
    int ntsel = (role == 0) ? s_t : d_t;
    const float* A = xn + (size_t)(b * 2 + ntsel) * N_ * C_;
    int slot = (role == 0) ? 2 + et : (role == 1) ? 6 + et : 14 + et;
    ffrag acc[2][8];
    zero_acc(acc);
    mfma128(A, wph + SLOT(slot), wpl + SLOT(slot), acc);
    size_t obase = (size_t)(b * T_ + et) * N_ * C_;
    float* out = (role == 0) ? Z + obase : (role == 1) ? Yi + obase : P2 + obase;
    const float* bias = (role == 1) ? bias_i + et * C_ : (role == 2) ? agg_b + et * C_ : nullptr;
    const int wave = threadIdx.x >> 6, lane = threadIdx.x & 63;
    const int mloc = lane & 15, quad = lane >> 4;
    const int rbase = blockIdx.x * 128 + wave * 32 + quad * 4;
#pragma unroll
    for (int h = 0; h < 2; ++h)
#pragma unroll
        for (int r = 0; r < 4; ++r) {
            int row = rbase + h * 16 + r;
            if (row >= N_) continue;
#pragma unroll
            for (int t = 0; t < 8; ++t) {
                int col = t * 16 + mloc;
                float v = acc[h][t][r];
                if (role == 0) v *= A[(size_t)row * C_ + col];
                else v += bias[col];
                out[(size_t)row * C_ + col] = v;
            }
        }
}

// Segment-softmax aggregation: one wave per (node, et, b), XCD-pinned by pair.
// aggr = (Σ p·Z[s] + Yi'⊙Σ p·xs + v1⊙Σ q·xs) / Σ p
__global__ __launch_bounds__(256) void aggregate_kernel(
    const float* __restrict__ Z, const float* __restrict__ xn,
    const float* __restrict__ Yi, const float* __restrict__ v1,
    const float* __restrict__ pw, const int* __restrict__ ssrc,
    const int* __restrict__ offs, float* __restrict__ aggr)
{
    int pair = blockIdx.x & 7;                       // = b*T_+et (XCD-pin)
    int n = (blockIdx.x >> 3) * 4 + (threadIdx.x >> 6);
    int b = pair >> 2, et = pair & 3;
    int be = pair;
    int s_t = et & 1;
    int l = threadIdx.x & 63;
    int col = l * 2;
    const float* Zp = Z + (size_t)be * N_ * C_;
    const float* xs = xn + (size_t)(b * 2 + s_t) * N_ * C_;
    int beg = offs[(size_t)be * (N_ + 1) + n];
    int end = offs[(size_t)be * (N_ + 1) + n + 1];
    const int* sp = ssrc + (size_t)be * EP_ + beg;
    const float* pwp = pw + ((size_t)be * EP_ + beg) * 2;
    float a1x = 0.f, a1y = 0.f, a2x = 0.f, a2y = 0.f, a3x = 0.f, a3y = 0.f, denom = 0.f;
    int cnt = end - beg;  // multiple of 4; pads have p=q=0, ssrc=0
    for (int i = 0; i < cnt; i += 4) {
        int4 ss = *(const int4*)(sp + i);
        float4 pq0 = *(const float4*)(pwp + 2 * i);      // p0 q0 p1 q1
        float4 pq1 = *(const float4*)(pwp + 2 * i + 4);  // p2 q2 p3 q3
        float2 z0 = *(const float2*)(Zp + (size_t)ss.x * C_ + col);
        float2 x0 = *(const float2*)(xs + (size_t)ss.x * C_ + col);
        float2 z1 = *(const float2*)(Zp + (size_t)ss.y * C_ + col);
        float2 x1 = *(const float2*)(xs + (size_t)ss.y * C_ + col);
        float2 z2 = *(const float2*)(Zp + (size_t)ss.z * C_ + col);
        float2 x2 = *(const float2*)(xs + (size_t)ss.z * C_ + col);
        float2 z3 = *(const float2*)(Zp + (size_t)ss.w * C_ + col);
        float2 x3 = *(const float2*)(xs + (size_t)ss.w * C_ + col);
        denom += pq0.x + pq0.z + pq1.x + pq1.z;
        a1x = fmaf(pq0.x, z0.x, a1x); a1y = fmaf(pq0.x, z0.y, a1y);
        a2x = fmaf(pq0.x, x0.x, a2x); a2y = fmaf(pq0.x, x0.y, a2y);
        a3x = fmaf(pq0.y, x0.x, a3x); a3y = fmaf(pq0.y, x0.y, a3y);
        a1x = fmaf(pq0.z, z1.x, a1x); a1y = fmaf(pq0.z, z1.y, a1y);
        a2x = fmaf(pq0.z, x1.x, a2x); a2y = fmaf(pq0.z, x1.y, a2y);
        a3x = fmaf(pq0.w, x1.x, a3x); a3y = fmaf(pq0.w, x1.y, a3y);
        a1x = fmaf(pq1.x, z2.x, a1x); a1y = fmaf(pq1.x, z2.y, a1y);
        a2x = fmaf(pq1.x, x2.x, a2x); a2y = fmaf(pq1.x, x2.y, a2y);
        a3x = fmaf(pq1.y, x2.x, a3x); a3y = fmaf(pq1.y, x2.y, a3y);
        a1x = fmaf(pq1.z, z3.x, a1x); a1y = fmaf(pq1.z, z3.y, a1y);
        a2x = fmaf(pq1.z, x3.x, a2x); a2y = fmaf(pq1.z, x3.y, a2y);
        a3x = fmaf(pq1.w, x3.x, a3x); a3y = fmaf(pq1.w, x3.y, a3y);
    }
    float2 yi = *(const float2*)(Yi + ((size_t)be * N_ + n) * C_ + col);
    float2 vv = *(const float2*)(v1 + et * C_ + col);
    float inv = (denom > 0.f) ? 1.f / denom : 0.f;
    float2 o;
    o.x = (a1x + yi.x * a2x + vv.x * a3x) * inv;
    o.y = (a1y + yi.y * a2y + vv.y * a3y) * inv;
    *(float2*)(aggr + ((size_t)be * N_ + n) * C_ + col) = o;
}

// outs = tanh(relu(aggr @ W1 + P2))   (P2 already holds xd@W2 + agg_b)
__global__ __launch_bounds__(256) void agg_mfma(const float* __restrict__ aggr,
                                                const unsigned short* __restrict__ wph,
                                                const unsigned short* __restrict__ wpl,
                                                const float* __restrict__ P2,
                                                float* __restrict__ outs)
{
    int et = blockIdx.y, b = blockIdx.z;
    size_t base = (size_t)(b * T_ + et) * N_ * C_;
    ffrag acc[2][8];
    zero_acc(acc);
    mfma128(aggr + base, wph + SLOT(10 + et), wpl + SLOT(10 + et), acc);
    const int wave = threadIdx.x >> 6, lane = threadIdx.x & 63;
    const int mloc = lane & 15, quad = lane >> 4;
    const int rbase = blockIdx.x * 128 + wave * 32 + quad * 4;
#pragma unroll
    for (int h = 0; h < 2; ++h)
#pragma unroll
        for (int r = 0; r < 4; ++r) {
            int row = rbase + h * 16 + r;
            if (row >= N_) continue;
#pragma unroll
            for (int t = 0; t < 8; ++t) {
                int col = t * 16 + mloc;
                float v = acc[h][t][r] + P2[base + (size_t)row * C_ + col];
                v = (v > 0.f) ? tanhf(v) : 0.f;
                outs[base + (size_t)row * C_ + col] = v;
            }
        }
}

// colsum[b][nt][tt] += Σ_n tanh(outs[et] @ klin[nt] + klin_b[nt])
__global__ __launch_bounds__(256) void klin_mfma(const float* __restrict__ outs,
                                                 const unsigned short* __restrict__ wph,
                                                 const unsigned short* __restrict__ wpl,
                                                 const float* __restrict__ klin_b,
                                                 float* __restrict__ colsum)
{
    int g = blockIdx.y, b = blockIdx.z;
    int nt = g >> 1, tt = g & 1;
    int et = (tt == 0) ? nt : 3 - nt;
    size_t abase = (size_t)(b * T_ + et) * N_ * C_;
    ffrag acc[2][8];
    zero_acc(acc);
    mfma128(outs + abase, wph + SLOT(18 + nt), wpl + SLOT(18 + nt), acc);
    __shared__ float cs[128];
    if (threadIdx.x < 128) cs[threadIdx.x] = 0.f;
    __syncthreads();
    const int wave = threadIdx.x >> 6, lane = threadIdx.x & 63;
    const int mloc = lane & 15, quad = lane >> 4;
    const int rbase = blockIdx.x * 128 + wave * 32 + quad * 4;
#pragma unroll
    for (int t = 0; t < 8; ++t) {
        int col = t * 16 + mloc;
        float bv = klin_b[nt * C_ + col];
        float s = 0.f;
#pragma unroll
        for (int h = 0; h < 2; ++h)
#pragma unroll
            for (int r = 0; r < 4; ++r) {
                int row = rbase + h * 16 + r;
                if (row < N_) s += tanhf(acc[h][t][r] + bv);
            }
        atomicAdd(&cs[col], s);
    }
    __syncthreads();
    if (threadIdx.x < 128)
        atomicAdd(&colsum[(size_t)((b * 2 + nt) * 2 + tt) * C_ + threadIdx.x], cs[threadIdx.x]);
}

__global__ __launch_bounds__(128) void score_kernel(const float* __restrict__ colsum,
                                                    const float* __restrict__ q,
                                                    float* __restrict__ attn)
{
    int bnt = blockIdx.x;
    int nt = bnt & 1;
    int c = threadIdx.x;
    __shared__ float r0[128], r1[128];
    float qc = q[nt * C_ + c];
    r0[c] = qc * colsum[(size_t)(bnt * 2 + 0) * C_ + c];
    r1[c] = qc * colsum[(size_t)(bnt * 2 + 1) * C_ + c];
    __syncthreads();
    for (int s = 64; s > 0; s >>= 1) {
        if (c < s) { r0[c] += r0[c + s]; r1[c] += r1[c + s]; }
        __syncthreads();
    }
    if (c == 0) {
        float s0 = r0[0] / (float)N_, s1 = r1[0] / (float)N_;
        float mx = fmaxf(s0, s1);
        float e0 = __expf(s0 - mx), e1 = __expf(s1 - mx);
        float inv = 1.f / (e0 + e1);
        attn[bnt * 2 + 0] = e0 * inv;
        attn[bnt * 2 + 1] = e1 * inv;
    }
}

__global__ void output_kernel(const float* __restrict__ outs,
                              const float* __restrict__ attn,
                              float* __restrict__ out)
{
    int idx = blockIdx.x * blockDim.x + threadIdx.x;
    int c4 = idx & 31;
    int row = idx >> 5;
    int b = row / TWO_N;
    int r = row % TWO_N;
    int nt = (r >= N_) ? 1 : 0;
    int n = r - nt * N_;
    int et0 = nt, et1 = 3 - nt;
    float a0 = attn[(b * 2 + nt) * 2 + 0];
    float a1 = attn[(b * 2 + nt) * 2 + 1];
    const float4* o0 = (const float4*)(outs + ((size_t)(b * T_ + et0) * N_ + n) * C_);
    const float4* o1 = (const float4*)(outs + ((size_t)(b * T_ + et1) * N_ + n) * C_);
    float4 v0 = o0[c4], v1 = o1[c4], o;
    o.x = a0 * v0.x + a1 * v1.x;
    o.y = a0 * v0.y + a1 * v1.y;
    o.z = a0 * v0.z + a1 * v1.z;
    o.w = a0 * v0.w + a1 * v1.w;
    ((float4*)out)[idx] = o;
}

extern "C" void kernel_launch(void* const* d_in, const int* in_sizes, int n_in,
                              void* d_out, int out_size, void* d_ws, size_t ws_size,
                              hipStream_t stream)
{
    const float* x       = (const float*)d_in[0];
    const int*   eidx    = (const int*)d_in[1];
    const float* ew      = (const float*)d_in[2];
    const float* proj_w  = (const float*)d_in[3];
    const float* proj_b  = (const float*)d_in[4];
    const float* q       = (const float*)d_in[5];
    const float* klin_w  = (const float*)d_in[6];
    const float* klin_b  = (const float*)d_in[7];
    const float* lin_src = (const float*)d_in[8];
    const float* lin_dst = (const float*)d_in[9];
    const float* eproj_w = (const float*)d_in[10];
    const float* eproj_b = (const float*)d_in[11];
    const float* agg_w   = (const float*)d_in[12];
    const float* agg_b   = (const float*)d_in[13];
    const float* att_w   = (const float*)d_in[14];
    const float* att_b   = (const float*)d_in[15];

    float* ws = (float*)d_ws;
    size_t o = 0;
    float* xn     = ws + o; o += 2560000;   // live proj -> aggregate
    float* U1     = ws + o; o += 5120000;   // Z (yji->aggregate)  ∪  outs (agg_mfma->output)
    float* Yi     = ws + o; o += 5120000;
    float* P2     = ws + o; o += 5120000;
    float* aggr   = ws + o; o += 5120000;
    float* pw     = ws + o; o += 2 * 8 * EP_;      // 1,310,720  (zeroed)
    int*   ssrc   = (int*)(ws + o); o += 8 * EP_;  //   655,360  (zeroed, contiguous w/ pw)
    float* asrc   = ws + o; o += 40000;
    float* adst   = ws + o; o += 40000;
    float* v1     = ws + o; o += 512;
    float* bias_i = ws + o; o += 512;
    float* attn   = ws + o; o += 16;
    int*   count  = (int*)(ws + o); o += 40000;    // zeroed block start
    int*   cursor = (int*)(ws + o); o += 40000;
    float* colsum = ws + o; o += 1024;
    int*   offs   = (int*)(ws + o); o += 40008;
    unsigned short* wph = (unsigned short*)(ws + o); o += 163840;
    unsigned short* wpl = (unsigned short*)(ws + o); o += 163840;
    unsigned short* lph = (unsigned short*)(ws + o); o += 1024;
    unsigned short* lpl = (unsigned short*)(ws + o); o += 1024;
    // total ≈ 25.54M floats ≈ 102 MB

    float* Z    = U1;
    float* outs = U1;

    hipMemsetAsync(pw, 0, (size_t)(2 * 8 * EP_ + 8 * EP_) * 4, stream);
    hipMemsetAsync(count, 0, (size_t)(40000 + 40000 + 1024) * 4, stream);

    prep_kernel<<<dim3(T_), 128, 0, stream>>>(eproj_w, eproj_b, att_w, att_b, v1, bias_i);
    pack_w_kernel<<<dim3(32, 20), 64, 0, stream>>>(proj_w, att_w, agg_w, klin_w, wph, wpl);
    pack_L_kernel<<<dim3(4), 64, 0, stream>>>(lin_src, lin_dst, lph, lpl);

    proj_mfma<<<dim3(40, 2, B_), 256, 0, stream>>>(x, wph, wpl, proj_b, xn);
    nodedot_mfma<<<dim3(40, 2, B_), 256, 0, stream>>>(xn, lph, lpl, asrc, adst);
    count_kernel<<<dim3(E_ / 256, T_, B_), 256, 0, stream>>>(eidx, count);
    scan_kernel<<<dim3(B_ * T_), 256, 0, stream>>>(count, offs);
    scatter_kernel<<<dim3(E_ / 256, T_, B_), 256, 0, stream>>>(eidx, ew, asrc, adst,
                                                               offs, cursor, ssrc, pw);
    yji_mfma<<<dim3(40, 12, B_), 256, 0, stream>>>(xn, wph, wpl, bias_i, agg_b, Z, Yi, P2);
    aggregate_kernel<<<dim3(10000), 256, 0, stream>>>(Z, xn, Yi, v1, pw, ssrc, offs, aggr);
    agg_mfma<<<dim3(40, T_, B_), 256, 0, stream>>>(aggr, wph, wpl, P2, outs);
    klin_mfma<<<dim3(40, 4, B_), 256, 0, stream>>>(outs, wph, wpl, klin_b, colsum);
    score_kernel<<<dim3(B_ * 2), 128, 0, stream>>>(colsum, q, attn);
    output_kernel<<<dim3(2500), 256, 0, stream>>>(outs, attn, (float*)d_out);
}

// Round 6
// 336.158 us; speedup vs baseline: 1.5516x; 1.0730x over previous
//
#include <hip/hip_runtime.h>
#include <math.h>

// Problem constants (from reference setup_inputs)
#define B_    2
#define N_    5000
#define C_    128
#define E_    65536
#define T_    4
#define TWO_N 10000
#define EP_   81920   // padded CSR capacity per (et,b)

// edge types: (src,dst) node types = (0,0),(1,1),(0,1),(1,0)
// s_t = et & 1 ; d_t = ((et+1)>>1) & 1

__device__ __forceinline__ unsigned short f2bf(float f) {
    unsigned u = __float_as_uint(f);
    u += 0x7fffu + ((u >> 16) & 1u);   // RNE
    return (unsigned short)(u >> 16);
}
__device__ __forceinline__ float bf2f(unsigned short h) {
    return __uint_as_float(((unsigned)h) << 16);
}

typedef __attribute__((ext_vector_type(8))) short bfrag;   // 8 bf16
typedef __attribute__((ext_vector_type(4))) float ffrag;   // 4 fp32 acc

__device__ __forceinline__ void split8(const float* __restrict__ p, bfrag& hi, bfrag& lo) {
#pragma unroll
    for (int j = 0; j < 8; ++j) {
        float v = p[j];
        unsigned short h = f2bf(v);
        hi[j] = (short)h;
        lo[j] = (short)f2bf(v - bf2f(h));
    }
}

// Weight slots (each 128x128, B-fragment packed):
// 0-1: proj ; 2-5: Wj[et] ; 6-9: Wi[et] ; 10-13: W1[et] ; 14-17: W2[et] ; 18-19: klin[nt]
#define SLOT(i) ((size_t)(i) * 16384)

__device__ __forceinline__ void zero_acc(ffrag (&acc)[2][8]) {
#pragma unroll
    for (int h = 0; h < 2; ++h)
#pragma unroll
        for (int t = 0; t < 8; ++t) acc[h][t] = (ffrag){0.f, 0.f, 0.f, 0.f};
}

// Split-bf16 MFMA GEMM core, K=128, 4 waves x 32 rows, N=128. fp32 A.
__device__ __forceinline__ void mfma128(const float* __restrict__ A,
                                        const unsigned short* __restrict__ Whi,
                                        const unsigned short* __restrict__ Wlo,
                                        ffrag (&acc)[2][8], int bx)
{
    const int wave = threadIdx.x >> 6, lane = threadIdx.x & 63;
    const int mloc = lane & 15, quad = lane >> 4;
    const int row0w = bx * 128 + wave * 32;
    int r0 = row0w + mloc;      if (r0 >= N_) r0 = N_ - 1;  // clamp, stores guarded
    int r1 = row0w + 16 + mloc; if (r1 >= N_) r1 = N_ - 1;
#pragma unroll
    for (int s = 0; s < 4; ++s) {
        bfrag a0h, a0l, a1h, a1l;
        split8(A + (size_t)r0 * C_ + s * 32 + quad * 8, a0h, a0l);
        split8(A + (size_t)r1 * C_ + s * 32 + quad * 8, a1h, a1l);
        const unsigned short* pBh = Whi + ((size_t)s * 512 + lane) * 8;
        const unsigned short* pBl = Wlo + ((size_t)s * 512 + lane) * 8;
#pragma unroll
        for (int t = 0; t < 8; ++t) {
            bfrag bh = *(const bfrag*)(pBh + (size_t)t * 512);
            bfrag bl = *(const bfrag*)(pBl + (size_t)t * 512);
            acc[0][t] = __builtin_amdgcn_mfma_f32_16x16x32_bf16(a0h, bh, acc[0][t], 0, 0, 0);
            acc[0][t] = __builtin_amdgcn_mfma_f32_16x16x32_bf16(a0l, bh, acc[0][t], 0, 0, 0);
            acc[0][t] = __builtin_amdgcn_mfma_f32_16x16x32_bf16(a0h, bl, acc[0][t], 0, 0, 0);
            acc[1][t] = __builtin_amdgcn_mfma_f32_16x16x32_bf16(a1h, bh, acc[1][t], 0, 0, 0);
            acc[1][t] = __builtin_amdgcn_mfma_f32_16x16x32_bf16(a1l, bh, acc[1][t], 0, 0, 0);
            acc[1][t] = __builtin_amdgcn_mfma_f32_16x16x32_bf16(a1h, bl, acc[1][t], 0, 0, 0);
        }
    }
}

// Same core but A is bf16 (single, no split): D = A @ (Wh + Wl).
__device__ __forceinline__ void mfma128_bfA(const unsigned short* __restrict__ A,
                                            const unsigned short* __restrict__ Whi,
                                            const unsigned short* __restrict__ Wlo,
                                            ffrag (&acc)[2][8], int bx)
{
    const int wave = threadIdx.x >> 6, lane = threadIdx.x & 63;
    const int mloc = lane & 15, quad = lane >> 4;
    const int row0w = bx * 128 + wave * 32;
    int r0 = row0w + mloc;      if (r0 >= N_) r0 = N_ - 1;
    int r1 = row0w + 16 + mloc; if (r1 >= N_) r1 = N_ - 1;
#pragma unroll
    for (int s = 0; s < 4; ++s) {
        bfrag a0 = *(const bfrag*)(A + (size_t)r0 * C_ + s * 32 + quad * 8);
        bfrag a1 = *(const bfrag*)(A + (size_t)r1 * C_ + s * 32 + quad * 8);
        const unsigned short* pBh = Whi + ((size_t)s * 512 + lane) * 8;
        const unsigned short* pBl = Wlo + ((size_t)s * 512 + lane) * 8;
#pragma unroll
        for (int t = 0; t < 8; ++t) {
            bfrag bh = *(const bfrag*)(pBh + (size_t)t * 512);
            bfrag bl = *(const bfrag*)(pBl + (size_t)t * 512);
            acc[0][t] = __builtin_amdgcn_mfma_f32_16x16x32_bf16(a0, bh, acc[0][t], 0, 0, 0);
            acc[0][t] = __builtin_amdgcn_mfma_f32_16x16x32_bf16(a0, bl, acc[0][t], 0, 0, 0);
            acc[1][t] = __builtin_amdgcn_mfma_f32_16x16x32_bf16(a1, bh, acc[1][t], 0, 0, 0);
            acc[1][t] = __builtin_amdgcn_mfma_f32_16x16x32_bf16(a1, bl, acc[1][t], 0, 0, 0);
        }
    }
}

#define ZN_ 81028   // count(40000) + cursor(40000) + colsum(1024) + done(4)

// setup: blocks [0,160) pack_w ; [160] pack_L ; [161,163) prep ; [163,243) zero
__global__ __launch_bounds__(256) void setup_kernel(
    const float* __restrict__ proj_w, const float* __restrict__ att_w,
    const float* __restrict__ agg_w, const float* __restrict__ klin_w,
    const float* __restrict__ lin_src, const float* __restrict__ lin_dst,
    const float* __restrict__ eproj_w, const float* __restrict__ eproj_b,
    const float* __restrict__ att_b,
    unsigned short* __restrict__ wh, unsigned short* __restrict__ wl,
    unsigned short* __restrict__ lph, unsigned short* __restrict__ lpl,
    float* __restrict__ v1, float* __restrict__ bias_i, int* __restrict__ zbase)
{
    int blk = blockIdx.x;
    if (blk < 160) {
        int wave = threadIdx.x >> 6, lane = threadIdx.x & 63;
        int unit = blk * 4 + wave;      // 0..639
        int id = unit >> 5;             // slot 0..19
        int st = unit & 31;
        int s = st >> 3, t = st & 7;
        const float* src;
        if (id < 2)       src = proj_w + (size_t)id * 16384;
        else if (id < 6)  src = att_w + (size_t)(id - 2) * 384 * C_;
        else if (id < 10) src = att_w + (size_t)(id - 6) * 384 * C_ + (size_t)128 * C_;
        else if (id < 14) src = agg_w + (size_t)(id - 10) * 256 * C_;
        else if (id < 18) src = agg_w + (size_t)(id - 14) * 256 * C_ + (size_t)128 * C_;
        else              src = klin_w + (size_t)(id - 18) * 16384;
        int mloc = lane & 15, quad = lane >> 4;
        size_t dbase = SLOT(id) + ((size_t)(s * 8 + t) * 64 + lane) * 8;
#pragma unroll
        for (int j = 0; j < 8; ++j) {
            float v = src[(size_t)(s * 32 + quad * 8 + j) * C_ + t * 16 + mloc];
            unsigned short h = f2bf(v);
            wh[dbase + j] = h;
            wl[dbase + j] = f2bf(v - bf2f(h));
        }
    } else if (blk == 160) {
        int s = threadIdx.x >> 6;       // wave = s (0..3)
        int lane = threadIdx.x & 63;
        int mloc = lane & 15, quad = lane >> 4;
        const float* vec = nullptr;
        if (mloc < 8) {
            int nt = mloc >> 2, idx = mloc & 3;
            if (idx == 0)      vec = lin_src + nt * C_;
            else if (idx == 1) vec = lin_src + (nt + 2) * C_;
            else if (idx == 2) vec = lin_dst + nt * C_;
            else               vec = lin_dst + (3 - nt) * C_;
        }
        size_t dbase = ((size_t)(s * 64) + lane) * 8;
#pragma unroll
        for (int j = 0; j < 8; ++j) {
            float v = vec ? vec[s * 32 + quad * 8 + j] : 0.f;
            unsigned short h = f2bf(v);
            lph[dbase + j] = h;
            lpl[dbase + j] = f2bf(v - bf2f(h));
        }
    } else if (blk < 163) {
        int et = (blk - 161) * 2 + (threadIdx.x >> 7);
        int c = threadIdx.x & 127;
        float s1 = 0.f, s0 = 0.f;
        for (int k = 0; k < 128; ++k) {
            float wv = att_w[(size_t)et * 384 * C_ + (size_t)(256 + k) * C_ + c];
            s1 = fmaf(eproj_w[et * C_ + k], wv, s1);
            s0 = fmaf(eproj_b[et * C_ + k], wv, s0);
        }
        v1[et * C_ + c] = s1;
        bias_i[et * C_ + c] = att_b[et * C_ + c] + s0;
    } else {
        int base = (blk - 163) * 1024 + threadIdx.x * 4;
#pragma unroll
        for (int j = 0; j < 4; ++j)
            if (base + j < ZN_) zbase[base + j] = 0;
    }
}

// count + proj(+nodedot) hybrid: blocks [0,2048) count ; [2048,2208) proj
__global__ __launch_bounds__(256) void cp_kernel(
    const int* __restrict__ eidx, int* __restrict__ count,
    const float* __restrict__ x,
    const unsigned short* __restrict__ wph, const unsigned short* __restrict__ wpl,
    const float* __restrict__ proj_b,
    const float* __restrict__ lin_src, const float* __restrict__ lin_dst,
    float* __restrict__ xn, float* __restrict__ asrc, float* __restrict__ adst)
{
    int blk = blockIdx.x;
    if (blk < 2048) {
        int eb = blk >> 8;            // 0..7
        int et = eb >> 1, b = eb & 1;
        int e = (blk & 255) * 256 + threadIdx.x;
        int dst = eidx[(((size_t)et * B_ + b) * 2 + 1) * E_ + e];
        atomicAdd(&count[(size_t)(b * T_ + et) * N_ + dst], 1);
        return;
    }
    int pidx = blk - 2048;            // 0..159
    int bx = pidx % 40;
    int nt = (pidx / 40) & 1;
    int b = pidx / 80;
    const float* A = x + ((size_t)b * TWO_N + (size_t)nt * N_) * C_;
    ffrag acc[2][8];
    zero_acc(acc);
    mfma128(A, wph + SLOT(nt), wpl + SLOT(nt), acc, bx);
    float* out = xn + (size_t)(b * 2 + nt) * N_ * C_;
    const float* bias = proj_b + nt * C_;
    const int wave = threadIdx.x >> 6, lane = threadIdx.x & 63;
    const int mloc = lane & 15, quad = lane >> 4;
    const int rbase = bx * 128 + wave * 32 + quad * 4;
    // lin columns for the fused nodedot
    const float* lv0 = lin_src + nt * C_;
    const float* lv1 = lin_src + (2 + nt) * C_;
    const float* lv2 = lin_dst + nt * C_;
    const float* lv3 = lin_dst + (3 - nt) * C_;
    float linv[4][8];
#pragma unroll
    for (int t = 0; t < 8; ++t) {
        int col = t * 16 + mloc;
        linv[0][t] = lv0[col]; linv[1][t] = lv1[col];
        linv[2][t] = lv2[col]; linv[3][t] = lv3[col];
    }
    const int et0 = nt, et1 = 2 + nt, et2 = nt, et3 = 3 - nt;
#pragma unroll
    for (int h = 0; h < 2; ++h)
#pragma unroll
        for (int r = 0; r < 4; ++r) {
            int row = rbase + h * 16 + r;
            bool ok = (row < N_);
            float p0 = 0.f, p1 = 0.f, p2 = 0.f, p3 = 0.f;
#pragma unroll
            for (int t = 0; t < 8; ++t) {
                int col = t * 16 + mloc;
                float vv = acc[h][t][r] + bias[col];
                if (ok) out[(size_t)row * C_ + col] = vv;
                p0 = fmaf(vv, linv[0][t], p0);
                p1 = fmaf(vv, linv[1][t], p1);
                p2 = fmaf(vv, linv[2][t], p2);
                p3 = fmaf(vv, linv[3][t], p3);
            }
#pragma unroll
            for (int m = 1; m < 16; m <<= 1) {
                p0 += __shfl_xor(p0, m);
                p1 += __shfl_xor(p1, m);
                p2 += __shfl_xor(p2, m);
                p3 += __shfl_xor(p3, m);
            }
            if (mloc == 0 && ok) {
                asrc[(size_t)(b * T_ + et0) * N_ + row] = p0;
                asrc[(size_t)(b * T_ + et1) * N_ + row] = p1;
                adst[(size_t)(b * T_ + et2) * N_ + row] = p2;
                adst[(size_t)(b * T_ + et3) * N_ + row] = p3;
            }
        }
}

// Exclusive scan of 4-aligned strides -> CSR offsets; zero pad slots.
__global__ __launch_bounds__(256) void scan_kernel(const int* __restrict__ count,
                                                   int* __restrict__ offs,
                                                   int* __restrict__ ssrc,
                                                   float* __restrict__ pw)
{
    int be = blockIdx.x;
    const int* cnt = count + (size_t)be * N_;
    int* off = offs + (size_t)be * (N_ + 1);
    __shared__ int sums[256];
    int tid = threadIdx.x;
    const int chunk = (N_ + 255) / 256;  // 20
    int lo = tid * chunk, hi = min(lo + chunk, N_);
    int s = 0;
    for (int i = lo; i < hi; ++i) s += (cnt[i] + 3) & ~3;
    sums[tid] = s;
    __syncthreads();
    for (int d = 1; d < 256; d <<= 1) {
        int v = (tid >= d) ? sums[tid - d] : 0;
        __syncthreads();
        sums[tid] += v;
        __syncthreads();
    }
    int run = (tid > 0) ? sums[tid - 1] : 0;
    float2* pwp = (float2*)pw;
    for (int i = lo; i < hi; ++i) {
        off[i] = run;
        int c = cnt[i], pc = (c + 3) & ~3;
        for (int k = c; k < pc; ++k) {
            int pos = run + k;
            ssrc[(size_t)be * EP_ + pos] = 0;
            pwp[(size_t)be * EP_ + pos] = make_float2(0.f, 0.f);
        }
        run += pc;
    }
    if (tid == 255) off[N_] = sums[255];
}

// scatter + yji hybrid: blocks [0,2048) scatter ; [2048,3008) yji
// yji roles: 0 -> G = interleaved bf16 {Z=xs*(xs@Wj), xs} ; 1 -> Yi ; 2 -> P2
__global__ __launch_bounds__(256) void sy_kernel(
    const int* __restrict__ eidx, const float* __restrict__ ew,
    const float* __restrict__ asrc, const float* __restrict__ adst,
    const int* __restrict__ offs, int* __restrict__ cursor,
    int* __restrict__ ssrc, float* __restrict__ pw,
    const float* __restrict__ xn,
    const unsigned short* __restrict__ wph, const unsigned short* __restrict__ wpl,
    const float* __restrict__ bias_i, const float* __restrict__ agg_b,
    unsigned short* __restrict__ G, float* __restrict__ Yi, float* __restrict__ P2)
{
    int blk = blockIdx.x;
    if (blk < 2048) {
        int eb = blk >> 8;
        int et = eb >> 1, b = eb & 1;
        int e = (blk & 255) * 256 + threadIdx.x;
        size_t ebase = ((size_t)et * B_ + b) * 2 * E_;
        int src = eidx[ebase + e];
        int dst = eidx[ebase + E_ + e];
        int be = b * T_ + et;
        float al = asrc[(size_t)be * N_ + src] + adst[(size_t)be * N_ + dst];
        al = (al > 0.f) ? al : 0.2f * al;
        float p = __expf(al);
        float w = ew[((size_t)et * B_ + b) * E_ + e];
        int pos = offs[(size_t)be * (N_ + 1) + dst] +
                  atomicAdd(&cursor[(size_t)be * N_ + dst], 1);
        ssrc[(size_t)be * EP_ + pos] = src;
        ((float2*)pw)[(size_t)be * EP_ + pos] = make_float2(p, p * w);
        return;
    }
    int yidx = blk - 2048;            // 0..959
    int bx = yidx % 40;
    int m = (yidx / 40) % 12;
    int b = yidx / 480;               // 0..1
    int role = m >> 2, et = m & 3;
    int s_t = et & 1, d_t = ((et + 1) >> 1) & 1;
    int ntsel = (role == 0) ? s_t : d_t;
    const float* A = xn + (size_t)(b * 2 + ntsel) * N_ * C_;
    int slot = (role == 0) ? 2 + et : (role == 1) ? 6 + et : 14 + et;
    ffrag acc[2][8];
    zero_acc(acc);
    mfma128(A, wph + SLOT(slot), wpl + SLOT(slot), acc, bx);
    int be = b * T_ + et;
    const float* bias = (role == 1) ? bias_i + et * C_ : agg_b + et * C_;
    const int wave = threadIdx.x >> 6, lane = threadIdx.x & 63;
    const int mloc = lane & 15, quad = lane >> 4;
    const int rbase = bx * 128 + wave * 32 + quad * 4;
#pragma unroll
    for (int h = 0; h < 2; ++h)
#pragma unroll
        for (int r = 0; r < 4; ++r) {
            int row = rbase + h * 16 + r;
            if (row >= N_) continue;
#pragma unroll
            for (int t = 0; t < 8; ++t) {
                int col = t * 16 + mloc;
                float v = acc[h][t][r];
                if (role == 0) {
                    float xv = A[(size_t)row * C_ + col];
                    unsigned short zh = f2bf(v * xv);
                    unsigned short xh = f2bf(xv);
                    *(ushort2*)(G + ((size_t)be * N_ + row) * 256 + 2 * col) =
                        make_ushort2(zh, xh);
                } else if (role == 1) {
                    Yi[((size_t)be * N_ + row) * C_ + col] = v + bias[col];
                } else {
                    P2[((size_t)be * N_ + row) * C_ + col] = v + bias[col];
                }
            }
        }
}

// Segment-softmax aggregation, one wave per (node, et, b), XCD-pinned by pair.
// aggr = (Σ p·Z[s] + Yi'⊙Σ p·xs + v1⊙Σ q·xs) / Σ p, emitted as bf16.
__global__ __launch_bounds__(256) void aggregate_kernel(
    const unsigned short* __restrict__ G, const float* __restrict__ Yi,
    const float* __restrict__ v1, const float* __restrict__ pw,
    const int* __restrict__ ssrc, const int* __restrict__ offs,
    unsigned short* __restrict__ aggrB)
{
    int pair = blockIdx.x & 7;                       // = b*T_+et (XCD-pin)
    int n = (blockIdx.x >> 3) * 4 + (threadIdx.x >> 6);
    int et = pair & 3;
    int be = pair;
    int l = threadIdx.x & 63;
    const unsigned short* Gp = G + (size_t)be * N_ * 256;
    int beg = offs[(size_t)be * (N_ + 1) + n];
    int end = offs[(size_t)be * (N_ + 1) + n + 1];
    const int* sp = ssrc + (size_t)be * EP_ + beg;
    const float* pwp = pw + ((size_t)be * EP_ + beg) * 2;
    float a1x = 0.f, a1y = 0.f, a2x = 0.f, a2y = 0.f, a3x = 0.f, a3y = 0.f, denom = 0.f;
    int cnt = end - beg;  // multiple of 4; pads have p=q=0, ssrc=0
    for (int i = 0; i < cnt; i += 4) {
        int4 ss = *(const int4*)(sp + i);
        float4 pq0 = *(const float4*)(pwp + 2 * i);      // p0 q0 p1 q1
        float4 pq1 = *(const float4*)(pwp + 2 * i + 4);  // p2 q2 p3 q3
        ushort4 g0 = *(const ushort4*)(Gp + (size_t)ss.x * 256 + 4 * l);
        ushort4 g1 = *(const ushort4*)(Gp + (size_t)ss.y * 256 + 4 * l);
        ushort4 g2 = *(const ushort4*)(Gp + (size_t)ss.z * 256 + 4 * l);
        ushort4 g3 = *(const ushort4*)(Gp + (size_t)ss.w * 256 + 4 * l);
        denom += pq0.x + pq0.z + pq1.x + pq1.z;
        a1x = fmaf(pq0.x, bf2f(g0.x), a1x); a2x = fmaf(pq0.x, bf2f(g0.y), a2x);
        a3x = fmaf(pq0.y, bf2f(g0.y), a3x);
        a1y = fmaf(pq0.x, bf2f(g0.z), a1y); a2y = fmaf(pq0.x, bf2f(g0.w), a2y);
        a3y = fmaf(pq0.y, bf2f(g0.w), a3y);
        a1x = fmaf(pq0.z, bf2f(g1.x), a1x); a2x = fmaf(pq0.z, bf2f(g1.y), a2x);
        a3x = fmaf(pq0.w, bf2f(g1.y), a3x);
        a1y = fmaf(pq0.z, bf2f(g1.z), a1y); a2y = fmaf(pq0.z, bf2f(g1.w), a2y);
        a3y = fmaf(pq0.w, bf2f(g1.w), a3y);
        a1x = fmaf(pq1.x, bf2f(g2.x), a1x); a2x = fmaf(pq1.x, bf2f(g2.y), a2x);
        a3x = fmaf(pq1.y, bf2f(g2.y), a3x);
        a1y = fmaf(pq1.x, bf2f(g2.z), a1y); a2y = fmaf(pq1.x, bf2f(g2.w), a2y);
        a3y = fmaf(pq1.y, bf2f(g2.w), a3y);
        a1x = fmaf(pq1.z, bf2f(g3.x), a1x); a2x = fmaf(pq1.z, bf2f(g3.y), a2x);
        a3x = fmaf(pq1.w, bf2f(g3.y), a3x);
        a1y = fmaf(pq1.z, bf2f(g3.z), a1y); a2y = fmaf(pq1.z, bf2f(g3.w), a2y);
        a3y = fmaf(pq1.w, bf2f(g3.w), a3y);
    }
    float2 yi = *(const float2*)(Yi + ((size_t)be * N_ + n) * C_ + 2 * l);
    float2 vv = *(const float2*)(v1 + et * C_ + 2 * l);
    float inv = (denom > 0.f) ? 1.f / denom : 0.f;
    float ox = (a1x + yi.x * a2x + vv.x * a3x) * inv;
    float oy = (a1y + yi.y * a2y + vv.y * a3y) * inv;
    *(ushort2*)(aggrB + ((size_t)be * N_ + n) * C_ + 2 * l) = make_ushort2(f2bf(ox), f2bf(oy));
}

// outs = tanh(relu(aggr @ W1 + P2))   (P2 already holds xd@W2 + agg_b)
__global__ __launch_bounds__(256) void agg_mfma(const unsigned short* __restrict__ aggrB,
                                                const unsigned short* __restrict__ wph,
                                                const unsigned short* __restrict__ wpl,
                                                const float* __restrict__ P2,
                                                float* __restrict__ outs)
{
    int et = blockIdx.y, b = blockIdx.z;
    int bx = blockIdx.x;
    size_t base = (size_t)(b * T_ + et) * N_ * C_;
    ffrag acc[2][8];
    zero_acc(acc);
    mfma128_bfA(aggrB + base, wph + SLOT(10 + et), wpl + SLOT(10 + et), acc, bx);
    const int wave = threadIdx.x >> 6, lane = threadIdx.x & 63;
    const int mloc = lane & 15, quad = lane >> 4;
    const int rbase = bx * 128 + wave * 32 + quad * 4;
#pragma unroll
    for (int h = 0; h < 2; ++h)
#pragma unroll
        for (int r = 0; r < 4; ++r) {
            int row = rbase + h * 16 + r;
            if (row >= N_) continue;
#pragma unroll
            for (int t = 0; t < 8; ++t) {
                int col = t * 16 + mloc;
                float v = acc[h][t][r] + P2[base + (size_t)row * C_ + col];
                v = (v > 0.f) ? tanhf(v) : 0.f;
                outs[base + (size_t)row * C_ + col] = v;
            }
        }
}

#define KLIN_BLOCKS (40 * 4 * B_)

// colsum += Σ_n tanh(outs[et] @ klin[nt] + klin_b[nt]) ; last block computes attn.
__global__ __launch_bounds__(256) void klin_mfma(const float* __restrict__ outs,
                                                 const unsigned short* __restrict__ wph,
                                                 const unsigned short* __restrict__ wpl,
                                                 const float* __restrict__ klin_b,
                                                 const float* __restrict__ q,
                                                 float* __restrict__ colsum,
                                                 int* __restrict__ done,
                                                 float* __restrict__ attn)
{
    int g = blockIdx.y, b = blockIdx.z;
    int bx = blockIdx.x;
    int nt = g >> 1, tt = g & 1;
    int et = (tt == 0) ? nt : 3 - nt;
    size_t abase = (size_t)(b * T_ + et) * N_ * C_;
    ffrag acc[2][8];
    zero_acc(acc);
    mfma128(outs + abase, wph + SLOT(18 + nt), wpl + SLOT(18 + nt), acc, bx);
    __shared__ float cs[128];
    if (threadIdx.x < 128) cs[threadIdx.x] = 0.f;
    __syncthreads();
    const int wave = threadIdx.x >> 6, lane = threadIdx.x & 63;
    const int mloc = lane & 15, quad = lane >> 4;
    const int rbase = bx * 128 + wave * 32 + quad * 4;
#pragma unroll
    for (int t = 0; t < 8; ++t) {
        int col = t * 16 + mloc;
        float bv = klin_b[nt * C_ + col];
        float s = 0.f;
#pragma unroll
        for (int h = 0; h < 2; ++h)
#pragma unroll
            for (int r = 0; r < 4; ++r) {
                int row = rbase + h * 16 + r;
                if (row < N_) s += tanhf(acc[h][t][r] + bv);
            }
        atomicAdd(&cs[col], s);
    }
    __syncthreads();
    if (threadIdx.x < 128)
        atomicAdd(&colsum[(size_t)((b * 2 + nt) * 2 + tt) * C_ + threadIdx.x], cs[threadIdx.x]);
    // last-block score fusion
    __shared__ int isLast;
    if (threadIdx.x == 0) {
        __threadfence();
        isLast = (atomicAdd(done, 1) == KLIN_BLOCKS - 1) ? 1 : 0;
    }
    __syncthreads();
    if (!isLast) return;
    __shared__ float red[2][2];
    for (int bnt = 0; bnt < 4; ++bnt) {
        int ntl = bnt & 1;
        float v0 = 0.f, v1 = 0.f;
        if (threadIdx.x < 128) {
            int c = threadIdx.x;
            float qc = q[ntl * C_ + c];
            float c0 = atomicAdd(&colsum[(size_t)(bnt * 2 + 0) * C_ + c], 0.f);
            float c1 = atomicAdd(&colsum[(size_t)(bnt * 2 + 1) * C_ + c], 0.f);
            v0 = qc * c0;
            v1 = qc * c1;
        }
#pragma unroll
        for (int m = 32; m > 0; m >>= 1) {
            v0 += __shfl_down(v0, m);
            v1 += __shfl_down(v1, m);
        }
        if ((threadIdx.x & 63) == 0 && wave < 2) {
            red[wave][0] = v0;
            red[wave][1] = v1;
        }
        __syncthreads();
        if (threadIdx.x == 0) {
            float s0 = (red[0][0] + red[1][0]) / (float)N_;
            float s1 = (red[0][1] + red[1][1]) / (float)N_;
            float mx = fmaxf(s0, s1);
            float e0 = __expf(s0 - mx), e1 = __expf(s1 - mx);
            float invd = 1.f / (e0 + e1);
            attn[bnt * 2 + 0] = e0 * invd;
            attn[bnt * 2 + 1] = e1 * invd;
        }
        __syncthreads();
    }
}

__global__ void output_kernel(const float* __restrict__ outs,
                              const float* __restrict__ attn,
                              float* __restrict__ out)
{
    int idx = blockIdx.x * blockDim.x + threadIdx.x;
    int c4 = idx & 31;
    int row = idx >> 5;
    int b = row / TWO_N;
    int r = row % TWO_N;
    int nt = (r >= N_) ? 1 : 0;
    int n = r - nt * N_;
    int et0 = nt, et1 = 3 - nt;
    float a0 = attn[(b * 2 + nt) * 2 + 0];
    float a1 = attn[(b * 2 + nt) * 2 + 1];
    const float4* o0 = (const float4*)(outs + ((size_t)(b * T_ + et0) * N_ + n) * C_);
    const float4* o1 = (const float4*)(outs + ((size_t)(b * T_ + et1) * N_ + n) * C_);
    float4 v0 = o0[c4], v1 = o1[c4], o;
    o.x = a0 * v0.x + a1 * v1.x;
    o.y = a0 * v0.y + a1 * v1.y;
    o.z = a0 * v0.z + a1 * v1.z;
    o.w = a0 * v0.w + a1 * v1.w;
    ((float4*)out)[idx] = o;
}

extern "C" void kernel_launch(void* const* d_in, const int* in_sizes, int n_in,
                              void* d_out, int out_size, void* d_ws, size_t ws_size,
                              hipStream_t stream)
{
    const float* x       = (const float*)d_in[0];
    const int*   eidx    = (const int*)d_in[1];
    const float* ew      = (const float*)d_in[2];
    const float* proj_w  = (const float*)d_in[3];
    const float* proj_b  = (const float*)d_in[4];
    const float* q       = (const float*)d_in[5];
    const float* klin_w  = (const float*)d_in[6];
    const float* klin_b  = (const float*)d_in[7];
    const float* lin_src = (const float*)d_in[8];
    const float* lin_dst = (const float*)d_in[9];
    const float* eproj_w = (const float*)d_in[10];
    const float* eproj_b = (const float*)d_in[11];
    const float* agg_w   = (const float*)d_in[12];
    const float* agg_b   = (const float*)d_in[13];
    const float* att_w   = (const float*)d_in[14];
    const float* att_b   = (const float*)d_in[15];

    float* ws = (float*)d_ws;
    size_t o = 0;
    float* xn     = ws + o; o += 2560000;   // live proj -> yji
    float* GU     = ws + o; o += 5120000;   // G (bf16, yji->aggregate) ∪ outs (fp32)
    float* Yi     = ws + o; o += 5120000;
    float* P2     = ws + o; o += 5120000;
    float* aggrBf = ws + o; o += 2560000;   // bf16 aggr
    float* pw     = ws + o; o += 2 * 8 * EP_;      // 1,310,720
    int*   ssrc   = (int*)(ws + o); o += 8 * EP_;  //   655,360
    float* asrc   = ws + o; o += 40000;
    float* adst   = ws + o; o += 40000;
    float* v1     = ws + o; o += 512;
    float* bias_i = ws + o; o += 512;
    float* attn   = ws + o; o += 16;
    // zeroed-by-setup region (contiguous ints): count, cursor, colsum, done
    int*   count  = (int*)(ws + o); o += 40000;
    int*   cursor = (int*)(ws + o); o += 40000;
    float* colsum = ws + o; o += 1024;
    int*   done   = (int*)(ws + o); o += 4;
    int*   offs   = (int*)(ws + o); o += 40008;
    unsigned short* wph = (unsigned short*)(ws + o); o += 163840;
    unsigned short* wpl = (unsigned short*)(ws + o); o += 163840;
    unsigned short* lph = (unsigned short*)(ws + o); o += 1024;
    unsigned short* lpl = (unsigned short*)(ws + o); o += 1024;
    // total ≈ 23.1M floats ≈ 92 MB

    unsigned short* G    = (unsigned short*)GU;
    float*          outs = GU;
    unsigned short* aggrB = (unsigned short*)aggrBf;

    setup_kernel<<<dim3(243), 256, 0, stream>>>(proj_w, att_w, agg_w, klin_w,
                                                lin_src, lin_dst, eproj_w, eproj_b,
                                                att_b, wph, wpl, lph, lpl,
                                                v1, bias_i, count);
    cp_kernel<<<dim3(2208), 256, 0, stream>>>(eidx, count, x, wph, wpl, proj_b,
                                              lin_src, lin_dst, xn, asrc, adst);
    scan_kernel<<<dim3(B_ * T_), 256, 0, stream>>>(count, offs, ssrc, pw);
    sy_kernel<<<dim3(3008), 256, 0, stream>>>(eidx, ew, asrc, adst, offs, cursor,
                                              ssrc, pw, xn, wph, wpl, bias_i, agg_b,
                                              G, Yi, P2);
    aggregate_kernel<<<dim3(10000), 256, 0, stream>>>(G, Yi, v1, pw, ssrc, offs, aggrB);
    agg_mfma<<<dim3(40, T_, B_), 256, 0, stream>>>(aggrB, wph, wpl, P2, outs);
    klin_mfma<<<dim3(40, 4, B_), 256, 0, stream>>>(outs, wph, wpl, klin_b, q,
                                                   colsum, done, attn);
    output_kernel<<<dim3(2500), 256, 0, stream>>>(outs, attn, (float*)d_out);
}

// Round 7
// 317.304 us; speedup vs baseline: 1.6438x; 1.0594x over previous
//
#include <hip/hip_runtime.h>
#include <math.h>

// Problem constants (from reference setup_inputs)
#define B_    2
#define N_    5000
#define C_    128
#define E_    65536
#define T_    4
#define TWO_N 10000
#define EP_   81920   // padded CSR capacity per (et,b)

// edge types: (src,dst) node types = (0,0),(1,1),(0,1),(1,0)
// s_t = et & 1 ; d_t = ((et+1)>>1) & 1

__device__ __forceinline__ unsigned short f2bf(float f) {
    unsigned u = __float_as_uint(f);
    u += 0x7fffu + ((u >> 16) & 1u);   // RNE
    return (unsigned short)(u >> 16);
}
__device__ __forceinline__ float bf2f(unsigned short h) {
    return __uint_as_float(((unsigned)h) << 16);
}

typedef __attribute__((ext_vector_type(8))) short bfrag;   // 8 bf16
typedef __attribute__((ext_vector_type(4))) float ffrag;   // 4 fp32 acc

__device__ __forceinline__ void split8(const float* __restrict__ p, bfrag& hi, bfrag& lo) {
#pragma unroll
    for (int j = 0; j < 8; ++j) {
        float v = p[j];
        unsigned short h = f2bf(v);
        hi[j] = (short)h;
        lo[j] = (short)f2bf(v - bf2f(h));
    }
}

// Weight slots (each 128x128, B-fragment packed):
// 0-1: proj ; 2-5: Wj[et] ; 6-9: Wi[et] ; 10-13: W1[et] ; 14-17: W2[et] ; 18-19: klin[nt]
#define SLOT(i) ((size_t)(i) * 16384)

__device__ __forceinline__ void zero_acc(ffrag (&acc)[2][8]) {
#pragma unroll
    for (int h = 0; h < 2; ++h)
#pragma unroll
        for (int t = 0; t < 8; ++t) acc[h][t] = (ffrag){0.f, 0.f, 0.f, 0.f};
}

// Split-bf16 MFMA GEMM core, K=128, 4 waves x 32 rows, N=128. fp32 A.
__device__ __forceinline__ void mfma128(const float* __restrict__ A,
                                        const unsigned short* __restrict__ Whi,
                                        const unsigned short* __restrict__ Wlo,
                                        ffrag (&acc)[2][8], int bx)
{
    const int wave = threadIdx.x >> 6, lane = threadIdx.x & 63;
    const int mloc = lane & 15, quad = lane >> 4;
    const int row0w = bx * 128 + wave * 32;
    int r0 = row0w + mloc;      if (r0 >= N_) r0 = N_ - 1;  // clamp, stores guarded
    int r1 = row0w + 16 + mloc; if (r1 >= N_) r1 = N_ - 1;
#pragma unroll
    for (int s = 0; s < 4; ++s) {
        bfrag a0h, a0l, a1h, a1l;
        split8(A + (size_t)r0 * C_ + s * 32 + quad * 8, a0h, a0l);
        split8(A + (size_t)r1 * C_ + s * 32 + quad * 8, a1h, a1l);
        const unsigned short* pBh = Whi + ((size_t)s * 512 + lane) * 8;
        const unsigned short* pBl = Wlo + ((size_t)s * 512 + lane) * 8;
#pragma unroll
        for (int t = 0; t < 8; ++t) {
            bfrag bh = *(const bfrag*)(pBh + (size_t)t * 512);
            bfrag bl = *(const bfrag*)(pBl + (size_t)t * 512);
            acc[0][t] = __builtin_amdgcn_mfma_f32_16x16x32_bf16(a0h, bh, acc[0][t], 0, 0, 0);
            acc[0][t] = __builtin_amdgcn_mfma_f32_16x16x32_bf16(a0l, bh, acc[0][t], 0, 0, 0);
            acc[0][t] = __builtin_amdgcn_mfma_f32_16x16x32_bf16(a0h, bl, acc[0][t], 0, 0, 0);
            acc[1][t] = __builtin_amdgcn_mfma_f32_16x16x32_bf16(a1h, bh, acc[1][t], 0, 0, 0);
            acc[1][t] = __builtin_amdgcn_mfma_f32_16x16x32_bf16(a1l, bh, acc[1][t], 0, 0, 0);
            acc[1][t] = __builtin_amdgcn_mfma_f32_16x16x32_bf16(a1h, bl, acc[1][t], 0, 0, 0);
        }
    }
}

// Same core but A is bf16 (single, no split): D = A @ (Wh + Wl).
__device__ __forceinline__ void mfma128_bfA(const unsigned short* __restrict__ A,
                                            const unsigned short* __restrict__ Whi,
                                            const unsigned short* __restrict__ Wlo,
                                            ffrag (&acc)[2][8], int bx)
{
    const int wave = threadIdx.x >> 6, lane = threadIdx.x & 63;
    const int mloc = lane & 15, quad = lane >> 4;
    const int row0w = bx * 128 + wave * 32;
    int r0 = row0w + mloc;      if (r0 >= N_) r0 = N_ - 1;
    int r1 = row0w + 16 + mloc; if (r1 >= N_) r1 = N_ - 1;
#pragma unroll
    for (int s = 0; s < 4; ++s) {
        bfrag a0 = *(const bfrag*)(A + (size_t)r0 * C_ + s * 32 + quad * 8);
        bfrag a1 = *(const bfrag*)(A + (size_t)r1 * C_ + s * 32 + quad * 8);
        const unsigned short* pBh = Whi + ((size_t)s * 512 + lane) * 8;
        const unsigned short* pBl = Wlo + ((size_t)s * 512 + lane) * 8;
#pragma unroll
        for (int t = 0; t < 8; ++t) {
            bfrag bh = *(const bfrag*)(pBh + (size_t)t * 512);
            bfrag bl = *(const bfrag*)(pBl + (size_t)t * 512);
            acc[0][t] = __builtin_amdgcn_mfma_f32_16x16x32_bf16(a0, bh, acc[0][t], 0, 0, 0);
            acc[0][t] = __builtin_amdgcn_mfma_f32_16x16x32_bf16(a0, bl, acc[0][t], 0, 0, 0);
            acc[1][t] = __builtin_amdgcn_mfma_f32_16x16x32_bf16(a1, bh, acc[1][t], 0, 0, 0);
            acc[1][t] = __builtin_amdgcn_mfma_f32_16x16x32_bf16(a1, bl, acc[1][t], 0, 0, 0);
        }
    }
}

#define ZN_ 81028   // count(40000) + cursor(40000) + colsum(1024) + done(4)

// setup: blocks [0,160) pack_w ; [160] pack_L ; [161,163) prep ; [163,243) zero
__global__ __launch_bounds__(256) void setup_kernel(
    const float* __restrict__ proj_w, const float* __restrict__ att_w,
    const float* __restrict__ agg_w, const float* __restrict__ klin_w,
    const float* __restrict__ lin_src, const float* __restrict__ lin_dst,
    const float* __restrict__ eproj_w, const float* __restrict__ eproj_b,
    const float* __restrict__ att_b,
    unsigned short* __restrict__ wh, unsigned short* __restrict__ wl,
    unsigned short* __restrict__ lph, unsigned short* __restrict__ lpl,
    float* __restrict__ v1, float* __restrict__ bias_i, int* __restrict__ zbase)
{
    int blk = blockIdx.x;
    if (blk < 160) {
        int wave = threadIdx.x >> 6, lane = threadIdx.x & 63;
        int unit = blk * 4 + wave;      // 0..639
        int id = unit >> 5;             // slot 0..19
        int st = unit & 31;
        int s = st >> 3, t = st & 7;
        const float* src;
        if (id < 2)       src = proj_w + (size_t)id * 16384;
        else if (id < 6)  src = att_w + (size_t)(id - 2) * 384 * C_;
        else if (id < 10) src = att_w + (size_t)(id - 6) * 384 * C_ + (size_t)128 * C_;
        else if (id < 14) src = agg_w + (size_t)(id - 10) * 256 * C_;
        else if (id < 18) src = agg_w + (size_t)(id - 14) * 256 * C_ + (size_t)128 * C_;
        else              src = klin_w + (size_t)(id - 18) * 16384;
        int mloc = lane & 15, quad = lane >> 4;
        size_t dbase = SLOT(id) + ((size_t)(s * 8 + t) * 64 + lane) * 8;
#pragma unroll
        for (int j = 0; j < 8; ++j) {
            float v = src[(size_t)(s * 32 + quad * 8 + j) * C_ + t * 16 + mloc];
            unsigned short h = f2bf(v);
            wh[dbase + j] = h;
            wl[dbase + j] = f2bf(v - bf2f(h));
        }
    } else if (blk == 160) {
        int s = threadIdx.x >> 6;       // wave = s (0..3)
        int lane = threadIdx.x & 63;
        int mloc = lane & 15, quad = lane >> 4;
        const float* vec = nullptr;
        if (mloc < 8) {
            int nt = mloc >> 2, idx = mloc & 3;
            if (idx == 0)      vec = lin_src + nt * C_;
            else if (idx == 1) vec = lin_src + (nt + 2) * C_;
            else if (idx == 2) vec = lin_dst + nt * C_;
            else               vec = lin_dst + (3 - nt) * C_;
        }
        size_t dbase = ((size_t)(s * 64) + lane) * 8;
#pragma unroll
        for (int j = 0; j < 8; ++j) {
            float v = vec ? vec[s * 32 + quad * 8 + j] : 0.f;
            unsigned short h = f2bf(v);
            lph[dbase + j] = h;
            lpl[dbase + j] = f2bf(v - bf2f(h));
        }
    } else if (blk < 163) {
        int et = (blk - 161) * 2 + (threadIdx.x >> 7);
        int c = threadIdx.x & 127;
        float s1 = 0.f, s0 = 0.f;
        for (int k = 0; k < 128; ++k) {
            float wv = att_w[(size_t)et * 384 * C_ + (size_t)(256 + k) * C_ + c];
            s1 = fmaf(eproj_w[et * C_ + k], wv, s1);
            s0 = fmaf(eproj_b[et * C_ + k], wv, s0);
        }
        v1[et * C_ + c] = s1;
        bias_i[et * C_ + c] = att_b[et * C_ + c] + s0;
    } else {
        int base = (blk - 163) * 1024 + threadIdx.x * 4;
#pragma unroll
        for (int j = 0; j < 4; ++j)
            if (base + j < ZN_) zbase[base + j] = 0;
    }
}

// count + proj(+nodedot) hybrid: blocks [0,2048) count ; [2048,2208) proj
__global__ __launch_bounds__(256) void cp_kernel(
    const int* __restrict__ eidx, int* __restrict__ count,
    const float* __restrict__ x,
    const unsigned short* __restrict__ wph, const unsigned short* __restrict__ wpl,
    const float* __restrict__ proj_b,
    const float* __restrict__ lin_src, const float* __restrict__ lin_dst,
    float* __restrict__ xn, float* __restrict__ asrc, float* __restrict__ adst)
{
    int blk = blockIdx.x;
    if (blk < 2048) {
        int eb = blk >> 8;            // 0..7
        int et = eb >> 1, b = eb & 1;
        int e = (blk & 255) * 256 + threadIdx.x;
        int dst = eidx[(((size_t)et * B_ + b) * 2 + 1) * E_ + e];
        atomicAdd(&count[(size_t)(b * T_ + et) * N_ + dst], 1);
        return;
    }
    int pidx = blk - 2048;            // 0..159
    int bx = pidx % 40;
    int nt = (pidx / 40) & 1;
    int b = pidx / 80;
    const float* A = x + ((size_t)b * TWO_N + (size_t)nt * N_) * C_;
    ffrag acc[2][8];
    zero_acc(acc);
    mfma128(A, wph + SLOT(nt), wpl + SLOT(nt), acc, bx);
    float* out = xn + (size_t)(b * 2 + nt) * N_ * C_;
    const float* bias = proj_b + nt * C_;
    const int wave = threadIdx.x >> 6, lane = threadIdx.x & 63;
    const int mloc = lane & 15, quad = lane >> 4;
    const int rbase = bx * 128 + wave * 32 + quad * 4;
    // lin columns for the fused nodedot
    const float* lv0 = lin_src + nt * C_;
    const float* lv1 = lin_src + (2 + nt) * C_;
    const float* lv2 = lin_dst + nt * C_;
    const float* lv3 = lin_dst + (3 - nt) * C_;
    float linv[4][8];
#pragma unroll
    for (int t = 0; t < 8; ++t) {
        int col = t * 16 + mloc;
        linv[0][t] = lv0[col]; linv[1][t] = lv1[col];
        linv[2][t] = lv2[col]; linv[3][t] = lv3[col];
    }
    const int et0 = nt, et1 = 2 + nt, et2 = nt, et3 = 3 - nt;
#pragma unroll
    for (int h = 0; h < 2; ++h)
#pragma unroll
        for (int r = 0; r < 4; ++r) {
            int row = rbase + h * 16 + r;
            bool ok = (row < N_);
            float p0 = 0.f, p1 = 0.f, p2 = 0.f, p3 = 0.f;
#pragma unroll
            for (int t = 0; t < 8; ++t) {
                int col = t * 16 + mloc;
                float vv = acc[h][t][r] + bias[col];
                if (ok) out[(size_t)row * C_ + col] = vv;
                p0 = fmaf(vv, linv[0][t], p0);
                p1 = fmaf(vv, linv[1][t], p1);
                p2 = fmaf(vv, linv[2][t], p2);
                p3 = fmaf(vv, linv[3][t], p3);
            }
#pragma unroll
            for (int m = 1; m < 16; m <<= 1) {
                p0 += __shfl_xor(p0, m);
                p1 += __shfl_xor(p1, m);
                p2 += __shfl_xor(p2, m);
                p3 += __shfl_xor(p3, m);
            }
            if (mloc == 0 && ok) {
                asrc[(size_t)(b * T_ + et0) * N_ + row] = p0;
                asrc[(size_t)(b * T_ + et1) * N_ + row] = p1;
                adst[(size_t)(b * T_ + et2) * N_ + row] = p2;
                adst[(size_t)(b * T_ + et3) * N_ + row] = p3;
            }
        }
}

// Exclusive scan of 4-aligned strides -> CSR offsets; zero pad slots.
__global__ __launch_bounds__(256) void scan_kernel(const int* __restrict__ count,
                                                   int* __restrict__ offs,
                                                   int* __restrict__ ssrc,
                                                   float* __restrict__ pw)
{
    int be = blockIdx.x;
    const int* cnt = count + (size_t)be * N_;
    int* off = offs + (size_t)be * (N_ + 1);
    __shared__ int sums[256];
    int tid = threadIdx.x;
    const int chunk = (N_ + 255) / 256;  // 20
    int lo = tid * chunk, hi = min(lo + chunk, N_);
    int s = 0;
    for (int i = lo; i < hi; ++i) s += (cnt[i] + 3) & ~3;
    sums[tid] = s;
    __syncthreads();
    for (int d = 1; d < 256; d <<= 1) {
        int v = (tid >= d) ? sums[tid - d] : 0;
        __syncthreads();
        sums[tid] += v;
        __syncthreads();
    }
    int run = (tid > 0) ? sums[tid - 1] : 0;
    float2* pwp = (float2*)pw;
    for (int i = lo; i < hi; ++i) {
        off[i] = run;
        int c = cnt[i], pc = (c + 3) & ~3;
        for (int k = c; k < pc; ++k) {
            int pos = run + k;
            ssrc[(size_t)be * EP_ + pos] = 0;
            pwp[(size_t)be * EP_ + pos] = make_float2(0.f, 0.f);
        }
        run += pc;
    }
    if (tid == 255) off[N_] = sums[255];
}

// scatter + yji hybrid: blocks [0,2048) scatter ; [2048,2688) yji
// yji roles: 0 -> G = interleaved bf16 {Z=xs*(xs@Wj), xs} ; 1 -> Yi (bf16)
__global__ __launch_bounds__(256) void sy_kernel(
    const int* __restrict__ eidx, const float* __restrict__ ew,
    const float* __restrict__ asrc, const float* __restrict__ adst,
    const int* __restrict__ offs, int* __restrict__ cursor,
    int* __restrict__ ssrc, float* __restrict__ pw,
    const float* __restrict__ xn,
    const unsigned short* __restrict__ wph, const unsigned short* __restrict__ wpl,
    const float* __restrict__ bias_i,
    unsigned short* __restrict__ G, unsigned short* __restrict__ YiB)
{
    int blk = blockIdx.x;
    if (blk < 2048) {
        int eb = blk >> 8;
        int et = eb >> 1, b = eb & 1;
        int e = (blk & 255) * 256 + threadIdx.x;
        size_t ebase = ((size_t)et * B_ + b) * 2 * E_;
        int src = eidx[ebase + e];
        int dst = eidx[ebase + E_ + e];
        int be = b * T_ + et;
        float al = asrc[(size_t)be * N_ + src] + adst[(size_t)be * N_ + dst];
        al = (al > 0.f) ? al : 0.2f * al;
        float p = __expf(al);
        float w = ew[((size_t)et * B_ + b) * E_ + e];
        int pos = offs[(size_t)be * (N_ + 1) + dst] +
                  atomicAdd(&cursor[(size_t)be * N_ + dst], 1);
        ssrc[(size_t)be * EP_ + pos] = src;
        ((float2*)pw)[(size_t)be * EP_ + pos] = make_float2(p, p * w);
        return;
    }
    int yidx = blk - 2048;            // 0..639
    int bx = yidx % 40;
    int m = (yidx / 40) % 8;          // role*4 + et
    int b = yidx / 320;               // 0..1
    int role = m >> 2, et = m & 3;
    int s_t = et & 1, d_t = ((et + 1) >> 1) & 1;
    int ntsel = (role == 0) ? s_t : d_t;
    const float* A = xn + (size_t)(b * 2 + ntsel) * N_ * C_;
    int slot = (role == 0) ? 2 + et : 6 + et;
    ffrag acc[2][8];
    zero_acc(acc);
    mfma128(A, wph + SLOT(slot), wpl + SLOT(slot), acc, bx);
    int be = b * T_ + et;
    const float* bias = bias_i + et * C_;
    const int wave = threadIdx.x >> 6, lane = threadIdx.x & 63;
    const int mloc = lane & 15, quad = lane >> 4;
    const int rbase = bx * 128 + wave * 32 + quad * 4;
#pragma unroll
    for (int h = 0; h < 2; ++h)
#pragma unroll
        for (int r = 0; r < 4; ++r) {
            int row = rbase + h * 16 + r;
            if (row >= N_) continue;
#pragma unroll
            for (int t = 0; t < 8; ++t) {
                int col = t * 16 + mloc;
                float v = acc[h][t][r];
                if (role == 0) {
                    float xv = A[(size_t)row * C_ + col];
                    *(ushort2*)(G + ((size_t)be * N_ + row) * 256 + 2 * col) =
                        make_ushort2(f2bf(v * xv), f2bf(xv));
                } else {
                    YiB[((size_t)be * N_ + row) * C_ + col] = f2bf(v + bias[col]);
                }
            }
        }
}

// Segment-softmax aggregation, one wave per (node, et, b), XCD-pinned by pair.
// aggr = (Σ p·Z[s] + Yi'⊙Σ p·xs + v1⊙Σ q·xs) / Σ p, emitted as bf16.
__global__ __launch_bounds__(256) void aggregate_kernel(
    const unsigned short* __restrict__ G, const unsigned short* __restrict__ YiB,
    const float* __restrict__ v1, const float* __restrict__ pw,
    const int* __restrict__ ssrc, const int* __restrict__ offs,
    unsigned short* __restrict__ aggrB)
{
    int pair = blockIdx.x & 7;                       // = b*T_+et (XCD-pin)
    int n = (blockIdx.x >> 3) * 4 + (threadIdx.x >> 6);
    int et = pair & 3;
    int be = pair;
    int l = threadIdx.x & 63;
    const unsigned short* Gp = G + (size_t)be * N_ * 256;
    int beg = offs[(size_t)be * (N_ + 1) + n];
    int end = offs[(size_t)be * (N_ + 1) + n + 1];
    const int* sp = ssrc + (size_t)be * EP_ + beg;
    const float* pwp = pw + ((size_t)be * EP_ + beg) * 2;
    float a1x = 0.f, a1y = 0.f, a2x = 0.f, a2y = 0.f, a3x = 0.f, a3y = 0.f, denom = 0.f;
    int cnt = end - beg;  // multiple of 4; pads have p=q=0, ssrc=0
    for (int i = 0; i < cnt; i += 4) {
        int4 ss = *(const int4*)(sp + i);
        float4 pq0 = *(const float4*)(pwp + 2 * i);      // p0 q0 p1 q1
        float4 pq1 = *(const float4*)(pwp + 2 * i + 4);  // p2 q2 p3 q3
        ushort4 g0 = *(const ushort4*)(Gp + (size_t)ss.x * 256 + 4 * l);
        ushort4 g1 = *(const ushort4*)(Gp + (size_t)ss.y * 256 + 4 * l);
        ushort4 g2 = *(const ushort4*)(Gp + (size_t)ss.z * 256 + 4 * l);
        ushort4 g3 = *(const ushort4*)(Gp + (size_t)ss.w * 256 + 4 * l);
        denom += pq0.x + pq0.z + pq1.x + pq1.z;
        a1x = fmaf(pq0.x, bf2f(g0.x), a1x); a2x = fmaf(pq0.x, bf2f(g0.y), a2x);
        a3x = fmaf(pq0.y, bf2f(g0.y), a3x);
        a1y = fmaf(pq0.x, bf2f(g0.z), a1y); a2y = fmaf(pq0.x, bf2f(g0.w), a2y);
        a3y = fmaf(pq0.y, bf2f(g0.w), a3y);
        a1x = fmaf(pq0.z, bf2f(g1.x), a1x); a2x = fmaf(pq0.z, bf2f(g1.y), a2x);
        a3x = fmaf(pq0.w, bf2f(g1.y), a3x);
        a1y = fmaf(pq0.z, bf2f(g1.z), a1y); a2y = fmaf(pq0.z, bf2f(g1.w), a2y);
        a3y = fmaf(pq0.w, bf2f(g1.w), a3y);
        a1x = fmaf(pq1.x, bf2f(g2.x), a1x); a2x = fmaf(pq1.x, bf2f(g2.y), a2x);
        a3x = fmaf(pq1.y, bf2f(g2.y), a3x);
        a1y = fmaf(pq1.x, bf2f(g2.z), a1y); a2y = fmaf(pq1.x, bf2f(g2.w), a2y);
        a3y = fmaf(pq1.y, bf2f(g2.w), a3y);
        a1x = fmaf(pq1.z, bf2f(g3.x), a1x); a2x = fmaf(pq1.z, bf2f(g3.y), a2x);
        a3x = fmaf(pq1.w, bf2f(g3.y), a3x);
        a1y = fmaf(pq1.z, bf2f(g3.z), a1y); a2y = fmaf(pq1.z, bf2f(g3.w), a2y);
        a3y = fmaf(pq1.w, bf2f(g3.w), a3y);
    }
    ushort2 yiu = *(const ushort2*)(YiB + ((size_t)be * N_ + n) * C_ + 2 * l);
    float2 vv = *(const float2*)(v1 + et * C_ + 2 * l);
    float inv = (denom > 0.f) ? 1.f / denom : 0.f;
    float ox = (a1x + bf2f(yiu.x) * a2x + vv.x * a3x) * inv;
    float oy = (a1y + bf2f(yiu.y) * a2y + vv.y * a3y) * inv;
    *(ushort2*)(aggrB + ((size_t)be * N_ + n) * C_ + 2 * l) = make_ushort2(f2bf(ox), f2bf(oy));
}

// outs = tanh(relu(aggr @ W1 + xn[d_t] @ W2 + agg_b)), emitted as bf16.
__global__ __launch_bounds__(256) void agg_mfma(const unsigned short* __restrict__ aggrB,
                                                const float* __restrict__ xn,
                                                const unsigned short* __restrict__ wph,
                                                const unsigned short* __restrict__ wpl,
                                                const float* __restrict__ agg_b,
                                                unsigned short* __restrict__ outsB)
{
    int et = blockIdx.y, b = blockIdx.z;
    int bx = blockIdx.x;
    int d_t = ((et + 1) >> 1) & 1;
    size_t base = (size_t)(b * T_ + et) * N_ * C_;
    ffrag acc[2][8];
    zero_acc(acc);
    mfma128_bfA(aggrB + base, wph + SLOT(10 + et), wpl + SLOT(10 + et), acc, bx);
    mfma128(xn + (size_t)(b * 2 + d_t) * N_ * C_, wph + SLOT(14 + et), wpl + SLOT(14 + et),
            acc, bx);
    const float* bias = agg_b + et * C_;
    const int wave = threadIdx.x >> 6, lane = threadIdx.x & 63;
    const int mloc = lane & 15, quad = lane >> 4;
    const int rbase = bx * 128 + wave * 32 + quad * 4;
#pragma unroll
    for (int h = 0; h < 2; ++h)
#pragma unroll
        for (int r = 0; r < 4; ++r) {
            int row = rbase + h * 16 + r;
            if (row >= N_) continue;
#pragma unroll
            for (int t = 0; t < 8; ++t) {
                int col = t * 16 + mloc;
                float v = acc[h][t][r] + bias[col];
                v = (v > 0.f) ? tanhf(v) : 0.f;
                outsB[base + (size_t)row * C_ + col] = f2bf(v);
            }
        }
}

#define KLIN_BLOCKS (40 * 4 * B_)

// colsum += Σ_n tanh(outs[et] @ klin[nt] + klin_b[nt]) ; last block computes attn.
__global__ __launch_bounds__(256) void klin_mfma(const unsigned short* __restrict__ outsB,
                                                 const unsigned short* __restrict__ wph,
                                                 const unsigned short* __restrict__ wpl,
                                                 const float* __restrict__ klin_b,
                                                 const float* __restrict__ q,
                                                 float* __restrict__ colsum,
                                                 int* __restrict__ done,
                                                 float* __restrict__ attn)
{
    int g = blockIdx.y, b = blockIdx.z;
    int bx = blockIdx.x;
    int nt = g >> 1, tt = g & 1;
    int et = (tt == 0) ? nt : 3 - nt;
    size_t abase = (size_t)(b * T_ + et) * N_ * C_;
    ffrag acc[2][8];
    zero_acc(acc);
    mfma128_bfA(outsB + abase, wph + SLOT(18 + nt), wpl + SLOT(18 + nt), acc, bx);
    __shared__ float cs[128];
    if (threadIdx.x < 128) cs[threadIdx.x] = 0.f;
    __syncthreads();
    const int wave = threadIdx.x >> 6, lane = threadIdx.x & 63;
    const int mloc = lane & 15, quad = lane >> 4;
    const int rbase = bx * 128 + wave * 32 + quad * 4;
#pragma unroll
    for (int t = 0; t < 8; ++t) {
        int col = t * 16 + mloc;
        float bv = klin_b[nt * C_ + col];
        float s = 0.f;
#pragma unroll
        for (int h = 0; h < 2; ++h)
#pragma unroll
            for (int r = 0; r < 4; ++r) {
                int row = rbase + h * 16 + r;
                if (row < N_) s += tanhf(acc[h][t][r] + bv);
            }
        atomicAdd(&cs[col], s);
    }
    __syncthreads();
    if (threadIdx.x < 128)
        atomicAdd(&colsum[(size_t)((b * 2 + nt) * 2 + tt) * C_ + threadIdx.x], cs[threadIdx.x]);
    // last-block score fusion
    __shared__ int isLast;
    if (threadIdx.x == 0) {
        __threadfence();
        isLast = (atomicAdd(done, 1) == KLIN_BLOCKS - 1) ? 1 : 0;
    }
    __syncthreads();
    if (!isLast) return;
    __shared__ float red[2][2];
    for (int bnt = 0; bnt < 4; ++bnt) {
        int ntl = bnt & 1;
        float v0 = 0.f, v1 = 0.f;
        if (threadIdx.x < 128) {
            int c = threadIdx.x;
            float qc = q[ntl * C_ + c];
            float c0 = atomicAdd(&colsum[(size_t)(bnt * 2 + 0) * C_ + c], 0.f);
            float c1 = atomicAdd(&colsum[(size_t)(bnt * 2 + 1) * C_ + c], 0.f);
            v0 = qc * c0;
            v1 = qc * c1;
        }
#pragma unroll
        for (int m = 32; m > 0; m >>= 1) {
            v0 += __shfl_down(v0, m);
            v1 += __shfl_down(v1, m);
        }
        if ((threadIdx.x & 63) == 0 && wave < 2) {
            red[wave][0] = v0;
            red[wave][1] = v1;
        }
        __syncthreads();
        if (threadIdx.x == 0) {
            float s0 = (red[0][0] + red[1][0]) / (float)N_;
            float s1 = (red[0][1] + red[1][1]) / (float)N_;
            float mx = fmaxf(s0, s1);
            float e0 = __expf(s0 - mx), e1 = __expf(s1 - mx);
            float invd = 1.f / (e0 + e1);
            attn[bnt * 2 + 0] = e0 * invd;
            attn[bnt * 2 + 1] = e1 * invd;
        }
        __syncthreads();
    }
}

__global__ void output_kernel(const unsigned short* __restrict__ outsB,
                              const float* __restrict__ attn,
                              float* __restrict__ out)
{
    int idx = blockIdx.x * blockDim.x + threadIdx.x;
    int c4 = idx & 31;
    int row = idx >> 5;
    int b = row / TWO_N;
    int r = row % TWO_N;
    int nt = (r >= N_) ? 1 : 0;
    int n = r - nt * N_;
    int et0 = nt, et1 = 3 - nt;
    float a0 = attn[(b * 2 + nt) * 2 + 0];
    float a1 = attn[(b * 2 + nt) * 2 + 1];
    const ushort4* o0 = (const ushort4*)(outsB + ((size_t)(b * T_ + et0) * N_ + n) * C_);
    const ushort4* o1 = (const ushort4*)(outsB + ((size_t)(b * T_ + et1) * N_ + n) * C_);
    ushort4 u0 = o0[c4], u1 = o1[c4];
    float4 o;
    o.x = a0 * bf2f(u0.x) + a1 * bf2f(u1.x);
    o.y = a0 * bf2f(u0.y) + a1 * bf2f(u1.y);
    o.z = a0 * bf2f(u0.z) + a1 * bf2f(u1.z);
    o.w = a0 * bf2f(u0.w) + a1 * bf2f(u1.w);
    ((float4*)out)[idx] = o;
}

extern "C" void kernel_launch(void* const* d_in, const int* in_sizes, int n_in,
                              void* d_out, int out_size, void* d_ws, size_t ws_size,
                              hipStream_t stream)
{
    const float* x       = (const float*)d_in[0];
    const int*   eidx    = (const int*)d_in[1];
    const float* ew      = (const float*)d_in[2];
    const float* proj_w  = (const float*)d_in[3];
    const float* proj_b  = (const float*)d_in[4];
    const float* q       = (const float*)d_in[5];
    const float* klin_w  = (const float*)d_in[6];
    const float* klin_b  = (const float*)d_in[7];
    const float* lin_src = (const float*)d_in[8];
    const float* lin_dst = (const float*)d_in[9];
    const float* eproj_w = (const float*)d_in[10];
    const float* eproj_b = (const float*)d_in[11];
    const float* agg_w   = (const float*)d_in[12];
    const float* agg_b   = (const float*)d_in[13];
    const float* att_w   = (const float*)d_in[14];
    const float* att_b   = (const float*)d_in[15];

    float* ws = (float*)d_ws;
    size_t o = 0;
    float* xn     = ws + o; o += 2560000;   // live proj -> agg_mfma
    float* GU     = ws + o; o += 5120000;   // G (bf16, sy->aggregate) ∪ outsB (bf16)
    float* YiBf   = ws + o; o += 2560000;   // Yi bf16
    float* aggrBf = ws + o; o += 2560000;   // bf16 aggr
    float* pw     = ws + o; o += 2 * 8 * EP_;      // 1,310,720
    int*   ssrc   = (int*)(ws + o); o += 8 * EP_;  //   655,360
    float* asrc   = ws + o; o += 40000;
    float* adst   = ws + o; o += 40000;
    float* v1     = ws + o; o += 512;
    float* bias_i = ws + o; o += 512;
    float* attn   = ws + o; o += 16;
    // zeroed-by-setup region (contiguous ints): count, cursor, colsum, done
    int*   count  = (int*)(ws + o); o += 40000;
    int*   cursor = (int*)(ws + o); o += 40000;
    float* colsum = ws + o; o += 1024;
    int*   done   = (int*)(ws + o); o += 4;
    int*   offs   = (int*)(ws + o); o += 40008;
    unsigned short* wph = (unsigned short*)(ws + o); o += 163840;
    unsigned short* wpl = (unsigned short*)(ws + o); o += 163840;
    unsigned short* lph = (unsigned short*)(ws + o); o += 1024;
    unsigned short* lpl = (unsigned short*)(ws + o); o += 1024;
    // total ≈ 15.3M floats ≈ 61 MB

    unsigned short* G     = (unsigned short*)GU;
    unsigned short* outsB = (unsigned short*)GU;
    unsigned short* YiB   = (unsigned short*)YiBf;
    unsigned short* aggrB = (unsigned short*)aggrBf;

    setup_kernel<<<dim3(243), 256, 0, stream>>>(proj_w, att_w, agg_w, klin_w,
                                                lin_src, lin_dst, eproj_w, eproj_b,
                                                att_b, wph, wpl, lph, lpl,
                                                v1, bias_i, count);
    cp_kernel<<<dim3(2208), 256, 0, stream>>>(eidx, count, x, wph, wpl, proj_b,
                                              lin_src, lin_dst, xn, asrc, adst);
    scan_kernel<<<dim3(B_ * T_), 256, 0, stream>>>(count, offs, ssrc, pw);
    sy_kernel<<<dim3(2688), 256, 0, stream>>>(eidx, ew, asrc, adst, offs, cursor,
                                              ssrc, pw, xn, wph, wpl, bias_i,
                                              G, YiB);
    aggregate_kernel<<<dim3(10000), 256, 0, stream>>>(G, YiB, v1, pw, ssrc, offs, aggrB);
    agg_mfma<<<dim3(40, T_, B_), 256, 0, stream>>>(aggrB, xn, wph, wpl, agg_b, outsB);
    klin_mfma<<<dim3(40, 4, B_), 256, 0, stream>>>(outsB, wph, wpl, klin_b, q,
                                                   colsum, done, attn);
    output_kernel<<<dim3(2500), 256, 0, stream>>>(outsB, attn, (float*)d_out);
}

// Round 8
// 309.285 us; speedup vs baseline: 1.6864x; 1.0259x over previous
//
#include <hip/hip_runtime.h>
#include <math.h>

// Problem constants (from reference setup_inputs)
#define B_    2
#define N_    5000
#define C_    128
#define E_    65536
#define T_    4
#define TWO_N 10000
#define EP_   81920   // padded CSR capacity per (et,b)

// edge types: (src,dst) node types = (0,0),(1,1),(0,1),(1,0)
// s_t = et & 1 ; d_t = ((et+1)>>1) & 1
// XCD-pin convention: pair index be = b*4+et == blockIdx.x & 7 for every
// kernel that touches per-pair edge data (count, scatter, yji-G, aggregate).

__device__ __forceinline__ unsigned short f2bf(float f) {
    unsigned u = __float_as_uint(f);
    u += 0x7fffu + ((u >> 16) & 1u);   // RNE
    return (unsigned short)(u >> 16);
}
__device__ __forceinline__ float bf2f(unsigned short h) {
    return __uint_as_float(((unsigned)h) << 16);
}

typedef __attribute__((ext_vector_type(8))) short bfrag;   // 8 bf16
typedef __attribute__((ext_vector_type(4))) float ffrag;   // 4 fp32 acc

__device__ __forceinline__ void split8(const float* __restrict__ p, bfrag& hi, bfrag& lo) {
#pragma unroll
    for (int j = 0; j < 8; ++j) {
        float v = p[j];
        unsigned short h = f2bf(v);
        hi[j] = (short)h;
        lo[j] = (short)f2bf(v - bf2f(h));
    }
}

// Weight slots (each 128x128, B-fragment packed):
// 0-1: proj ; 2-5: Wj[et] ; 6-9: Wi[et] ; 10-13: W1[et] ; 14-17: W2[et] ; 18-19: klin[nt]
#define SLOT(i) ((size_t)(i) * 16384)

__device__ __forceinline__ void zero_acc(ffrag (&acc)[2][8]) {
#pragma unroll
    for (int h = 0; h < 2; ++h)
#pragma unroll
        for (int t = 0; t < 8; ++t) acc[h][t] = (ffrag){0.f, 0.f, 0.f, 0.f};
}

// Split-bf16 MFMA GEMM core, K=128, 4 waves x 32 rows, N=128. fp32 A.
__device__ __forceinline__ void mfma128(const float* __restrict__ A,
                                        const unsigned short* __restrict__ Whi,
                                        const unsigned short* __restrict__ Wlo,
                                        ffrag (&acc)[2][8], int bx)
{
    const int wave = threadIdx.x >> 6, lane = threadIdx.x & 63;
    const int mloc = lane & 15, quad = lane >> 4;
    const int row0w = bx * 128 + wave * 32;
    int r0 = row0w + mloc;      if (r0 >= N_) r0 = N_ - 1;  // clamp, stores guarded
    int r1 = row0w + 16 + mloc; if (r1 >= N_) r1 = N_ - 1;
#pragma unroll
    for (int s = 0; s < 4; ++s) {
        bfrag a0h, a0l, a1h, a1l;
        split8(A + (size_t)r0 * C_ + s * 32 + quad * 8, a0h, a0l);
        split8(A + (size_t)r1 * C_ + s * 32 + quad * 8, a1h, a1l);
        const unsigned short* pBh = Whi + ((size_t)s * 512 + lane) * 8;
        const unsigned short* pBl = Wlo + ((size_t)s * 512 + lane) * 8;
#pragma unroll
        for (int t = 0; t < 8; ++t) {
            bfrag bh = *(const bfrag*)(pBh + (size_t)t * 512);
            bfrag bl = *(const bfrag*)(pBl + (size_t)t * 512);
            acc[0][t] = __builtin_amdgcn_mfma_f32_16x16x32_bf16(a0h, bh, acc[0][t], 0, 0, 0);
            acc[0][t] = __builtin_amdgcn_mfma_f32_16x16x32_bf16(a0l, bh, acc[0][t], 0, 0, 0);
            acc[0][t] = __builtin_amdgcn_mfma_f32_16x16x32_bf16(a0h, bl, acc[0][t], 0, 0, 0);
            acc[1][t] = __builtin_amdgcn_mfma_f32_16x16x32_bf16(a1h, bh, acc[1][t], 0, 0, 0);
            acc[1][t] = __builtin_amdgcn_mfma_f32_16x16x32_bf16(a1l, bh, acc[1][t], 0, 0, 0);
            acc[1][t] = __builtin_amdgcn_mfma_f32_16x16x32_bf16(a1h, bl, acc[1][t], 0, 0, 0);
        }
    }
}

// Same core but A is bf16 (single, no split): D = A @ (Wh + Wl).
__device__ __forceinline__ void mfma128_bfA(const unsigned short* __restrict__ A,
                                            const unsigned short* __restrict__ Whi,
                                            const unsigned short* __restrict__ Wlo,
                                            ffrag (&acc)[2][8], int bx)
{
    const int wave = threadIdx.x >> 6, lane = threadIdx.x & 63;
    const int mloc = lane & 15, quad = lane >> 4;
    const int row0w = bx * 128 + wave * 32;
    int r0 = row0w + mloc;      if (r0 >= N_) r0 = N_ - 1;
    int r1 = row0w + 16 + mloc; if (r1 >= N_) r1 = N_ - 1;
#pragma unroll
    for (int s = 0; s < 4; ++s) {
        bfrag a0 = *(const bfrag*)(A + (size_t)r0 * C_ + s * 32 + quad * 8);
        bfrag a1 = *(const bfrag*)(A + (size_t)r1 * C_ + s * 32 + quad * 8);
        const unsigned short* pBh = Whi + ((size_t)s * 512 + lane) * 8;
        const unsigned short* pBl = Wlo + ((size_t)s * 512 + lane) * 8;
#pragma unroll
        for (int t = 0; t < 8; ++t) {
            bfrag bh = *(const bfrag*)(pBh + (size_t)t * 512);
            bfrag bl = *(const bfrag*)(pBl + (size_t)t * 512);
            acc[0][t] = __builtin_amdgcn_mfma_f32_16x16x32_bf16(a0, bh, acc[0][t], 0, 0, 0);
            acc[0][t] = __builtin_amdgcn_mfma_f32_16x16x32_bf16(a0, bl, acc[0][t], 0, 0, 0);
            acc[1][t] = __builtin_amdgcn_mfma_f32_16x16x32_bf16(a1, bh, acc[1][t], 0, 0, 0);
            acc[1][t] = __builtin_amdgcn_mfma_f32_16x16x32_bf16(a1, bl, acc[1][t], 0, 0, 0);
        }
    }
}

#define ZN_ 81028   // count(40000) + cursor(40000) + colsum(1024) + done(4)

// setup: blocks [0,160) pack_w ; [160] pack_L ; [161,163) prep ; [163,243) zero
__global__ __launch_bounds__(256) void setup_kernel(
    const float* __restrict__ proj_w, const float* __restrict__ att_w,
    const float* __restrict__ agg_w, const float* __restrict__ klin_w,
    const float* __restrict__ lin_src, const float* __restrict__ lin_dst,
    const float* __restrict__ eproj_w, const float* __restrict__ eproj_b,
    const float* __restrict__ att_b,
    unsigned short* __restrict__ wh, unsigned short* __restrict__ wl,
    unsigned short* __restrict__ lph, unsigned short* __restrict__ lpl,
    float* __restrict__ v1, float* __restrict__ bias_i, int* __restrict__ zbase)
{
    int blk = blockIdx.x;
    if (blk < 160) {
        int wave = threadIdx.x >> 6, lane = threadIdx.x & 63;
        int unit = blk * 4 + wave;      // 0..639
        int id = unit >> 5;             // slot 0..19
        int st = unit & 31;
        int s = st >> 3, t = st & 7;
        const float* src;
        if (id < 2)       src = proj_w + (size_t)id * 16384;
        else if (id < 6)  src = att_w + (size_t)(id - 2) * 384 * C_;
        else if (id < 10) src = att_w + (size_t)(id - 6) * 384 * C_ + (size_t)128 * C_;
        else if (id < 14) src = agg_w + (size_t)(id - 10) * 256 * C_;
        else if (id < 18) src = agg_w + (size_t)(id - 14) * 256 * C_ + (size_t)128 * C_;
        else              src = klin_w + (size_t)(id - 18) * 16384;
        int mloc = lane & 15, quad = lane >> 4;
        size_t dbase = SLOT(id) + ((size_t)(s * 8 + t) * 64 + lane) * 8;
#pragma unroll
        for (int j = 0; j < 8; ++j) {
            float v = src[(size_t)(s * 32 + quad * 8 + j) * C_ + t * 16 + mloc];
            unsigned short h = f2bf(v);
            wh[dbase + j] = h;
            wl[dbase + j] = f2bf(v - bf2f(h));
        }
    } else if (blk == 160) {
        int s = threadIdx.x >> 6;       // wave = s (0..3)
        int lane = threadIdx.x & 63;
        int mloc = lane & 15, quad = lane >> 4;
        const float* vec = nullptr;
        if (mloc < 8) {
            int nt = mloc >> 2, idx = mloc & 3;
            if (idx == 0)      vec = lin_src + nt * C_;
            else if (idx == 1) vec = lin_src + (nt + 2) * C_;
            else if (idx == 2) vec = lin_dst + nt * C_;
            else               vec = lin_dst + (3 - nt) * C_;
        }
        size_t dbase = ((size_t)(s * 64) + lane) * 8;
#pragma unroll
        for (int j = 0; j < 8; ++j) {
            float v = vec ? vec[s * 32 + quad * 8 + j] : 0.f;
            unsigned short h = f2bf(v);
            lph[dbase + j] = h;
            lpl[dbase + j] = f2bf(v - bf2f(h));
        }
    } else if (blk < 163) {
        int et = (blk - 161) * 2 + (threadIdx.x >> 7);
        int c = threadIdx.x & 127;
        float s1 = 0.f, s0 = 0.f;
        for (int k = 0; k < 128; ++k) {
            float wv = att_w[(size_t)et * 384 * C_ + (size_t)(256 + k) * C_ + c];
            s1 = fmaf(eproj_w[et * C_ + k], wv, s1);
            s0 = fmaf(eproj_b[et * C_ + k], wv, s0);
        }
        v1[et * C_ + c] = s1;
        bias_i[et * C_ + c] = att_b[et * C_ + c] + s0;
    } else {
        int base = (blk - 163) * 1024 + threadIdx.x * 4;
#pragma unroll
        for (int j = 0; j < 4; ++j)
            if (base + j < ZN_) zbase[base + j] = 0;
    }
}

// count + proj(+nodedot) hybrid: blocks [0,2048) count (XCD-pinned) ; [2048,2208) proj
__global__ __launch_bounds__(256) void cp_kernel(
    const int* __restrict__ eidx, int* __restrict__ count,
    const float* __restrict__ x,
    const unsigned short* __restrict__ wph, const unsigned short* __restrict__ wpl,
    const float* __restrict__ proj_b,
    const float* __restrict__ lin_src, const float* __restrict__ lin_dst,
    float* __restrict__ xn, float* __restrict__ asrc, float* __restrict__ adst)
{
    int blk = blockIdx.x;
    if (blk < 2048) {
        int be = blk & 7;             // XCD-pin: pair = b*4+et
        int et = be & 3, b = be >> 2;
        int e = (blk >> 3) * 256 + threadIdx.x;
        int dst = eidx[(((size_t)et * B_ + b) * 2 + 1) * E_ + e];
        atomicAdd(&count[(size_t)be * N_ + dst], 1);
        return;
    }
    int pidx = blk - 2048;            // 0..159
    int bx = pidx % 40;
    int nt = (pidx / 40) & 1;
    int b = pidx / 80;
    const float* A = x + ((size_t)b * TWO_N + (size_t)nt * N_) * C_;
    ffrag acc[2][8];
    zero_acc(acc);
    mfma128(A, wph + SLOT(nt), wpl + SLOT(nt), acc, bx);
    float* out = xn + (size_t)(b * 2 + nt) * N_ * C_;
    const float* bias = proj_b + nt * C_;
    const int wave = threadIdx.x >> 6, lane = threadIdx.x & 63;
    const int mloc = lane & 15, quad = lane >> 4;
    const int rbase = bx * 128 + wave * 32 + quad * 4;
    // lin columns for the fused nodedot
    const float* lv0 = lin_src + nt * C_;
    const float* lv1 = lin_src + (2 + nt) * C_;
    const float* lv2 = lin_dst + nt * C_;
    const float* lv3 = lin_dst + (3 - nt) * C_;
    float linv[4][8];
#pragma unroll
    for (int t = 0; t < 8; ++t) {
        int col = t * 16 + mloc;
        linv[0][t] = lv0[col]; linv[1][t] = lv1[col];
        linv[2][t] = lv2[col]; linv[3][t] = lv3[col];
    }
    const int et0 = nt, et1 = 2 + nt, et2 = nt, et3 = 3 - nt;
#pragma unroll
    for (int h = 0; h < 2; ++h)
#pragma unroll
        for (int r = 0; r < 4; ++r) {
            int row = rbase + h * 16 + r;
            bool ok = (row < N_);
            float p0 = 0.f, p1 = 0.f, p2 = 0.f, p3 = 0.f;
#pragma unroll
            for (int t = 0; t < 8; ++t) {
                int col = t * 16 + mloc;
                float vv = acc[h][t][r] + bias[col];
                if (ok) out[(size_t)row * C_ + col] = vv;
                p0 = fmaf(vv, linv[0][t], p0);
                p1 = fmaf(vv, linv[1][t], p1);
                p2 = fmaf(vv, linv[2][t], p2);
                p3 = fmaf(vv, linv[3][t], p3);
            }
#pragma unroll
            for (int m = 1; m < 16; m <<= 1) {
                p0 += __shfl_xor(p0, m);
                p1 += __shfl_xor(p1, m);
                p2 += __shfl_xor(p2, m);
                p3 += __shfl_xor(p3, m);
            }
            if (mloc == 0 && ok) {
                asrc[(size_t)(b * T_ + et0) * N_ + row] = p0;
                asrc[(size_t)(b * T_ + et1) * N_ + row] = p1;
                adst[(size_t)(b * T_ + et2) * N_ + row] = p2;
                adst[(size_t)(b * T_ + et3) * N_ + row] = p3;
            }
        }
}

// Exclusive scan of 4-aligned strides -> CSR offsets; zero pad slots.
__global__ __launch_bounds__(256) void scan_kernel(const int* __restrict__ count,
                                                   int* __restrict__ offs,
                                                   int* __restrict__ ssrc,
                                                   float* __restrict__ pw)
{
    int be = blockIdx.x;
    const int* cnt = count + (size_t)be * N_;
    int* off = offs + (size_t)be * (N_ + 1);
    __shared__ int sums[256];
    int tid = threadIdx.x;
    const int chunk = (N_ + 255) / 256;  // 20
    int lo = tid * chunk, hi = min(lo + chunk, N_);
    int s = 0;
    for (int i = lo; i < hi; ++i) s += (cnt[i] + 3) & ~3;
    sums[tid] = s;
    __syncthreads();
    for (int d = 1; d < 256; d <<= 1) {
        int v = (tid >= d) ? sums[tid - d] : 0;
        __syncthreads();
        sums[tid] += v;
        __syncthreads();
    }
    int run = (tid > 0) ? sums[tid - 1] : 0;
    float2* pwp = (float2*)pw;
    for (int i = lo; i < hi; ++i) {
        off[i] = run;
        int c = cnt[i], pc = (c + 3) & ~3;
        for (int k = c; k < pc; ++k) {
            int pos = run + k;
            ssrc[(size_t)be * EP_ + pos] = 0;
            pwp[(size_t)be * EP_ + pos] = make_float2(0.f, 0.f);
        }
        run += pc;
    }
    if (tid == 255) off[N_] = sums[255];
}

// scatter + yji hybrid: blocks [0,2048) scatter ; [2048,2688) yji — both XCD-pinned
// by pair (blk & 7 == be), matching aggregate's mapping so G/CSR stay in one L2.
// yji roles: 0 -> G = interleaved bf16 {Z=xs*(xs@Wj), xs} ; 1 -> Yi (bf16)
__global__ __launch_bounds__(256) void sy_kernel(
    const int* __restrict__ eidx, const float* __restrict__ ew,
    const float* __restrict__ asrc, const float* __restrict__ adst,
    const int* __restrict__ offs, int* __restrict__ cursor,
    int* __restrict__ ssrc, float* __restrict__ pw,
    const float* __restrict__ xn,
    const unsigned short* __restrict__ wph, const unsigned short* __restrict__ wpl,
    const float* __restrict__ bias_i,
    unsigned short* __restrict__ G, unsigned short* __restrict__ YiB)
{
    int blk = blockIdx.x;
    if (blk < 2048) {
        int be = blk & 7;             // XCD-pin
        int et = be & 3, b = be >> 2;
        int e = (blk >> 3) * 256 + threadIdx.x;
        size_t ebase = ((size_t)et * B_ + b) * 2 * E_;
        int src = eidx[ebase + e];
        int dst = eidx[ebase + E_ + e];
        float al = asrc[(size_t)be * N_ + src] + adst[(size_t)be * N_ + dst];
        al = (al > 0.f) ? al : 0.2f * al;
        float p = __expf(al);
        float w = ew[((size_t)et * B_ + b) * E_ + e];
        int pos = offs[(size_t)be * (N_ + 1) + dst] +
                  atomicAdd(&cursor[(size_t)be * N_ + dst], 1);
        ssrc[(size_t)be * EP_ + pos] = src;
        ((float2*)pw)[(size_t)be * EP_ + pos] = make_float2(p, p * w);
        return;
    }
    int yidx = blk - 2048;            // 0..639 ; (yidx & 7) == blk & 7 (2048 % 8 == 0)
    int be = yidx & 7;                // XCD-pin: same pair -> same XCD as scatter/aggregate
    int et = be & 3, b = be >> 2;
    int rest = yidx >> 3;             // 0..79
    int role = rest & 1;
    int bx = rest >> 1;               // 0..39
    int s_t = et & 1, d_t = ((et + 1) >> 1) & 1;
    int ntsel = (role == 0) ? s_t : d_t;
    const float* A = xn + (size_t)(b * 2 + ntsel) * N_ * C_;
    int slot = (role == 0) ? 2 + et : 6 + et;
    ffrag acc[2][8];
    zero_acc(acc);
    mfma128(A, wph + SLOT(slot), wpl + SLOT(slot), acc, bx);
    const float* bias = bias_i + et * C_;
    const int wave = threadIdx.x >> 6, lane = threadIdx.x & 63;
    const int mloc = lane & 15, quad = lane >> 4;
    const int rbase = bx * 128 + wave * 32 + quad * 4;
#pragma unroll
    for (int h = 0; h < 2; ++h)
#pragma unroll
        for (int r = 0; r < 4; ++r) {
            int row = rbase + h * 16 + r;
            if (row >= N_) continue;
#pragma unroll
            for (int t = 0; t < 8; ++t) {
                int col = t * 16 + mloc;
                float v = acc[h][t][r];
                if (role == 0) {
                    float xv = A[(size_t)row * C_ + col];
                    *(ushort2*)(G + ((size_t)be * N_ + row) * 256 + 2 * col) =
                        make_ushort2(f2bf(v * xv), f2bf(xv));
                } else {
                    YiB[((size_t)be * N_ + row) * C_ + col] = f2bf(v + bias[col]);
                }
            }
        }
}

// Segment-softmax aggregation, one wave per (node, et, b), XCD-pinned by pair.
// aggr = (Σ p·Z[s] + Yi'⊙Σ p·xs + v1⊙Σ q·xs) / Σ p, emitted as bf16.
__global__ __launch_bounds__(256) void aggregate_kernel(
    const unsigned short* __restrict__ G, const unsigned short* __restrict__ YiB,
    const float* __restrict__ v1, const float* __restrict__ pw,
    const int* __restrict__ ssrc, const int* __restrict__ offs,
    unsigned short* __restrict__ aggrB)
{
    int pair = blockIdx.x & 7;                       // = b*T_+et (XCD-pin)
    int n = (blockIdx.x >> 3) * 4 + (threadIdx.x >> 6);
    int et = pair & 3;
    int be = pair;
    int l = threadIdx.x & 63;
    const unsigned short* Gp = G + (size_t)be * N_ * 256;
    int beg = offs[(size_t)be * (N_ + 1) + n];
    int end = offs[(size_t)be * (N_ + 1) + n + 1];
    const int* sp = ssrc + (size_t)be * EP_ + beg;
    const float* pwp = pw + ((size_t)be * EP_ + beg) * 2;
    float a1x = 0.f, a1y = 0.f, a2x = 0.f, a2y = 0.f, a3x = 0.f, a3y = 0.f, denom = 0.f;
    int cnt = end - beg;  // multiple of 4; pads have p=q=0, ssrc=0
    for (int i = 0; i < cnt; i += 4) {
        int4 ss = *(const int4*)(sp + i);
        float4 pq0 = *(const float4*)(pwp + 2 * i);      // p0 q0 p1 q1
        float4 pq1 = *(const float4*)(pwp + 2 * i + 4);  // p2 q2 p3 q3
        ushort4 g0 = *(const ushort4*)(Gp + (size_t)ss.x * 256 + 4 * l);
        ushort4 g1 = *(const ushort4*)(Gp + (size_t)ss.y * 256 + 4 * l);
        ushort4 g2 = *(const ushort4*)(Gp + (size_t)ss.z * 256 + 4 * l);
        ushort4 g3 = *(const ushort4*)(Gp + (size_t)ss.w * 256 + 4 * l);
        denom += pq0.x + pq0.z + pq1.x + pq1.z;
        a1x = fmaf(pq0.x, bf2f(g0.x), a1x); a2x = fmaf(pq0.x, bf2f(g0.y), a2x);
        a3x = fmaf(pq0.y, bf2f(g0.y), a3x);
        a1y = fmaf(pq0.x, bf2f(g0.z), a1y); a2y = fmaf(pq0.x, bf2f(g0.w), a2y);
        a3y = fmaf(pq0.y, bf2f(g0.w), a3y);
        a1x = fmaf(pq0.z, bf2f(g1.x), a1x); a2x = fmaf(pq0.z, bf2f(g1.y), a2x);
        a3x = fmaf(pq0.w, bf2f(g1.y), a3x);
        a1y = fmaf(pq0.z, bf2f(g1.z), a1y); a2y = fmaf(pq0.z, bf2f(g1.w), a2y);
        a3y = fmaf(pq0.w, bf2f(g1.w), a3y);
        a1x = fmaf(pq1.x, bf2f(g2.x), a1x); a2x = fmaf(pq1.x, bf2f(g2.y), a2x);
        a3x = fmaf(pq1.y, bf2f(g2.y), a3x);
        a1y = fmaf(pq1.x, bf2f(g2.z), a1y); a2y = fmaf(pq1.x, bf2f(g2.w), a2y);
        a3y = fmaf(pq1.y, bf2f(g2.w), a3y);
        a1x = fmaf(pq1.z, bf2f(g3.x), a1x); a2x = fmaf(pq1.z, bf2f(g3.y), a2x);
        a3x = fmaf(pq1.w, bf2f(g3.y), a3x);
        a1y = fmaf(pq1.z, bf2f(g3.z), a1y); a2y = fmaf(pq1.z, bf2f(g3.w), a2y);
        a3y = fmaf(pq1.w, bf2f(g3.w), a3y);
    }
    ushort2 yiu = *(const ushort2*)(YiB + ((size_t)be * N_ + n) * C_ + 2 * l);
    float2 vv = *(const float2*)(v1 + et * C_ + 2 * l);
    float inv = (denom > 0.f) ? 1.f / denom : 0.f;
    float ox = (a1x + bf2f(yiu.x) * a2x + vv.x * a3x) * inv;
    float oy = (a1y + bf2f(yiu.y) * a2y + vv.y * a3y) * inv;
    *(ushort2*)(aggrB + ((size_t)be * N_ + n) * C_ + 2 * l) = make_ushort2(f2bf(ox), f2bf(oy));
}

// outs = tanh(relu(aggr @ W1 + xn[d_t] @ W2 + agg_b)), emitted as bf16.
__global__ __launch_bounds__(256) void agg_mfma(const unsigned short* __restrict__ aggrB,
                                                const float* __restrict__ xn,
                                                const unsigned short* __restrict__ wph,
                                                const unsigned short* __restrict__ wpl,
                                                const float* __restrict__ agg_b,
                                                unsigned short* __restrict__ outsB)
{
    int et = blockIdx.y, b = blockIdx.z;
    int bx = blockIdx.x;
    int d_t = ((et + 1) >> 1) & 1;
    size_t base = (size_t)(b * T_ + et) * N_ * C_;
    ffrag acc[2][8];
    zero_acc(acc);
    mfma128_bfA(aggrB + base, wph + SLOT(10 + et), wpl + SLOT(10 + et), acc, bx);
    mfma128(xn + (size_t)(b * 2 + d_t) * N_ * C_, wph + SLOT(14 + et), wpl + SLOT(14 + et),
            acc, bx);
    const float* bias = agg_b + et * C_;
    const int wave = threadIdx.x >> 6, lane = threadIdx.x & 63;
    const int mloc = lane & 15, quad = lane >> 4;
    const int rbase = bx * 128 + wave * 32 + quad * 4;
#pragma unroll
    for (int h = 0; h < 2; ++h)
#pragma unroll
        for (int r = 0; r < 4; ++r) {
            int row = rbase + h * 16 + r;
            if (row >= N_) continue;
#pragma unroll
            for (int t = 0; t < 8; ++t) {
                int col = t * 16 + mloc;
                float v = acc[h][t][r] + bias[col];
                v = (v > 0.f) ? tanhf(v) : 0.f;
                outsB[base + (size_t)row * C_ + col] = f2bf(v);
            }
        }
}

#define KLIN_BLOCKS (40 * 4 * B_)

// colsum += Σ_n tanh(outs[et] @ klin[nt] + klin_b[nt]) ; last block computes attn.
__global__ __launch_bounds__(256) void klin_mfma(const unsigned short* __restrict__ outsB,
                                                 const unsigned short* __restrict__ wph,
                                                 const unsigned short* __restrict__ wpl,
                                                 const float* __restrict__ klin_b,
                                                 const float* __restrict__ q,
                                                 float* __restrict__ colsum,
                                                 int* __restrict__ done,
                                                 float* __restrict__ attn)
{
    int g = blockIdx.y, b = blockIdx.z;
    int bx = blockIdx.x;
    int nt = g >> 1, tt = g & 1;
    int et = (tt == 0) ? nt : 3 - nt;
    size_t abase = (size_t)(b * T_ + et) * N_ * C_;
    ffrag acc[2][8];
    zero_acc(acc);
    mfma128_bfA(outsB + abase, wph + SLOT(18 + nt), wpl + SLOT(18 + nt), acc, bx);
    __shared__ float cs[128];
    if (threadIdx.x < 128) cs[threadIdx.x] = 0.f;
    __syncthreads();
    const int wave = threadIdx.x >> 6, lane = threadIdx.x & 63;
    const int mloc = lane & 15, quad = lane >> 4;
    const int rbase = bx * 128 + wave * 32 + quad * 4;
#pragma unroll
    for (int t = 0; t < 8; ++t) {
        int col = t * 16 + mloc;
        float bv = klin_b[nt * C_ + col];
        float s = 0.f;
#pragma unroll
        for (int h = 0; h < 2; ++h)
#pragma unroll
            for (int r = 0; r < 4; ++r) {
                int row = rbase + h * 16 + r;
                if (row < N_) s += tanhf(acc[h][t][r] + bv);
            }
        atomicAdd(&cs[col], s);
    }
    __syncthreads();
    if (threadIdx.x < 128)
        atomicAdd(&colsum[(size_t)((b * 2 + nt) * 2 + tt) * C_ + threadIdx.x], cs[threadIdx.x]);
    // last-block score fusion
    __shared__ int isLast;
    if (threadIdx.x == 0) {
        __threadfence();
        isLast = (atomicAdd(done, 1) == KLIN_BLOCKS - 1) ? 1 : 0;
    }
    __syncthreads();
    if (!isLast) return;
    __shared__ float red[2][2];
    for (int bnt = 0; bnt < 4; ++bnt) {
        int ntl = bnt & 1;
        float v0 = 0.f, v1 = 0.f;
        if (threadIdx.x < 128) {
            int c = threadIdx.x;
            float qc = q[ntl * C_ + c];
            float c0 = atomicAdd(&colsum[(size_t)(bnt * 2 + 0) * C_ + c], 0.f);
            float c1 = atomicAdd(&colsum[(size_t)(bnt * 2 + 1) * C_ + c], 0.f);
            v0 = qc * c0;
            v1 = qc * c1;
        }
#pragma unroll
        for (int m = 32; m > 0; m >>= 1) {
            v0 += __shfl_down(v0, m);
            v1 += __shfl_down(v1, m);
        }
        if ((threadIdx.x & 63) == 0 && wave < 2) {
            red[wave][0] = v0;
            red[wave][1] = v1;
        }
        __syncthreads();
        if (threadIdx.x == 0) {
            float s0 = (red[0][0] + red[1][0]) / (float)N_;
            float s1 = (red[0][1] + red[1][1]) / (float)N_;
            float mx = fmaxf(s0, s1);
            float e0 = __expf(s0 - mx), e1 = __expf(s1 - mx);
            float invd = 1.f / (e0 + e1);
            attn[bnt * 2 + 0] = e0 * invd;
            attn[bnt * 2 + 1] = e1 * invd;
        }
        __syncthreads();
    }
}

__global__ void output_kernel(const unsigned short* __restrict__ outsB,
                              const float* __restrict__ attn,
                              float* __restrict__ out)
{
    int idx = blockIdx.x * blockDim.x + threadIdx.x;
    int c4 = idx & 31;
    int row = idx >> 5;
    int b = row / TWO_N;
    int r = row % TWO_N;
    int nt = (r >= N_) ? 1 : 0;
    int n = r - nt * N_;
    int et0 = nt, et1 = 3 - nt;
    float a0 = attn[(b * 2 + nt) * 2 + 0];
    float a1 = attn[(b * 2 + nt) * 2 + 1];
    const ushort4* o0 = (const ushort4*)(outsB + ((size_t)(b * T_ + et0) * N_ + n) * C_);
    const ushort4* o1 = (const ushort4*)(outsB + ((size_t)(b * T_ + et1) * N_ + n) * C_);
    ushort4 u0 = o0[c4], u1 = o1[c4];
    float4 o;
    o.x = a0 * bf2f(u0.x) + a1 * bf2f(u1.x);
    o.y = a0 * bf2f(u0.y) + a1 * bf2f(u1.y);
    o.z = a0 * bf2f(u0.z) + a1 * bf2f(u1.z);
    o.w = a0 * bf2f(u0.w) + a1 * bf2f(u1.w);
    ((float4*)out)[idx] = o;
}

extern "C" void kernel_launch(void* const* d_in, const int* in_sizes, int n_in,
                              void* d_out, int out_size, void* d_ws, size_t ws_size,
                              hipStream_t stream)
{
    const float* x       = (const float*)d_in[0];
    const int*   eidx    = (const int*)d_in[1];
    const float* ew      = (const float*)d_in[2];
    const float* proj_w  = (const float*)d_in[3];
    const float* proj_b  = (const float*)d_in[4];
    const float* q       = (const float*)d_in[5];
    const float* klin_w  = (const float*)d_in[6];
    const float* klin_b  = (const float*)d_in[7];
    const float* lin_src = (const float*)d_in[8];
    const float* lin_dst = (const float*)d_in[9];
    const float* eproj_w = (const float*)d_in[10];
    const float* eproj_b = (const float*)d_in[11];
    const float* agg_w   = (const float*)d_in[12];
    const float* agg_b   = (const float*)d_in[13];
    const float* att_w   = (const float*)d_in[14];
    const float* att_b   = (const float*)d_in[15];

    float* ws = (float*)d_ws;
    size_t o = 0;
    float* xn     = ws + o; o += 2560000;   // live proj -> agg_mfma
    float* GU     = ws + o; o += 5120000;   // G (bf16, sy->aggregate) ∪ outsB (bf16)
    float* YiBf   = ws + o; o += 2560000;   // Yi bf16
    float* aggrBf = ws + o; o += 2560000;   // bf16 aggr
    float* pw     = ws + o; o += 2 * 8 * EP_;      // 1,310,720
    int*   ssrc   = (int*)(ws + o); o += 8 * EP_;  //   655,360
    float* asrc   = ws + o; o += 40000;
    float* adst   = ws + o; o += 40000;
    float* v1     = ws + o; o += 512;
    float* bias_i = ws + o; o += 512;
    float* attn   = ws + o; o += 16;
    // zeroed-by-setup region (contiguous ints): count, cursor, colsum, done
    int*   count  = (int*)(ws + o); o += 40000;
    int*   cursor = (int*)(ws + o); o += 40000;
    float* colsum = ws + o; o += 1024;
    int*   done   = (int*)(ws + o); o += 4;
    int*   offs   = (int*)(ws + o); o += 40008;
    unsigned short* wph = (unsigned short*)(ws + o); o += 163840;
    unsigned short* wpl = (unsigned short*)(ws + o); o += 163840;
    unsigned short* lph = (unsigned short*)(ws + o); o += 1024;
    unsigned short* lpl = (unsigned short*)(ws + o); o += 1024;
    // total ≈ 15.3M floats ≈ 61 MB

    unsigned short* G     = (unsigned short*)GU;
    unsigned short* outsB = (unsigned short*)GU;
    unsigned short* YiB   = (unsigned short*)YiBf;
    unsigned short* aggrB = (unsigned short*)aggrBf;

    setup_kernel<<<dim3(243), 256, 0, stream>>>(proj_w, att_w, agg_w, klin_w,
                                                lin_src, lin_dst, eproj_w, eproj_b,
                                                att_b, wph, wpl, lph, lpl,
                                                v1, bias_i, count);
    cp_kernel<<<dim3(2208), 256, 0, stream>>>(eidx, count, x, wph, wpl, proj_b,
                                              lin_src, lin_dst, xn, asrc, adst);
    scan_kernel<<<dim3(B_ * T_), 256, 0, stream>>>(count, offs, ssrc, pw);
    sy_kernel<<<dim3(2688), 256, 0, stream>>>(eidx, ew, asrc, adst, offs, cursor,
                                              ssrc, pw, xn, wph, wpl, bias_i,
                                              G, YiB);
    aggregate_kernel<<<dim3(10000), 256, 0, stream>>>(G, YiB, v1, pw, ssrc, offs, aggrB);
    agg_mfma<<<dim3(40, T_, B_), 256, 0, stream>>>(aggrB, xn, wph, wpl, agg_b, outsB);
    klin_mfma<<<dim3(40, 4, B_), 256, 0, stream>>>(outsB, wph, wpl, klin_b, q,
                                                   colsum, done, attn);
    output_kernel<<<dim3(2500), 256, 0, stream>>>(outsB, attn, (float*)d_out);
}

// Round 9
// 296.189 us; speedup vs baseline: 1.7610x; 1.0442x over previous
//
#include <hip/hip_runtime.h>
#include <math.h>

// Problem constants (from reference setup_inputs)
#define B_    2
#define N_    5000
#define C_    128
#define E_    65536
#define T_    4
#define TWO_N 10000
#define EP_   81920   // padded CSR capacity per (et,b)

// edge types: (src,dst) node types = (0,0),(1,1),(0,1),(1,0)
// s_t = et & 1 ; d_t = ((et+1)>>1) & 1
// XCD-pin convention: pair be = b*4+et == blockIdx.x & 7 for every kernel
// touching per-pair edge data (count, scatter, yji, aggregate, aggklin).
// CSR entry (8 B): uint2 { p fp32 ; (q_bf16 << 16) | src_u16 }

__device__ __forceinline__ unsigned short f2bf(float f) {
    unsigned u = __float_as_uint(f);
    u += 0x7fffu + ((u >> 16) & 1u);   // RNE
    return (unsigned short)(u >> 16);
}
__device__ __forceinline__ float bf2f(unsigned short h) {
    return __uint_as_float(((unsigned)h) << 16);
}

typedef __attribute__((ext_vector_type(8))) short bfrag;   // 8 bf16
typedef __attribute__((ext_vector_type(4))) float ffrag;   // 4 fp32 acc

__device__ __forceinline__ void split8(const float* __restrict__ p, bfrag& hi, bfrag& lo) {
#pragma unroll
    for (int j = 0; j < 8; ++j) {
        float v = p[j];
        unsigned short h = f2bf(v);
        hi[j] = (short)h;
        lo[j] = (short)f2bf(v - bf2f(h));
    }
}

// Weight slots (each 128x128, B-fragment packed):
// 0-1: proj ; 2-5: Wj[et] ; 6-9: Wi[et] ; 10-13: W1[et] ; 14-17: W2[et] ; 18-19: klin[nt]
#define SLOT(i) ((size_t)(i) * 16384)

__device__ __forceinline__ void zero_acc(ffrag (&acc)[2][8]) {
#pragma unroll
    for (int h = 0; h < 2; ++h)
#pragma unroll
        for (int t = 0; t < 8; ++t) acc[h][t] = (ffrag){0.f, 0.f, 0.f, 0.f};
}

// Split-bf16 MFMA GEMM core, K=128, 4 waves x 32 rows, N=128. fp32 A.
__device__ __forceinline__ void mfma128(const float* __restrict__ A,
                                        const unsigned short* __restrict__ Whi,
                                        const unsigned short* __restrict__ Wlo,
                                        ffrag (&acc)[2][8], int bx)
{
    const int wave = threadIdx.x >> 6, lane = threadIdx.x & 63;
    const int mloc = lane & 15, quad = lane >> 4;
    const int row0w = bx * 128 + wave * 32;
    int r0 = row0w + mloc;      if (r0 >= N_) r0 = N_ - 1;  // clamp, stores guarded
    int r1 = row0w + 16 + mloc; if (r1 >= N_) r1 = N_ - 1;
#pragma unroll
    for (int s = 0; s < 4; ++s) {
        bfrag a0h, a0l, a1h, a1l;
        split8(A + (size_t)r0 * C_ + s * 32 + quad * 8, a0h, a0l);
        split8(A + (size_t)r1 * C_ + s * 32 + quad * 8, a1h, a1l);
        const unsigned short* pBh = Whi + ((size_t)s * 512 + lane) * 8;
        const unsigned short* pBl = Wlo + ((size_t)s * 512 + lane) * 8;
#pragma unroll
        for (int t = 0; t < 8; ++t) {
            bfrag bh = *(const bfrag*)(pBh + (size_t)t * 512);
            bfrag bl = *(const bfrag*)(pBl + (size_t)t * 512);
            acc[0][t] = __builtin_amdgcn_mfma_f32_16x16x32_bf16(a0h, bh, acc[0][t], 0, 0, 0);
            acc[0][t] = __builtin_amdgcn_mfma_f32_16x16x32_bf16(a0l, bh, acc[0][t], 0, 0, 0);
            acc[0][t] = __builtin_amdgcn_mfma_f32_16x16x32_bf16(a0h, bl, acc[0][t], 0, 0, 0);
            acc[1][t] = __builtin_amdgcn_mfma_f32_16x16x32_bf16(a1h, bh, acc[1][t], 0, 0, 0);
            acc[1][t] = __builtin_amdgcn_mfma_f32_16x16x32_bf16(a1l, bh, acc[1][t], 0, 0, 0);
            acc[1][t] = __builtin_amdgcn_mfma_f32_16x16x32_bf16(a1h, bl, acc[1][t], 0, 0, 0);
        }
    }
}

// Half-width core: only 4 of 8 n-tiles (cols [half*64, half*64+64)). fp32 A.
__device__ __forceinline__ void mfma128_half(const float* __restrict__ A,
                                             const unsigned short* __restrict__ Whi,
                                             const unsigned short* __restrict__ Wlo,
                                             ffrag (&acc)[2][4], int bx, int half)
{
    const int wave = threadIdx.x >> 6, lane = threadIdx.x & 63;
    const int mloc = lane & 15, quad = lane >> 4;
    const int row0w = bx * 128 + wave * 32;
    int r0 = row0w + mloc;      if (r0 >= N_) r0 = N_ - 1;
    int r1 = row0w + 16 + mloc; if (r1 >= N_) r1 = N_ - 1;
#pragma unroll
    for (int s = 0; s < 4; ++s) {
        bfrag a0h, a0l, a1h, a1l;
        split8(A + (size_t)r0 * C_ + s * 32 + quad * 8, a0h, a0l);
        split8(A + (size_t)r1 * C_ + s * 32 + quad * 8, a1h, a1l);
        const unsigned short* pBh = Whi + ((size_t)s * 512 + (size_t)half * 256 + lane) * 8;
        const unsigned short* pBl = Wlo + ((size_t)s * 512 + (size_t)half * 256 + lane) * 8;
#pragma unroll
        for (int t = 0; t < 4; ++t) {
            bfrag bh = *(const bfrag*)(pBh + (size_t)t * 512);
            bfrag bl = *(const bfrag*)(pBl + (size_t)t * 512);
            acc[0][t] = __builtin_amdgcn_mfma_f32_16x16x32_bf16(a0h, bh, acc[0][t], 0, 0, 0);
            acc[0][t] = __builtin_amdgcn_mfma_f32_16x16x32_bf16(a0l, bh, acc[0][t], 0, 0, 0);
            acc[0][t] = __builtin_amdgcn_mfma_f32_16x16x32_bf16(a0h, bl, acc[0][t], 0, 0, 0);
            acc[1][t] = __builtin_amdgcn_mfma_f32_16x16x32_bf16(a1h, bh, acc[1][t], 0, 0, 0);
            acc[1][t] = __builtin_amdgcn_mfma_f32_16x16x32_bf16(a1l, bh, acc[1][t], 0, 0, 0);
            acc[1][t] = __builtin_amdgcn_mfma_f32_16x16x32_bf16(a1h, bl, acc[1][t], 0, 0, 0);
        }
    }
}

// bf16-A core (single, no split): D = A @ (Wh + Wl).
__device__ __forceinline__ void mfma128_bfA(const unsigned short* __restrict__ A,
                                            const unsigned short* __restrict__ Whi,
                                            const unsigned short* __restrict__ Wlo,
                                            ffrag (&acc)[2][8], int bx)
{
    const int wave = threadIdx.x >> 6, lane = threadIdx.x & 63;
    const int mloc = lane & 15, quad = lane >> 4;
    const int row0w = bx * 128 + wave * 32;
    int r0 = row0w + mloc;      if (r0 >= N_) r0 = N_ - 1;
    int r1 = row0w + 16 + mloc; if (r1 >= N_) r1 = N_ - 1;
#pragma unroll
    for (int s = 0; s < 4; ++s) {
        bfrag a0 = *(const bfrag*)(A + (size_t)r0 * C_ + s * 32 + quad * 8);
        bfrag a1 = *(const bfrag*)(A + (size_t)r1 * C_ + s * 32 + quad * 8);
        const unsigned short* pBh = Whi + ((size_t)s * 512 + lane) * 8;
        const unsigned short* pBl = Wlo + ((size_t)s * 512 + lane) * 8;
#pragma unroll
        for (int t = 0; t < 8; ++t) {
            bfrag bh = *(const bfrag*)(pBh + (size_t)t * 512);
            bfrag bl = *(const bfrag*)(pBl + (size_t)t * 512);
            acc[0][t] = __builtin_amdgcn_mfma_f32_16x16x32_bf16(a0, bh, acc[0][t], 0, 0, 0);
            acc[0][t] = __builtin_amdgcn_mfma_f32_16x16x32_bf16(a0, bl, acc[0][t], 0, 0, 0);
            acc[1][t] = __builtin_amdgcn_mfma_f32_16x16x32_bf16(a1, bh, acc[1][t], 0, 0, 0);
            acc[1][t] = __builtin_amdgcn_mfma_f32_16x16x32_bf16(a1, bl, acc[1][t], 0, 0, 0);
        }
    }
}

#define ZN_ 81028   // count(40000) + cursor(40000) + colsum(1024) + done(4)

// setup: blocks [0,160) pack_w ; [160] pack_L ; [161,163) prep ; [163,243) zero
__global__ __launch_bounds__(256) void setup_kernel(
    const float* __restrict__ proj_w, const float* __restrict__ att_w,
    const float* __restrict__ agg_w, const float* __restrict__ klin_w,
    const float* __restrict__ lin_src, const float* __restrict__ lin_dst,
    const float* __restrict__ eproj_w, const float* __restrict__ eproj_b,
    const float* __restrict__ att_b,
    unsigned short* __restrict__ wh, unsigned short* __restrict__ wl,
    unsigned short* __restrict__ lph, unsigned short* __restrict__ lpl,
    float* __restrict__ v1, float* __restrict__ bias_i, int* __restrict__ zbase)
{
    int blk = blockIdx.x;
    if (blk < 160) {
        int wave = threadIdx.x >> 6, lane = threadIdx.x & 63;
        int unit = blk * 4 + wave;      // 0..639
        int id = unit >> 5;             // slot 0..19
        int st = unit & 31;
        int s = st >> 3, t = st & 7;
        const float* src;
        if (id < 2)       src = proj_w + (size_t)id * 16384;
        else if (id < 6)  src = att_w + (size_t)(id - 2) * 384 * C_;
        else if (id < 10) src = att_w + (size_t)(id - 6) * 384 * C_ + (size_t)128 * C_;
        else if (id < 14) src = agg_w + (size_t)(id - 10) * 256 * C_;
        else if (id < 18) src = agg_w + (size_t)(id - 14) * 256 * C_ + (size_t)128 * C_;
        else              src = klin_w + (size_t)(id - 18) * 16384;
        int mloc = lane & 15, quad = lane >> 4;
        size_t dbase = SLOT(id) + ((size_t)(s * 8 + t) * 64 + lane) * 8;
#pragma unroll
        for (int j = 0; j < 8; ++j) {
            float v = src[(size_t)(s * 32 + quad * 8 + j) * C_ + t * 16 + mloc];
            unsigned short h = f2bf(v);
            wh[dbase + j] = h;
            wl[dbase + j] = f2bf(v - bf2f(h));
        }
    } else if (blk == 160) {
        int s = threadIdx.x >> 6;       // wave = s (0..3)
        int lane = threadIdx.x & 63;
        int mloc = lane & 15, quad = lane >> 4;
        const float* vec = nullptr;
        if (mloc < 8) {
            int nt = mloc >> 2, idx = mloc & 3;
            if (idx == 0)      vec = lin_src + nt * C_;
            else if (idx == 1) vec = lin_src + (nt + 2) * C_;
            else if (idx == 2) vec = lin_dst + nt * C_;
            else               vec = lin_dst + (3 - nt) * C_;
        }
        size_t dbase = ((size_t)(s * 64) + lane) * 8;
#pragma unroll
        for (int j = 0; j < 8; ++j) {
            float v = vec ? vec[s * 32 + quad * 8 + j] : 0.f;
            unsigned short h = f2bf(v);
            lph[dbase + j] = h;
            lpl[dbase + j] = f2bf(v - bf2f(h));
        }
    } else if (blk < 163) {
        int et = (blk - 161) * 2 + (threadIdx.x >> 7);
        int c = threadIdx.x & 127;
        float s1 = 0.f, s0 = 0.f;
        for (int k = 0; k < 128; ++k) {
            float wv = att_w[(size_t)et * 384 * C_ + (size_t)(256 + k) * C_ + c];
            s1 = fmaf(eproj_w[et * C_ + k], wv, s1);
            s0 = fmaf(eproj_b[et * C_ + k], wv, s0);
        }
        v1[et * C_ + c] = s1;
        bias_i[et * C_ + c] = att_b[et * C_ + c] + s0;
    } else {
        int base = (blk - 163) * 1024 + threadIdx.x * 4;
#pragma unroll
        for (int j = 0; j < 4; ++j)
            if (base + j < ZN_) zbase[base + j] = 0;
    }
}

// count + proj(+nodedot) hybrid: blocks [0,2048) count (XCD-pinned) ; [2048,2208) proj
__global__ __launch_bounds__(256) void cp_kernel(
    const int* __restrict__ eidx, int* __restrict__ count,
    const float* __restrict__ x,
    const unsigned short* __restrict__ wph, const unsigned short* __restrict__ wpl,
    const float* __restrict__ proj_b,
    const float* __restrict__ lin_src, const float* __restrict__ lin_dst,
    float* __restrict__ xn, float* __restrict__ asrc, float* __restrict__ adst)
{
    int blk = blockIdx.x;
    if (blk < 2048) {
        int be = blk & 7;             // XCD-pin: pair = b*4+et
        int et = be & 3, b = be >> 2;
        int e = (blk >> 3) * 256 + threadIdx.x;
        int dst = eidx[(((size_t)et * B_ + b) * 2 + 1) * E_ + e];
        atomicAdd(&count[(size_t)be * N_ + dst], 1);
        return;
    }
    int pidx = blk - 2048;            // 0..159
    int bx = pidx % 40;
    int nt = (pidx / 40) & 1;
    int b = pidx / 80;
    const float* A = x + ((size_t)b * TWO_N + (size_t)nt * N_) * C_;
    ffrag acc[2][8];
    zero_acc(acc);
    mfma128(A, wph + SLOT(nt), wpl + SLOT(nt), acc, bx);
    float* out = xn + (size_t)(b * 2 + nt) * N_ * C_;
    const float* bias = proj_b + nt * C_;
    const int wave = threadIdx.x >> 6, lane = threadIdx.x & 63;
    const int mloc = lane & 15, quad = lane >> 4;
    const int rbase = bx * 128 + wave * 32 + quad * 4;
    // lin columns for the fused nodedot
    const float* lv0 = lin_src + nt * C_;
    const float* lv1 = lin_src + (2 + nt) * C_;
    const float* lv2 = lin_dst + nt * C_;
    const float* lv3 = lin_dst + (3 - nt) * C_;
    float linv[4][8];
#pragma unroll
    for (int t = 0; t < 8; ++t) {
        int col = t * 16 + mloc;
        linv[0][t] = lv0[col]; linv[1][t] = lv1[col];
        linv[2][t] = lv2[col]; linv[3][t] = lv3[col];
    }
    const int et0 = nt, et1 = 2 + nt, et2 = nt, et3 = 3 - nt;
#pragma unroll
    for (int h = 0; h < 2; ++h)
#pragma unroll
        for (int r = 0; r < 4; ++r) {
            int row = rbase + h * 16 + r;
            bool ok = (row < N_);
            float p0 = 0.f, p1 = 0.f, p2 = 0.f, p3 = 0.f;
#pragma unroll
            for (int t = 0; t < 8; ++t) {
                int col = t * 16 + mloc;
                float vv = acc[h][t][r] + bias[col];
                if (ok) out[(size_t)row * C_ + col] = vv;
                p0 = fmaf(vv, linv[0][t], p0);
                p1 = fmaf(vv, linv[1][t], p1);
                p2 = fmaf(vv, linv[2][t], p2);
                p3 = fmaf(vv, linv[3][t], p3);
            }
#pragma unroll
            for (int m = 1; m < 16; m <<= 1) {
                p0 += __shfl_xor(p0, m);
                p1 += __shfl_xor(p1, m);
                p2 += __shfl_xor(p2, m);
                p3 += __shfl_xor(p3, m);
            }
            if (mloc == 0 && ok) {
                asrc[(size_t)(b * T_ + et0) * N_ + row] = p0;
                asrc[(size_t)(b * T_ + et1) * N_ + row] = p1;
                adst[(size_t)(b * T_ + et2) * N_ + row] = p2;
                adst[(size_t)(b * T_ + et3) * N_ + row] = p3;
            }
        }
}

// Exclusive scan of 4-aligned strides -> CSR offsets; zero pad slots.
__global__ __launch_bounds__(256) void scan_kernel(const int* __restrict__ count,
                                                   int* __restrict__ offs,
                                                   unsigned int* __restrict__ pwq)
{
    int be = blockIdx.x;
    const int* cnt = count + (size_t)be * N_;
    int* off = offs + (size_t)be * (N_ + 1);
    __shared__ int sums[256];
    int tid = threadIdx.x;
    const int chunk = (N_ + 255) / 256;  // 20
    int lo = tid * chunk, hi = min(lo + chunk, N_);
    int s = 0;
    for (int i = lo; i < hi; ++i) s += (cnt[i] + 3) & ~3;
    sums[tid] = s;
    __syncthreads();
    for (int d = 1; d < 256; d <<= 1) {
        int v = (tid >= d) ? sums[tid - d] : 0;
        __syncthreads();
        sums[tid] += v;
        __syncthreads();
    }
    int run = (tid > 0) ? sums[tid - 1] : 0;
    uint2* ep = (uint2*)pwq;
    for (int i = lo; i < hi; ++i) {
        off[i] = run;
        int c = cnt[i], pc = (c + 3) & ~3;
        for (int k = c; k < pc; ++k)
            ep[(size_t)be * EP_ + run + k] = make_uint2(0u, 0u);
        run += pc;
    }
    if (tid == 255) off[N_] = sums[255];
}

// scatter + yji hybrid: blocks [0,2048) scatter ; [2048,3328) yji — XCD-pinned.
// yji roles: 0 -> G = interleaved bf16 {Z=xs*(xs@Wj), xs} ; 1 -> Yi (bf16);
// each role split into col-halves (64 cols/block).
__global__ __launch_bounds__(256) void sy_kernel(
    const int* __restrict__ eidx, const float* __restrict__ ew,
    const float* __restrict__ asrc, const float* __restrict__ adst,
    const int* __restrict__ offs, int* __restrict__ cursor,
    unsigned int* __restrict__ pwq,
    const float* __restrict__ xn,
    const unsigned short* __restrict__ wph, const unsigned short* __restrict__ wpl,
    const float* __restrict__ bias_i,
    unsigned short* __restrict__ G, unsigned short* __restrict__ YiB)
{
    int blk = blockIdx.x;
    if (blk < 2048) {
        int be = blk & 7;             // XCD-pin
        int et = be & 3, b = be >> 2;
        int e = (blk >> 3) * 256 + threadIdx.x;
        size_t ebase = ((size_t)et * B_ + b) * 2 * E_;
        int src = eidx[ebase + e];
        int dst = eidx[ebase + E_ + e];
        float al = asrc[(size_t)be * N_ + src] + adst[(size_t)be * N_ + dst];
        al = (al > 0.f) ? al : 0.2f * al;
        float p = __expf(al);
        float w = ew[((size_t)et * B_ + b) * E_ + e];
        int pos = offs[(size_t)be * (N_ + 1) + dst] +
                  atomicAdd(&cursor[(size_t)be * N_ + dst], 1);
        unsigned int packed = (unsigned int)src | ((unsigned int)f2bf(p * w) << 16);
        ((uint2*)pwq)[(size_t)be * EP_ + pos] = make_uint2(__float_as_uint(p), packed);
        return;
    }
    int yidx = blk - 2048;            // 0..1279 ; 2048 % 8 == 0 keeps pin aligned
    int be = yidx & 7;                // XCD-pin
    int et = be & 3, b = be >> 2;
    int rest = yidx >> 3;             // 0..159
    int half = rest & 1;
    int role = (rest >> 1) & 1;
    int bx = rest >> 2;               // 0..39
    int s_t = et & 1, d_t = ((et + 1) >> 1) & 1;
    int ntsel = (role == 0) ? s_t : d_t;
    const float* A = xn + (size_t)(b * 2 + ntsel) * N_ * C_;
    int slot = (role == 0) ? 2 + et : 6 + et;
    ffrag acc[2][4];
#pragma unroll
    for (int h = 0; h < 2; ++h)
#pragma unroll
        for (int t = 0; t < 4; ++t) acc[h][t] = (ffrag){0.f, 0.f, 0.f, 0.f};
    mfma128_half(A, wph + SLOT(slot), wpl + SLOT(slot), acc, bx, half);
    const float* bias = bias_i + et * C_;
    const int wave = threadIdx.x >> 6, lane = threadIdx.x & 63;
    const int mloc = lane & 15, quad = lane >> 4;
    const int rbase = bx * 128 + wave * 32 + quad * 4;
#pragma unroll
    for (int h = 0; h < 2; ++h)
#pragma unroll
        for (int r = 0; r < 4; ++r) {
            int row = rbase + h * 16 + r;
            if (row >= N_) continue;
#pragma unroll
            for (int t = 0; t < 4; ++t) {
                int col = (half * 4 + t) * 16 + mloc;
                float v = acc[h][t][r];
                if (role == 0) {
                    float xv = A[(size_t)row * C_ + col];
                    *(ushort2*)(G + ((size_t)be * N_ + row) * 256 + 2 * col) =
                        make_ushort2(f2bf(v * xv), f2bf(xv));
                } else {
                    YiB[((size_t)be * N_ + row) * C_ + col] = f2bf(v + bias[col]);
                }
            }
        }
}

// Segment-softmax aggregation, one wave per (node, et, b), XCD-pinned by pair.
// aggr = (Σ p·Z[s] + Yi'⊙Σ p·xs + v1⊙Σ q·xs) / Σ p, emitted as bf16.
__global__ __launch_bounds__(256) void aggregate_kernel(
    const unsigned short* __restrict__ G, const unsigned short* __restrict__ YiB,
    const float* __restrict__ v1, const unsigned int* __restrict__ pwq,
    const int* __restrict__ offs, unsigned short* __restrict__ aggrB)
{
    int pair = blockIdx.x & 7;                       // = b*T_+et (XCD-pin)
    int n = (blockIdx.x >> 3) * 4 + (threadIdx.x >> 6);
    int et = pair & 3;
    int be = pair;
    int l = threadIdx.x & 63;
    const unsigned short* Gp = G + (size_t)be * N_ * 256;
    int beg = offs[(size_t)be * (N_ + 1) + n];
    int end = offs[(size_t)be * (N_ + 1) + n + 1];
    const unsigned int* ep = pwq + ((size_t)be * EP_ + beg) * 2;
    float a1x = 0.f, a1y = 0.f, a2x = 0.f, a2y = 0.f, a3x = 0.f, a3y = 0.f, denom = 0.f;
    int cnt = end - beg;  // multiple of 4; pads have p=q=0, src=0
    for (int i = 0; i < cnt; i += 4) {
        uint4 u01 = *(const uint4*)(ep + 2 * i);      // entries i, i+1
        uint4 u23 = *(const uint4*)(ep + 2 * i + 4);  // entries i+2, i+3
        float p0 = __uint_as_float(u01.x), q0 = bf2f((unsigned short)(u01.y >> 16));
        float p1 = __uint_as_float(u01.z), q1 = bf2f((unsigned short)(u01.w >> 16));
        float p2 = __uint_as_float(u23.x), q2 = bf2f((unsigned short)(u23.y >> 16));
        float p3 = __uint_as_float(u23.z), q3 = bf2f((unsigned short)(u23.w >> 16));
        int s0 = u01.y & 0xffff, s1 = u01.w & 0xffff;
        int s2 = u23.y & 0xffff, s3 = u23.w & 0xffff;
        ushort4 g0 = *(const ushort4*)(Gp + (size_t)s0 * 256 + 4 * l);
        ushort4 g1 = *(const ushort4*)(Gp + (size_t)s1 * 256 + 4 * l);
        ushort4 g2 = *(const ushort4*)(Gp + (size_t)s2 * 256 + 4 * l);
        ushort4 g3 = *(const ushort4*)(Gp + (size_t)s3 * 256 + 4 * l);
        denom += p0 + p1 + p2 + p3;
        a1x = fmaf(p0, bf2f(g0.x), a1x); a2x = fmaf(p0, bf2f(g0.y), a2x);
        a3x = fmaf(q0, bf2f(g0.y), a3x);
        a1y = fmaf(p0, bf2f(g0.z), a1y); a2y = fmaf(p0, bf2f(g0.w), a2y);
        a3y = fmaf(q0, bf2f(g0.w), a3y);
        a1x = fmaf(p1, bf2f(g1.x), a1x); a2x = fmaf(p1, bf2f(g1.y), a2x);
        a3x = fmaf(q1, bf2f(g1.y), a3x);
        a1y = fmaf(p1, bf2f(g1.z), a1y); a2y = fmaf(p1, bf2f(g1.w), a2y);
        a3y = fmaf(q1, bf2f(g1.w), a3y);
        a1x = fmaf(p2, bf2f(g2.x), a1x); a2x = fmaf(p2, bf2f(g2.y), a2x);
        a3x = fmaf(q2, bf2f(g2.y), a3x);
        a1y = fmaf(p2, bf2f(g2.z), a1y); a2y = fmaf(p2, bf2f(g2.w), a2y);
        a3y = fmaf(q2, bf2f(g2.w), a3y);
        a1x = fmaf(p3, bf2f(g3.x), a1x); a2x = fmaf(p3, bf2f(g3.y), a2x);
        a3x = fmaf(q3, bf2f(g3.y), a3x);
        a1y = fmaf(p3, bf2f(g3.z), a1y); a2y = fmaf(p3, bf2f(g3.w), a2y);
        a3y = fmaf(q3, bf2f(g3.w), a3y);
    }
    ushort2 yiu = *(const ushort2*)(YiB + ((size_t)be * N_ + n) * C_ + 2 * l);
    float2 vv = *(const float2*)(v1 + et * C_ + 2 * l);
    float inv = (denom > 0.f) ? 1.f / denom : 0.f;
    float ox = (a1x + bf2f(yiu.x) * a2x + vv.x * a3x) * inv;
    float oy = (a1y + bf2f(yiu.y) * a2y + vv.y * a3y) * inv;
    *(ushort2*)(aggrB + ((size_t)be * N_ + n) * C_ + 2 * l) = make_ushort2(f2bf(ox), f2bf(oy));
}

#define AGGK_BLOCKS 320

// Fused: outs = tanh(relu(aggr@W1 + xn[d_t]@W2 + agg_b)) -> outsB + LDS tile;
// then klin GEMM on the tile (A-fragments from LDS) -> colsum; last block -> attn.
__global__ __launch_bounds__(256) void aggklin_kernel(
    const unsigned short* __restrict__ aggrB, const float* __restrict__ xn,
    const unsigned short* __restrict__ wph, const unsigned short* __restrict__ wpl,
    const float* __restrict__ agg_b, const float* __restrict__ klin_b,
    const float* __restrict__ q, unsigned short* __restrict__ outsB,
    float* __restrict__ colsum, int* __restrict__ done, float* __restrict__ attn)
{
    int blk = blockIdx.x;
    int be = blk & 7, bx = blk >> 3;   // XCD-pin by pair
    int et = be & 3, b = be >> 2;
    int d_t = ((et + 1) >> 1) & 1;
    size_t base = (size_t)be * N_ * C_;
    ffrag acc[2][8];
    zero_acc(acc);
    mfma128_bfA(aggrB + base, wph + SLOT(10 + et), wpl + SLOT(10 + et), acc, bx);
    mfma128(xn + (size_t)(b * 2 + d_t) * N_ * C_, wph + SLOT(14 + et), wpl + SLOT(14 + et),
            acc, bx);
    __shared__ unsigned short tile[128][136];   // pad 8 -> 272 B row stride (16B-aligned)
    const float* bias = agg_b + et * C_;
    const int wave = threadIdx.x >> 6, lane = threadIdx.x & 63;
    const int mloc = lane & 15, quad = lane >> 4;
#pragma unroll
    for (int h = 0; h < 2; ++h)
#pragma unroll
        for (int r = 0; r < 4; ++r) {
            int lrow = wave * 32 + quad * 4 + h * 16 + r;
            int row = bx * 128 + lrow;
#pragma unroll
            for (int t = 0; t < 8; ++t) {
                int col = t * 16 + mloc;
                float v = acc[h][t][r] + bias[col];
                v = (v > 0.f) ? tanhf(v) : 0.f;
                unsigned short hv = f2bf(v);
                tile[lrow][col] = hv;
                if (row < N_) outsB[base + (size_t)row * C_ + col] = hv;
            }
        }
    __syncthreads();
    // second GEMM: klin[nt] on the tile (nt == d_t ; tt = et>=2)
    int nt = d_t, tt = (et >= 2) ? 1 : 0;
    ffrag acc2[2][8];
    zero_acc(acc2);
    const unsigned short* Kh = wph + SLOT(18 + nt);
    const unsigned short* Kl = wpl + SLOT(18 + nt);
    int lr0 = wave * 32 + mloc, lr1 = lr0 + 16;
#pragma unroll
    for (int s = 0; s < 4; ++s) {
        bfrag a0 = *(const bfrag*)&tile[lr0][s * 32 + quad * 8];
        bfrag a1 = *(const bfrag*)&tile[lr1][s * 32 + quad * 8];
        const unsigned short* pBh = Kh + ((size_t)s * 512 + lane) * 8;
        const unsigned short* pBl = Kl + ((size_t)s * 512 + lane) * 8;
#pragma unroll
        for (int t = 0; t < 8; ++t) {
            bfrag bh = *(const bfrag*)(pBh + (size_t)t * 512);
            bfrag bl = *(const bfrag*)(pBl + (size_t)t * 512);
            acc2[0][t] = __builtin_amdgcn_mfma_f32_16x16x32_bf16(a0, bh, acc2[0][t], 0, 0, 0);
            acc2[0][t] = __builtin_amdgcn_mfma_f32_16x16x32_bf16(a0, bl, acc2[0][t], 0, 0, 0);
            acc2[1][t] = __builtin_amdgcn_mfma_f32_16x16x32_bf16(a1, bh, acc2[1][t], 0, 0, 0);
            acc2[1][t] = __builtin_amdgcn_mfma_f32_16x16x32_bf16(a1, bl, acc2[1][t], 0, 0, 0);
        }
    }
    __shared__ float cs[128];
    if (threadIdx.x < 128) cs[threadIdx.x] = 0.f;
    __syncthreads();
    const int rbase = bx * 128 + wave * 32 + quad * 4;
#pragma unroll
    for (int t = 0; t < 8; ++t) {
        int col = t * 16 + mloc;
        float bv = klin_b[nt * C_ + col];
        float s = 0.f;
#pragma unroll
        for (int h = 0; h < 2; ++h)
#pragma unroll
            for (int r = 0; r < 4; ++r) {
                int row = rbase + h * 16 + r;
                if (row < N_) s += tanhf(acc2[h][t][r] + bv);
            }
        atomicAdd(&cs[col], s);
    }
    __syncthreads();
    if (threadIdx.x < 128)
        atomicAdd(&colsum[(size_t)((b * 2 + nt) * 2 + tt) * C_ + threadIdx.x], cs[threadIdx.x]);
    // last-block score fusion
    __shared__ int isLast;
    if (threadIdx.x == 0) {
        __threadfence();
        isLast = (atomicAdd(done, 1) == AGGK_BLOCKS - 1) ? 1 : 0;
    }
    __syncthreads();
    if (!isLast) return;
    __shared__ float red[2][2];
    for (int bnt = 0; bnt < 4; ++bnt) {
        int ntl = bnt & 1;
        float v0 = 0.f, v1l = 0.f;
        if (threadIdx.x < 128) {
            int c = threadIdx.x;
            float qc = q[ntl * C_ + c];
            float c0 = atomicAdd(&colsum[(size_t)(bnt * 2 + 0) * C_ + c], 0.f);
            float c1 = atomicAdd(&colsum[(size_t)(bnt * 2 + 1) * C_ + c], 0.f);
            v0 = qc * c0;
            v1l = qc * c1;
        }
#pragma unroll
        for (int m = 32; m > 0; m >>= 1) {
            v0 += __shfl_down(v0, m);
            v1l += __shfl_down(v1l, m);
        }
        if ((threadIdx.x & 63) == 0 && wave < 2) {
            red[wave][0] = v0;
            red[wave][1] = v1l;
        }
        __syncthreads();
        if (threadIdx.x == 0) {
            float s0 = (red[0][0] + red[1][0]) / (float)N_;
            float s1 = (red[0][1] + red[1][1]) / (float)N_;
            float mx = fmaxf(s0, s1);
            float e0 = __expf(s0 - mx), e1 = __expf(s1 - mx);
            float invd = 1.f / (e0 + e1);
            attn[bnt * 2 + 0] = e0 * invd;
            attn[bnt * 2 + 1] = e1 * invd;
        }
        __syncthreads();
    }
}

__global__ void output_kernel(const unsigned short* __restrict__ outsB,
                              const float* __restrict__ attn,
                              float* __restrict__ out)
{
    int idx = blockIdx.x * blockDim.x + threadIdx.x;
    int c4 = idx & 31;
    int row = idx >> 5;
    int b = row / TWO_N;
    int r = row % TWO_N;
    int nt = (r >= N_) ? 1 : 0;
    int n = r - nt * N_;
    int et0 = nt, et1 = 3 - nt;
    float a0 = attn[(b * 2 + nt) * 2 + 0];
    float a1 = attn[(b * 2 + nt) * 2 + 1];
    const ushort4* o0 = (const ushort4*)(outsB + ((size_t)(b * T_ + et0) * N_ + n) * C_);
    const ushort4* o1 = (const ushort4*)(outsB + ((size_t)(b * T_ + et1) * N_ + n) * C_);
    ushort4 u0 = o0[c4], u1 = o1[c4];
    float4 o;
    o.x = a0 * bf2f(u0.x) + a1 * bf2f(u1.x);
    o.y = a0 * bf2f(u0.y) + a1 * bf2f(u1.y);
    o.z = a0 * bf2f(u0.z) + a1 * bf2f(u1.z);
    o.w = a0 * bf2f(u0.w) + a1 * bf2f(u1.w);
    ((float4*)out)[idx] = o;
}

extern "C" void kernel_launch(void* const* d_in, const int* in_sizes, int n_in,
                              void* d_out, int out_size, void* d_ws, size_t ws_size,
                              hipStream_t stream)
{
    const float* x       = (const float*)d_in[0];
    const int*   eidx    = (const int*)d_in[1];
    const float* ew      = (const float*)d_in[2];
    const float* proj_w  = (const float*)d_in[3];
    const float* proj_b  = (const float*)d_in[4];
    const float* q       = (const float*)d_in[5];
    const float* klin_w  = (const float*)d_in[6];
    const float* klin_b  = (const float*)d_in[7];
    const float* lin_src = (const float*)d_in[8];
    const float* lin_dst = (const float*)d_in[9];
    const float* eproj_w = (const float*)d_in[10];
    const float* eproj_b = (const float*)d_in[11];
    const float* agg_w   = (const float*)d_in[12];
    const float* agg_b   = (const float*)d_in[13];
    const float* att_w   = (const float*)d_in[14];
    const float* att_b   = (const float*)d_in[15];

    float* ws = (float*)d_ws;
    size_t o = 0;
    float* xn     = ws + o; o += 2560000;   // live proj -> aggklin
    float* GU     = ws + o; o += 5120000;   // G (bf16, sy->aggregate) ∪ outsB (bf16)
    float* YiBf   = ws + o; o += 2560000;   // Yi bf16
    float* aggrBf = ws + o; o += 2560000;   // bf16 aggr
    float* pwqf   = ws + o; o += 2 * 8 * EP_;      // 1,310,720 (uint2 CSR entries)
    float* asrc   = ws + o; o += 40000;
    float* adst   = ws + o; o += 40000;
    float* v1     = ws + o; o += 512;
    float* bias_i = ws + o; o += 512;
    float* attn   = ws + o; o += 16;
    // zeroed-by-setup region (contiguous ints): count, cursor, colsum, done
    int*   count  = (int*)(ws + o); o += 40000;
    int*   cursor = (int*)(ws + o); o += 40000;
    float* colsum = ws + o; o += 1024;
    int*   done   = (int*)(ws + o); o += 4;
    int*   offs   = (int*)(ws + o); o += 40008;
    unsigned short* wph = (unsigned short*)(ws + o); o += 163840;
    unsigned short* wpl = (unsigned short*)(ws + o); o += 163840;
    unsigned short* lph = (unsigned short*)(ws + o); o += 1024;
    unsigned short* lpl = (unsigned short*)(ws + o); o += 1024;
    // total ≈ 14.7M floats ≈ 59 MB

    unsigned short* G     = (unsigned short*)GU;
    unsigned short* outsB = (unsigned short*)GU;
    unsigned short* YiB   = (unsigned short*)YiBf;
    unsigned short* aggrB = (unsigned short*)aggrBf;
    unsigned int*   pwq   = (unsigned int*)pwqf;

    setup_kernel<<<dim3(243), 256, 0, stream>>>(proj_w, att_w, agg_w, klin_w,
                                                lin_src, lin_dst, eproj_w, eproj_b,
                                                att_b, wph, wpl, lph, lpl,
                                                v1, bias_i, count);
    cp_kernel<<<dim3(2208), 256, 0, stream>>>(eidx, count, x, wph, wpl, proj_b,
                                              lin_src, lin_dst, xn, asrc, adst);
    scan_kernel<<<dim3(B_ * T_), 256, 0, stream>>>(count, offs, pwq);
    sy_kernel<<<dim3(3328), 256, 0, stream>>>(eidx, ew, asrc, adst, offs, cursor,
                                              pwq, xn, wph, wpl, bias_i, G, YiB);
    aggregate_kernel<<<dim3(10000), 256, 0, stream>>>(G, YiB, v1, pwq, offs, aggrB);
    aggklin_kernel<<<dim3(AGGK_BLOCKS), 256, 0, stream>>>(aggrB, xn, wph, wpl, agg_b,
                                                          klin_b, q, outsB, colsum,
                                                          done, attn);
    output_kernel<<<dim3(2500), 256, 0, stream>>>(outsB, attn, (float*)d_out);
}

// Round 10
// 281.919 us; speedup vs baseline: 1.8501x; 1.0506x over previous
//
#include <hip/hip_runtime.h>
#include <math.h>

// Problem constants (from reference setup_inputs)
#define B_    2
#define N_    5000
#define C_    128
#define E_    65536
#define T_    4
#define TWO_N 10000
#define EP_   81920   // padded CSR capacity per (et,b)

// edge types: (src,dst) node types = (0,0),(1,1),(0,1),(1,0)
// s_t = et & 1 ; d_t = ((et+1)>>1) & 1
// XCD-pin convention: pair be = b*4+et == blockIdx.x & 7 for every kernel
// touching per-pair edge data (count, scatter, yji, aggregate, aggklin).
// CSR entry (8 B): uint2 { p fp32 ; (q_bf16 << 16) | src_u16 }

__device__ __forceinline__ unsigned short f2bf(float f) {
    unsigned u = __float_as_uint(f);
    u += 0x7fffu + ((u >> 16) & 1u);   // RNE
    return (unsigned short)(u >> 16);
}
__device__ __forceinline__ float bf2f(unsigned short h) {
    return __uint_as_float(((unsigned)h) << 16);
}

typedef __attribute__((ext_vector_type(8))) short bfrag;   // 8 bf16
typedef __attribute__((ext_vector_type(4))) float ffrag;   // 4 fp32 acc

__device__ __forceinline__ void split8(const float* __restrict__ p, bfrag& hi, bfrag& lo) {
#pragma unroll
    for (int j = 0; j < 8; ++j) {
        float v = p[j];
        unsigned short h = f2bf(v);
        hi[j] = (short)h;
        lo[j] = (short)f2bf(v - bf2f(h));
    }
}

// Weight slots (each 128x128, B-fragment packed):
// 0-1: proj ; 2-5: Wj[et] ; 6-9: Wi[et] ; 10-13: W1[et] ; 14-17: W2[et] ; 18-19: klin[nt]
#define SLOT(i) ((size_t)(i) * 16384)

__device__ __forceinline__ void zero_acc(ffrag (&acc)[2][8]) {
#pragma unroll
    for (int h = 0; h < 2; ++h)
#pragma unroll
        for (int t = 0; t < 8; ++t) acc[h][t] = (ffrag){0.f, 0.f, 0.f, 0.f};
}

// Split-bf16 MFMA GEMM core, K=128, 4 waves x 32 rows, N=128. fp32 A.
__device__ __forceinline__ void mfma128(const float* __restrict__ A,
                                        const unsigned short* __restrict__ Whi,
                                        const unsigned short* __restrict__ Wlo,
                                        ffrag (&acc)[2][8], int bx)
{
    const int wave = threadIdx.x >> 6, lane = threadIdx.x & 63;
    const int mloc = lane & 15, quad = lane >> 4;
    const int row0w = bx * 128 + wave * 32;
    int r0 = row0w + mloc;      if (r0 >= N_) r0 = N_ - 1;  // clamp, stores guarded
    int r1 = row0w + 16 + mloc; if (r1 >= N_) r1 = N_ - 1;
#pragma unroll
    for (int s = 0; s < 4; ++s) {
        bfrag a0h, a0l, a1h, a1l;
        split8(A + (size_t)r0 * C_ + s * 32 + quad * 8, a0h, a0l);
        split8(A + (size_t)r1 * C_ + s * 32 + quad * 8, a1h, a1l);
        const unsigned short* pBh = Whi + ((size_t)s * 512 + lane) * 8;
        const unsigned short* pBl = Wlo + ((size_t)s * 512 + lane) * 8;
#pragma unroll
        for (int t = 0; t < 8; ++t) {
            bfrag bh = *(const bfrag*)(pBh + (size_t)t * 512);
            bfrag bl = *(const bfrag*)(pBl + (size_t)t * 512);
            acc[0][t] = __builtin_amdgcn_mfma_f32_16x16x32_bf16(a0h, bh, acc[0][t], 0, 0, 0);
            acc[0][t] = __builtin_amdgcn_mfma_f32_16x16x32_bf16(a0l, bh, acc[0][t], 0, 0, 0);
            acc[0][t] = __builtin_amdgcn_mfma_f32_16x16x32_bf16(a0h, bl, acc[0][t], 0, 0, 0);
            acc[1][t] = __builtin_amdgcn_mfma_f32_16x16x32_bf16(a1h, bh, acc[1][t], 0, 0, 0);
            acc[1][t] = __builtin_amdgcn_mfma_f32_16x16x32_bf16(a1l, bh, acc[1][t], 0, 0, 0);
            acc[1][t] = __builtin_amdgcn_mfma_f32_16x16x32_bf16(a1h, bl, acc[1][t], 0, 0, 0);
        }
    }
}

// M=64 split core: 4 waves x 16 rows, N=128. fp32 A.
__device__ __forceinline__ void mfma64(const float* __restrict__ A,
                                       const unsigned short* __restrict__ Whi,
                                       const unsigned short* __restrict__ Wlo,
                                       ffrag (&acc)[8], int bx)
{
    const int wave = threadIdx.x >> 6, lane = threadIdx.x & 63;
    const int mloc = lane & 15, quad = lane >> 4;
    int r0 = bx * 64 + wave * 16 + mloc; if (r0 >= N_) r0 = N_ - 1;
#pragma unroll
    for (int s = 0; s < 4; ++s) {
        bfrag a0h, a0l;
        split8(A + (size_t)r0 * C_ + s * 32 + quad * 8, a0h, a0l);
        const unsigned short* pBh = Whi + ((size_t)s * 512 + lane) * 8;
        const unsigned short* pBl = Wlo + ((size_t)s * 512 + lane) * 8;
#pragma unroll
        for (int t = 0; t < 8; ++t) {
            bfrag bh = *(const bfrag*)(pBh + (size_t)t * 512);
            bfrag bl = *(const bfrag*)(pBl + (size_t)t * 512);
            acc[t] = __builtin_amdgcn_mfma_f32_16x16x32_bf16(a0h, bh, acc[t], 0, 0, 0);
            acc[t] = __builtin_amdgcn_mfma_f32_16x16x32_bf16(a0l, bh, acc[t], 0, 0, 0);
            acc[t] = __builtin_amdgcn_mfma_f32_16x16x32_bf16(a0h, bl, acc[t], 0, 0, 0);
        }
    }
}

// M=64 bf16-A core: D = A @ (Wh + Wl).
__device__ __forceinline__ void mfma64_bfA(const unsigned short* __restrict__ A,
                                           const unsigned short* __restrict__ Whi,
                                           const unsigned short* __restrict__ Wlo,
                                           ffrag (&acc)[8], int bx)
{
    const int wave = threadIdx.x >> 6, lane = threadIdx.x & 63;
    const int mloc = lane & 15, quad = lane >> 4;
    int r0 = bx * 64 + wave * 16 + mloc; if (r0 >= N_) r0 = N_ - 1;
#pragma unroll
    for (int s = 0; s < 4; ++s) {
        bfrag a0 = *(const bfrag*)(A + (size_t)r0 * C_ + s * 32 + quad * 8);
        const unsigned short* pBh = Whi + ((size_t)s * 512 + lane) * 8;
        const unsigned short* pBl = Wlo + ((size_t)s * 512 + lane) * 8;
#pragma unroll
        for (int t = 0; t < 8; ++t) {
            bfrag bh = *(const bfrag*)(pBh + (size_t)t * 512);
            bfrag bl = *(const bfrag*)(pBl + (size_t)t * 512);
            acc[t] = __builtin_amdgcn_mfma_f32_16x16x32_bf16(a0, bh, acc[t], 0, 0, 0);
            acc[t] = __builtin_amdgcn_mfma_f32_16x16x32_bf16(a0, bl, acc[t], 0, 0, 0);
        }
    }
}

// Half-width core: only 4 of 8 n-tiles (cols [half*64, half*64+64)). fp32 A.
__device__ __forceinline__ void mfma128_half(const float* __restrict__ A,
                                             const unsigned short* __restrict__ Whi,
                                             const unsigned short* __restrict__ Wlo,
                                             ffrag (&acc)[2][4], int bx, int half)
{
    const int wave = threadIdx.x >> 6, lane = threadIdx.x & 63;
    const int mloc = lane & 15, quad = lane >> 4;
    const int row0w = bx * 128 + wave * 32;
    int r0 = row0w + mloc;      if (r0 >= N_) r0 = N_ - 1;
    int r1 = row0w + 16 + mloc; if (r1 >= N_) r1 = N_ - 1;
#pragma unroll
    for (int s = 0; s < 4; ++s) {
        bfrag a0h, a0l, a1h, a1l;
        split8(A + (size_t)r0 * C_ + s * 32 + quad * 8, a0h, a0l);
        split8(A + (size_t)r1 * C_ + s * 32 + quad * 8, a1h, a1l);
        const unsigned short* pBh = Whi + ((size_t)s * 512 + (size_t)half * 256 + lane) * 8;
        const unsigned short* pBl = Wlo + ((size_t)s * 512 + (size_t)half * 256 + lane) * 8;
#pragma unroll
        for (int t = 0; t < 4; ++t) {
            bfrag bh = *(const bfrag*)(pBh + (size_t)t * 512);
            bfrag bl = *(const bfrag*)(pBl + (size_t)t * 512);
            acc[0][t] = __builtin_amdgcn_mfma_f32_16x16x32_bf16(a0h, bh, acc[0][t], 0, 0, 0);
            acc[0][t] = __builtin_amdgcn_mfma_f32_16x16x32_bf16(a0l, bh, acc[0][t], 0, 0, 0);
            acc[0][t] = __builtin_amdgcn_mfma_f32_16x16x32_bf16(a0h, bl, acc[0][t], 0, 0, 0);
            acc[1][t] = __builtin_amdgcn_mfma_f32_16x16x32_bf16(a1h, bh, acc[1][t], 0, 0, 0);
            acc[1][t] = __builtin_amdgcn_mfma_f32_16x16x32_bf16(a1l, bh, acc[1][t], 0, 0, 0);
            acc[1][t] = __builtin_amdgcn_mfma_f32_16x16x32_bf16(a1h, bl, acc[1][t], 0, 0, 0);
        }
    }
}

#define ZN_ 81028   // count(40000) + cursor(40000) + colsum(1024) + done(4)

// setup: blocks [0,160) pack_w ; [160] pack_L ; [161,163) prep ; [163,243) zero
__global__ __launch_bounds__(256) void setup_kernel(
    const float* __restrict__ proj_w, const float* __restrict__ att_w,
    const float* __restrict__ agg_w, const float* __restrict__ klin_w,
    const float* __restrict__ lin_src, const float* __restrict__ lin_dst,
    const float* __restrict__ eproj_w, const float* __restrict__ eproj_b,
    const float* __restrict__ att_b,
    unsigned short* __restrict__ wh, unsigned short* __restrict__ wl,
    unsigned short* __restrict__ lph, unsigned short* __restrict__ lpl,
    float* __restrict__ v1, float* __restrict__ bias_i, int* __restrict__ zbase)
{
    int blk = blockIdx.x;
    if (blk < 160) {
        int wave = threadIdx.x >> 6, lane = threadIdx.x & 63;
        int unit = blk * 4 + wave;      // 0..639
        int id = unit >> 5;             // slot 0..19
        int st = unit & 31;
        int s = st >> 3, t = st & 7;
        const float* src;
        if (id < 2)       src = proj_w + (size_t)id * 16384;
        else if (id < 6)  src = att_w + (size_t)(id - 2) * 384 * C_;
        else if (id < 10) src = att_w + (size_t)(id - 6) * 384 * C_ + (size_t)128 * C_;
        else if (id < 14) src = agg_w + (size_t)(id - 10) * 256 * C_;
        else if (id < 18) src = agg_w + (size_t)(id - 14) * 256 * C_ + (size_t)128 * C_;
        else              src = klin_w + (size_t)(id - 18) * 16384;
        int mloc = lane & 15, quad = lane >> 4;
        size_t dbase = SLOT(id) + ((size_t)(s * 8 + t) * 64 + lane) * 8;
#pragma unroll
        for (int j = 0; j < 8; ++j) {
            float v = src[(size_t)(s * 32 + quad * 8 + j) * C_ + t * 16 + mloc];
            unsigned short h = f2bf(v);
            wh[dbase + j] = h;
            wl[dbase + j] = f2bf(v - bf2f(h));
        }
    } else if (blk == 160) {
        int s = threadIdx.x >> 6;       // wave = s (0..3)
        int lane = threadIdx.x & 63;
        int mloc = lane & 15, quad = lane >> 4;
        const float* vec = nullptr;
        if (mloc < 8) {
            int nt = mloc >> 2, idx = mloc & 3;
            if (idx == 0)      vec = lin_src + nt * C_;
            else if (idx == 1) vec = lin_src + (nt + 2) * C_;
            else if (idx == 2) vec = lin_dst + nt * C_;
            else               vec = lin_dst + (3 - nt) * C_;
        }
        size_t dbase = ((size_t)(s * 64) + lane) * 8;
#pragma unroll
        for (int j = 0; j < 8; ++j) {
            float v = vec ? vec[s * 32 + quad * 8 + j] : 0.f;
            unsigned short h = f2bf(v);
            lph[dbase + j] = h;
            lpl[dbase + j] = f2bf(v - bf2f(h));
        }
    } else if (blk < 163) {
        int et = (blk - 161) * 2 + (threadIdx.x >> 7);
        int c = threadIdx.x & 127;
        float s1 = 0.f, s0 = 0.f;
        for (int k = 0; k < 128; ++k) {
            float wv = att_w[(size_t)et * 384 * C_ + (size_t)(256 + k) * C_ + c];
            s1 = fmaf(eproj_w[et * C_ + k], wv, s1);
            s0 = fmaf(eproj_b[et * C_ + k], wv, s0);
        }
        v1[et * C_ + c] = s1;
        bias_i[et * C_ + c] = att_b[et * C_ + c] + s0;
    } else {
        int base = (blk - 163) * 1024 + threadIdx.x * 4;
#pragma unroll
        for (int j = 0; j < 4; ++j)
            if (base + j < ZN_) zbase[base + j] = 0;
    }
}

// count + proj(+nodedot) hybrid: blocks [0,2048) count (XCD-pinned) ; [2048,2208) proj
__global__ __launch_bounds__(256) void cp_kernel(
    const int* __restrict__ eidx, int* __restrict__ count,
    const float* __restrict__ x,
    const unsigned short* __restrict__ wph, const unsigned short* __restrict__ wpl,
    const float* __restrict__ proj_b,
    const float* __restrict__ lin_src, const float* __restrict__ lin_dst,
    float* __restrict__ xn, float* __restrict__ asrc, float* __restrict__ adst)
{
    int blk = blockIdx.x;
    if (blk < 2048) {
        int be = blk & 7;             // XCD-pin: pair = b*4+et
        int et = be & 3, b = be >> 2;
        int e = (blk >> 3) * 256 + threadIdx.x;
        int dst = eidx[(((size_t)et * B_ + b) * 2 + 1) * E_ + e];
        atomicAdd(&count[(size_t)be * N_ + dst], 1);
        return;
    }
    int pidx = blk - 2048;            // 0..159
    int bx = pidx % 40;
    int nt = (pidx / 40) & 1;
    int b = pidx / 80;
    const float* A = x + ((size_t)b * TWO_N + (size_t)nt * N_) * C_;
    ffrag acc[2][8];
    zero_acc(acc);
    mfma128(A, wph + SLOT(nt), wpl + SLOT(nt), acc, bx);
    float* out = xn + (size_t)(b * 2 + nt) * N_ * C_;
    const float* bias = proj_b + nt * C_;
    const int wave = threadIdx.x >> 6, lane = threadIdx.x & 63;
    const int mloc = lane & 15, quad = lane >> 4;
    const int rbase = bx * 128 + wave * 32 + quad * 4;
    // lin columns for the fused nodedot
    const float* lv0 = lin_src + nt * C_;
    const float* lv1 = lin_src + (2 + nt) * C_;
    const float* lv2 = lin_dst + nt * C_;
    const float* lv3 = lin_dst + (3 - nt) * C_;
    float linv[4][8];
#pragma unroll
    for (int t = 0; t < 8; ++t) {
        int col = t * 16 + mloc;
        linv[0][t] = lv0[col]; linv[1][t] = lv1[col];
        linv[2][t] = lv2[col]; linv[3][t] = lv3[col];
    }
    const int et0 = nt, et1 = 2 + nt, et2 = nt, et3 = 3 - nt;
#pragma unroll
    for (int h = 0; h < 2; ++h)
#pragma unroll
        for (int r = 0; r < 4; ++r) {
            int row = rbase + h * 16 + r;
            bool ok = (row < N_);
            float p0 = 0.f, p1 = 0.f, p2 = 0.f, p3 = 0.f;
#pragma unroll
            for (int t = 0; t < 8; ++t) {
                int col = t * 16 + mloc;
                float vv = acc[h][t][r] + bias[col];
                if (ok) out[(size_t)row * C_ + col] = vv;
                p0 = fmaf(vv, linv[0][t], p0);
                p1 = fmaf(vv, linv[1][t], p1);
                p2 = fmaf(vv, linv[2][t], p2);
                p3 = fmaf(vv, linv[3][t], p3);
            }
#pragma unroll
            for (int m = 1; m < 16; m <<= 1) {
                p0 += __shfl_xor(p0, m);
                p1 += __shfl_xor(p1, m);
                p2 += __shfl_xor(p2, m);
                p3 += __shfl_xor(p3, m);
            }
            if (mloc == 0 && ok) {
                asrc[(size_t)(b * T_ + et0) * N_ + row] = p0;
                asrc[(size_t)(b * T_ + et1) * N_ + row] = p1;
                adst[(size_t)(b * T_ + et2) * N_ + row] = p2;
                adst[(size_t)(b * T_ + et3) * N_ + row] = p3;
            }
        }
}

// Exclusive scan of 4-aligned strides -> CSR offsets; zero pad slots.
__global__ __launch_bounds__(256) void scan_kernel(const int* __restrict__ count,
                                                   int* __restrict__ offs,
                                                   unsigned int* __restrict__ pwq)
{
    int be = blockIdx.x;
    const int* cnt = count + (size_t)be * N_;
    int* off = offs + (size_t)be * (N_ + 1);
    __shared__ int sums[256];
    int tid = threadIdx.x;
    const int chunk = (N_ + 255) / 256;  // 20
    int lo = tid * chunk, hi = min(lo + chunk, N_);
    int s = 0;
    for (int i = lo; i < hi; ++i) s += (cnt[i] + 3) & ~3;
    sums[tid] = s;
    __syncthreads();
    for (int d = 1; d < 256; d <<= 1) {
        int v = (tid >= d) ? sums[tid - d] : 0;
        __syncthreads();
        sums[tid] += v;
        __syncthreads();
    }
    int run = (tid > 0) ? sums[tid - 1] : 0;
    uint2* ep = (uint2*)pwq;
    for (int i = lo; i < hi; ++i) {
        off[i] = run;
        int c = cnt[i], pc = (c + 3) & ~3;
        for (int k = c; k < pc; ++k)
            ep[(size_t)be * EP_ + run + k] = make_uint2(0u, 0u);
        run += pc;
    }
    if (tid == 255) off[N_] = sums[255];
}

// scatter + yji hybrid: blocks [0,2048) scatter ; [2048,3328) yji — XCD-pinned.
// yji roles: 0 -> G = interleaved bf16 {Z=xs*(xs@Wj), xs} ; 1 -> Yi (bf16);
// each role split into col-halves (64 cols/block).
__global__ __launch_bounds__(256) void sy_kernel(
    const int* __restrict__ eidx, const float* __restrict__ ew,
    const float* __restrict__ asrc, const float* __restrict__ adst,
    const int* __restrict__ offs, int* __restrict__ cursor,
    unsigned int* __restrict__ pwq,
    const float* __restrict__ xn,
    const unsigned short* __restrict__ wph, const unsigned short* __restrict__ wpl,
    const float* __restrict__ bias_i,
    unsigned short* __restrict__ G, unsigned short* __restrict__ YiB)
{
    int blk = blockIdx.x;
    if (blk < 2048) {
        int be = blk & 7;             // XCD-pin
        int et = be & 3, b = be >> 2;
        int e = (blk >> 3) * 256 + threadIdx.x;
        size_t ebase = ((size_t)et * B_ + b) * 2 * E_;
        int src = eidx[ebase + e];
        int dst = eidx[ebase + E_ + e];
        float al = asrc[(size_t)be * N_ + src] + adst[(size_t)be * N_ + dst];
        al = (al > 0.f) ? al : 0.2f * al;
        float p = __expf(al);
        float w = ew[((size_t)et * B_ + b) * E_ + e];
        int pos = offs[(size_t)be * (N_ + 1) + dst] +
                  atomicAdd(&cursor[(size_t)be * N_ + dst], 1);
        unsigned int packed = (unsigned int)src | ((unsigned int)f2bf(p * w) << 16);
        ((uint2*)pwq)[(size_t)be * EP_ + pos] = make_uint2(__float_as_uint(p), packed);
        return;
    }
    int yidx = blk - 2048;            // 0..1279 ; 2048 % 8 == 0 keeps pin aligned
    int be = yidx & 7;                // XCD-pin
    int et = be & 3, b = be >> 2;
    int rest = yidx >> 3;             // 0..159
    int half = rest & 1;
    int role = (rest >> 1) & 1;
    int bx = rest >> 2;               // 0..39
    int s_t = et & 1, d_t = ((et + 1) >> 1) & 1;
    int ntsel = (role == 0) ? s_t : d_t;
    const float* A = xn + (size_t)(b * 2 + ntsel) * N_ * C_;
    int slot = (role == 0) ? 2 + et : 6 + et;
    ffrag acc[2][4];
#pragma unroll
    for (int h = 0; h < 2; ++h)
#pragma unroll
        for (int t = 0; t < 4; ++t) acc[h][t] = (ffrag){0.f, 0.f, 0.f, 0.f};
    mfma128_half(A, wph + SLOT(slot), wpl + SLOT(slot), acc, bx, half);
    const float* bias = bias_i + et * C_;
    const int wave = threadIdx.x >> 6, lane = threadIdx.x & 63;
    const int mloc = lane & 15, quad = lane >> 4;
    const int rbase = bx * 128 + wave * 32 + quad * 4;
#pragma unroll
    for (int h = 0; h < 2; ++h)
#pragma unroll
        for (int r = 0; r < 4; ++r) {
            int row = rbase + h * 16 + r;
            if (row >= N_) continue;
#pragma unroll
            for (int t = 0; t < 4; ++t) {
                int col = (half * 4 + t) * 16 + mloc;
                float v = acc[h][t][r];
                if (role == 0) {
                    float xv = A[(size_t)row * C_ + col];
                    *(ushort2*)(G + ((size_t)be * N_ + row) * 256 + 2 * col) =
                        make_ushort2(f2bf(v * xv), f2bf(xv));
                } else {
                    YiB[((size_t)be * N_ + row) * C_ + col] = f2bf(v + bias[col]);
                }
            }
        }
}

// Segment-softmax aggregation, one wave per (node, et, b), XCD-pinned by pair.
// aggr = (Σ p·Z[s] + Yi'⊙Σ p·xs + v1⊙Σ q·xs) / Σ p, emitted as bf16.
__global__ __launch_bounds__(256) void aggregate_kernel(
    const unsigned short* __restrict__ G, const unsigned short* __restrict__ YiB,
    const float* __restrict__ v1, const unsigned int* __restrict__ pwq,
    const int* __restrict__ offs, unsigned short* __restrict__ aggrB)
{
    int pair = blockIdx.x & 7;                       // = b*T_+et (XCD-pin)
    int n = (blockIdx.x >> 3) * 4 + (threadIdx.x >> 6);
    int et = pair & 3;
    int be = pair;
    int l = threadIdx.x & 63;
    const unsigned short* Gp = G + (size_t)be * N_ * 256;
    int beg = offs[(size_t)be * (N_ + 1) + n];
    int end = offs[(size_t)be * (N_ + 1) + n + 1];
    const unsigned int* ep = pwq + ((size_t)be * EP_ + beg) * 2;
    float a1x = 0.f, a1y = 0.f, a2x = 0.f, a2y = 0.f, a3x = 0.f, a3y = 0.f, denom = 0.f;
    int cnt = end - beg;  // multiple of 4; pads have p=q=0, src=0
    for (int i = 0; i < cnt; i += 4) {
        uint4 u01 = *(const uint4*)(ep + 2 * i);      // entries i, i+1
        uint4 u23 = *(const uint4*)(ep + 2 * i + 4);  // entries i+2, i+3
        float p0 = __uint_as_float(u01.x), q0 = bf2f((unsigned short)(u01.y >> 16));
        float p1 = __uint_as_float(u01.z), q1 = bf2f((unsigned short)(u01.w >> 16));
        float p2 = __uint_as_float(u23.x), q2 = bf2f((unsigned short)(u23.y >> 16));
        float p3 = __uint_as_float(u23.z), q3 = bf2f((unsigned short)(u23.w >> 16));
        int s0 = u01.y & 0xffff, s1 = u01.w & 0xffff;
        int s2 = u23.y & 0xffff, s3 = u23.w & 0xffff;
        ushort4 g0 = *(const ushort4*)(Gp + (size_t)s0 * 256 + 4 * l);
        ushort4 g1 = *(const ushort4*)(Gp + (size_t)s1 * 256 + 4 * l);
        ushort4 g2 = *(const ushort4*)(Gp + (size_t)s2 * 256 + 4 * l);
        ushort4 g3 = *(const ushort4*)(Gp + (size_t)s3 * 256 + 4 * l);
        denom += p0 + p1 + p2 + p3;
        a1x = fmaf(p0, bf2f(g0.x), a1x); a2x = fmaf(p0, bf2f(g0.y), a2x);
        a3x = fmaf(q0, bf2f(g0.y), a3x);
        a1y = fmaf(p0, bf2f(g0.z), a1y); a2y = fmaf(p0, bf2f(g0.w), a2y);
        a3y = fmaf(q0, bf2f(g0.w), a3y);
        a1x = fmaf(p1, bf2f(g1.x), a1x); a2x = fmaf(p1, bf2f(g1.y), a2x);
        a3x = fmaf(q1, bf2f(g1.y), a3x);
        a1y = fmaf(p1, bf2f(g1.z), a1y); a2y = fmaf(p1, bf2f(g1.w), a2y);
        a3y = fmaf(q1, bf2f(g1.w), a3y);
        a1x = fmaf(p2, bf2f(g2.x), a1x); a2x = fmaf(p2, bf2f(g2.y), a2x);
        a3x = fmaf(q2, bf2f(g2.y), a3x);
        a1y = fmaf(p2, bf2f(g2.z), a1y); a2y = fmaf(p2, bf2f(g2.w), a2y);
        a3y = fmaf(q2, bf2f(g2.w), a3y);
        a1x = fmaf(p3, bf2f(g3.x), a1x); a2x = fmaf(p3, bf2f(g3.y), a2x);
        a3x = fmaf(q3, bf2f(g3.y), a3x);
        a1y = fmaf(p3, bf2f(g3.z), a1y); a2y = fmaf(p3, bf2f(g3.w), a2y);
        a3y = fmaf(q3, bf2f(g3.w), a3y);
    }
    ushort2 yiu = *(const ushort2*)(YiB + ((size_t)be * N_ + n) * C_ + 2 * l);
    float2 vv = *(const float2*)(v1 + et * C_ + 2 * l);
    float inv = (denom > 0.f) ? 1.f / denom : 0.f;
    float ox = (a1x + bf2f(yiu.x) * a2x + vv.x * a3x) * inv;
    float oy = (a1y + bf2f(yiu.y) * a2y + vv.y * a3y) * inv;
    *(ushort2*)(aggrB + ((size_t)be * N_ + n) * C_ + 2 * l) = make_ushort2(f2bf(ox), f2bf(oy));
}

#define AGGK_BLOCKS 640

// Fused (M=64 tiles): outs = tanh(relu(aggr@W1 + xn[d_t]@W2 + agg_b)) -> outsB
// + LDS tile; then klin GEMM on the tile -> colsum; last block -> attn.
__global__ __launch_bounds__(256) void aggklin_kernel(
    const unsigned short* __restrict__ aggrB, const float* __restrict__ xn,
    const unsigned short* __restrict__ wph, const unsigned short* __restrict__ wpl,
    const float* __restrict__ agg_b, const float* __restrict__ klin_b,
    const float* __restrict__ q, unsigned short* __restrict__ outsB,
    float* __restrict__ colsum, int* __restrict__ done, float* __restrict__ attn)
{
    int blk = blockIdx.x;
    int be = blk & 7, bx = blk >> 3;   // XCD-pin by pair; bx 0..79 (M=64 tiles)
    int et = be & 3, b = be >> 2;
    int d_t = ((et + 1) >> 1) & 1;
    size_t base = (size_t)be * N_ * C_;
    ffrag acc[8];
#pragma unroll
    for (int t = 0; t < 8; ++t) acc[t] = (ffrag){0.f, 0.f, 0.f, 0.f};
    mfma64_bfA(aggrB + base, wph + SLOT(10 + et), wpl + SLOT(10 + et), acc, bx);
    mfma64(xn + (size_t)(b * 2 + d_t) * N_ * C_, wph + SLOT(14 + et), wpl + SLOT(14 + et),
           acc, bx);
    __shared__ unsigned short tile[64][136];   // 17.4 KB
    const float* bias = agg_b + et * C_;
    const int wave = threadIdx.x >> 6, lane = threadIdx.x & 63;
    const int mloc = lane & 15, quad = lane >> 4;
#pragma unroll
    for (int r = 0; r < 4; ++r) {
        int lrow = wave * 16 + quad * 4 + r;
        int row = bx * 64 + lrow;
#pragma unroll
        for (int t = 0; t < 8; ++t) {
            int col = t * 16 + mloc;
            float v = acc[t][r] + bias[col];
            v = (v > 0.f) ? tanhf(v) : 0.f;
            unsigned short hv = f2bf(v);
            tile[lrow][col] = hv;
            if (row < N_) outsB[base + (size_t)row * C_ + col] = hv;
        }
    }
    __syncthreads();
    // second GEMM: klin[nt] on the tile (nt == d_t ; tt = et>=2)
    int nt = d_t, tt = (et >= 2) ? 1 : 0;
    ffrag acc2[8];
#pragma unroll
    for (int t = 0; t < 8; ++t) acc2[t] = (ffrag){0.f, 0.f, 0.f, 0.f};
    const unsigned short* Kh = wph + SLOT(18 + nt);
    const unsigned short* Kl = wpl + SLOT(18 + nt);
    int lr = wave * 16 + mloc;
#pragma unroll
    for (int s = 0; s < 4; ++s) {
        bfrag a0 = *(const bfrag*)&tile[lr][s * 32 + quad * 8];
        const unsigned short* pBh = Kh + ((size_t)s * 512 + lane) * 8;
        const unsigned short* pBl = Kl + ((size_t)s * 512 + lane) * 8;
#pragma unroll
        for (int t = 0; t < 8; ++t) {
            bfrag bh = *(const bfrag*)(pBh + (size_t)t * 512);
            bfrag bl = *(const bfrag*)(pBl + (size_t)t * 512);
            acc2[t] = __builtin_amdgcn_mfma_f32_16x16x32_bf16(a0, bh, acc2[t], 0, 0, 0);
            acc2[t] = __builtin_amdgcn_mfma_f32_16x16x32_bf16(a0, bl, acc2[t], 0, 0, 0);
        }
    }
    __shared__ float cs[128];
    if (threadIdx.x < 128) cs[threadIdx.x] = 0.f;
    __syncthreads();
    const int rbase = bx * 64 + wave * 16 + quad * 4;
#pragma unroll
    for (int t = 0; t < 8; ++t) {
        int col = t * 16 + mloc;
        float bv = klin_b[nt * C_ + col];
        float s = 0.f;
#pragma unroll
        for (int r = 0; r < 4; ++r) {
            int row = rbase + r;
            if (row < N_) s += tanhf(acc2[t][r] + bv);
        }
        atomicAdd(&cs[col], s);
    }
    __syncthreads();
    if (threadIdx.x < 128)
        atomicAdd(&colsum[(size_t)((b * 2 + nt) * 2 + tt) * C_ + threadIdx.x], cs[threadIdx.x]);
    // last-block score fusion
    __shared__ int isLast;
    if (threadIdx.x == 0) {
        __threadfence();
        isLast = (atomicAdd(done, 1) == AGGK_BLOCKS - 1) ? 1 : 0;
    }
    __syncthreads();
    if (!isLast) return;
    __shared__ float red[2][2];
    for (int bnt = 0; bnt < 4; ++bnt) {
        int ntl = bnt & 1;
        float v0 = 0.f, v1l = 0.f;
        if (threadIdx.x < 128) {
            int c = threadIdx.x;
            float qc = q[ntl * C_ + c];
            float c0 = atomicAdd(&colsum[(size_t)(bnt * 2 + 0) * C_ + c], 0.f);
            float c1 = atomicAdd(&colsum[(size_t)(bnt * 2 + 1) * C_ + c], 0.f);
            v0 = qc * c0;
            v1l = qc * c1;
        }
#pragma unroll
        for (int m = 32; m > 0; m >>= 1) {
            v0 += __shfl_down(v0, m);
            v1l += __shfl_down(v1l, m);
        }
        if ((threadIdx.x & 63) == 0 && wave < 2) {
            red[wave][0] = v0;
            red[wave][1] = v1l;
        }
        __syncthreads();
        if (threadIdx.x == 0) {
            float s0 = (red[0][0] + red[1][0]) / (float)N_;
            float s1 = (red[0][1] + red[1][1]) / (float)N_;
            float mx = fmaxf(s0, s1);
            float e0 = __expf(s0 - mx), e1 = __expf(s1 - mx);
            float invd = 1.f / (e0 + e1);
            attn[bnt * 2 + 0] = e0 * invd;
            attn[bnt * 2 + 1] = e1 * invd;
        }
        __syncthreads();
    }
}

__global__ void output_kernel(const unsigned short* __restrict__ outsB,
                              const float* __restrict__ attn,
                              float* __restrict__ out)
{
    int idx = blockIdx.x * blockDim.x + threadIdx.x;
    int c4 = idx & 31;
    int row = idx >> 5;
    int b = row / TWO_N;
    int r = row % TWO_N;
    int nt = (r >= N_) ? 1 : 0;
    int n = r - nt * N_;
    int et0 = nt, et1 = 3 - nt;
    float a0 = attn[(b * 2 + nt) * 2 + 0];
    float a1 = attn[(b * 2 + nt) * 2 + 1];
    const ushort4* o0 = (const ushort4*)(outsB + ((size_t)(b * T_ + et0) * N_ + n) * C_);
    const ushort4* o1 = (const ushort4*)(outsB + ((size_t)(b * T_ + et1) * N_ + n) * C_);
    ushort4 u0 = o0[c4], u1 = o1[c4];
    float4 o;
    o.x = a0 * bf2f(u0.x) + a1 * bf2f(u1.x);
    o.y = a0 * bf2f(u0.y) + a1 * bf2f(u1.y);
    o.z = a0 * bf2f(u0.z) + a1 * bf2f(u1.z);
    o.w = a0 * bf2f(u0.w) + a1 * bf2f(u1.w);
    ((float4*)out)[idx] = o;
}

extern "C" void kernel_launch(void* const* d_in, const int* in_sizes, int n_in,
                              void* d_out, int out_size, void* d_ws, size_t ws_size,
                              hipStream_t stream)
{
    const float* x       = (const float*)d_in[0];
    const int*   eidx    = (const int*)d_in[1];
    const float* ew      = (const float*)d_in[2];
    const float* proj_w  = (const float*)d_in[3];
    const float* proj_b  = (const float*)d_in[4];
    const float* q       = (const float*)d_in[5];
    const float* klin_w  = (const float*)d_in[6];
    const float* klin_b  = (const float*)d_in[7];
    const float* lin_src = (const float*)d_in[8];
    const float* lin_dst = (const float*)d_in[9];
    const float* eproj_w = (const float*)d_in[10];
    const float* eproj_b = (const float*)d_in[11];
    const float* agg_w   = (const float*)d_in[12];
    const float* agg_b   = (const float*)d_in[13];
    const float* att_w   = (const float*)d_in[14];
    const float* att_b   = (const float*)d_in[15];

    float* ws = (float*)d_ws;
    size_t o = 0;
    float* xn     = ws + o; o += 2560000;   // live proj -> aggklin
    float* GU     = ws + o; o += 5120000;   // G (bf16, sy->aggregate) ∪ outsB (bf16)
    float* YiBf   = ws + o; o += 2560000;   // Yi bf16
    float* aggrBf = ws + o; o += 2560000;   // bf16 aggr
    float* pwqf   = ws + o; o += 2 * 8 * EP_;      // 1,310,720 (uint2 CSR entries)
    float* asrc   = ws + o; o += 40000;
    float* adst   = ws + o; o += 40000;
    float* v1     = ws + o; o += 512;
    float* bias_i = ws + o; o += 512;
    float* attn   = ws + o; o += 16;
    // zeroed-by-setup region (contiguous ints): count, cursor, colsum, done
    int*   count  = (int*)(ws + o); o += 40000;
    int*   cursor = (int*)(ws + o); o += 40000;
    float* colsum = ws + o; o += 1024;
    int*   done   = (int*)(ws + o); o += 4;
    int*   offs   = (int*)(ws + o); o += 40008;
    unsigned short* wph = (unsigned short*)(ws + o); o += 163840;
    unsigned short* wpl = (unsigned short*)(ws + o); o += 163840;
    unsigned short* lph = (unsigned short*)(ws + o); o += 1024;
    unsigned short* lpl = (unsigned short*)(ws + o); o += 1024;
    // total ≈ 14.7M floats ≈ 59 MB

    unsigned short* G     = (unsigned short*)GU;
    unsigned short* outsB = (unsigned short*)GU;
    unsigned short* YiB   = (unsigned short*)YiBf;
    unsigned short* aggrB = (unsigned short*)aggrBf;
    unsigned int*   pwq   = (unsigned int*)pwqf;

    setup_kernel<<<dim3(243), 256, 0, stream>>>(proj_w, att_w, agg_w, klin_w,
                                                lin_src, lin_dst, eproj_w, eproj_b,
                                                att_b, wph, wpl, lph, lpl,
                                                v1, bias_i, count);
    cp_kernel<<<dim3(2208), 256, 0, stream>>>(eidx, count, x, wph, wpl, proj_b,
                                              lin_src, lin_dst, xn, asrc, adst);
    scan_kernel<<<dim3(B_ * T_), 256, 0, stream>>>(count, offs, pwq);
    sy_kernel<<<dim3(3328), 256, 0, stream>>>(eidx, ew, asrc, adst, offs, cursor,
                                              pwq, xn, wph, wpl, bias_i, G, YiB);
    aggregate_kernel<<<dim3(10000), 256, 0, stream>>>(G, YiB, v1, pwq, offs, aggrB);
    aggklin_kernel<<<dim3(AGGK_BLOCKS), 256, 0, stream>>>(aggrB, xn, wph, wpl, agg_b,
                                                          klin_b, q, outsB, colsum,
                                                          done, attn);
    output_kernel<<<dim3(2500), 256, 0, stream>>>(outsB, attn, (float*)d_out);
}

// Round 11
// 272.623 us; speedup vs baseline: 1.9132x; 1.0341x over previous
//
#include <hip/hip_runtime.h>
#include <math.h>

// Problem constants (from reference setup_inputs)
#define B_    2
#define N_    5000
#define C_    128
#define E_    65536
#define T_    4
#define TWO_N 10000
#define EP_   81920   // padded CSR capacity per (et,b)

// edge types: (src,dst) node types = (0,0),(1,1),(0,1),(1,0)
// s_t = et & 1 ; d_t = ((et+1)>>1) & 1
// XCD-pin convention: pair be = b*4+et == blockIdx.x & 7 for every kernel
// touching per-pair edge data (count, scatter, yji, aggregate, aggklin).
// CSR entry (8 B): uint2 { p fp32 ; (q_bf16 << 16) | src_u16 }
// xn is kept ONLY as bf16 (xnB): all consumers (yji GEMMs, aggklin W2, G.xs)
// quantize to bf16 anyway; nodedot is fused on the fp32 accumulators in cp.

__device__ __forceinline__ unsigned short f2bf(float f) {
    unsigned u = __float_as_uint(f);
    u += 0x7fffu + ((u >> 16) & 1u);   // RNE
    return (unsigned short)(u >> 16);
}
__device__ __forceinline__ float bf2f(unsigned short h) {
    return __uint_as_float(((unsigned)h) << 16);
}

typedef __attribute__((ext_vector_type(8))) short bfrag;   // 8 bf16
typedef __attribute__((ext_vector_type(4))) float ffrag;   // 4 fp32 acc

__device__ __forceinline__ void split8(const float* __restrict__ p, bfrag& hi, bfrag& lo) {
#pragma unroll
    for (int j = 0; j < 8; ++j) {
        float v = p[j];
        unsigned short h = f2bf(v);
        hi[j] = (short)h;
        lo[j] = (short)f2bf(v - bf2f(h));
    }
}

// Weight slots (each 128x128, B-fragment packed):
// 0-1: proj ; 2-5: Wj[et] ; 6-9: Wi[et] ; 10-13: W1[et] ; 14-17: W2[et] ; 18-19: klin[nt]
#define SLOT(i) ((size_t)(i) * 16384)

__device__ __forceinline__ void zero_acc(ffrag (&acc)[2][8]) {
#pragma unroll
    for (int h = 0; h < 2; ++h)
#pragma unroll
        for (int t = 0; t < 8; ++t) acc[h][t] = (ffrag){0.f, 0.f, 0.f, 0.f};
}

// Split-bf16 MFMA GEMM core, K=128, 4 waves x 32 rows, N=128. fp32 A (cp only).
__device__ __forceinline__ void mfma128(const float* __restrict__ A,
                                        const unsigned short* __restrict__ Whi,
                                        const unsigned short* __restrict__ Wlo,
                                        ffrag (&acc)[2][8], int bx)
{
    const int wave = threadIdx.x >> 6, lane = threadIdx.x & 63;
    const int mloc = lane & 15, quad = lane >> 4;
    const int row0w = bx * 128 + wave * 32;
    int r0 = row0w + mloc;      if (r0 >= N_) r0 = N_ - 1;  // clamp, stores guarded
    int r1 = row0w + 16 + mloc; if (r1 >= N_) r1 = N_ - 1;
#pragma unroll
    for (int s = 0; s < 4; ++s) {
        bfrag a0h, a0l, a1h, a1l;
        split8(A + (size_t)r0 * C_ + s * 32 + quad * 8, a0h, a0l);
        split8(A + (size_t)r1 * C_ + s * 32 + quad * 8, a1h, a1l);
        const unsigned short* pBh = Whi + ((size_t)s * 512 + lane) * 8;
        const unsigned short* pBl = Wlo + ((size_t)s * 512 + lane) * 8;
#pragma unroll
        for (int t = 0; t < 8; ++t) {
            bfrag bh = *(const bfrag*)(pBh + (size_t)t * 512);
            bfrag bl = *(const bfrag*)(pBl + (size_t)t * 512);
            acc[0][t] = __builtin_amdgcn_mfma_f32_16x16x32_bf16(a0h, bh, acc[0][t], 0, 0, 0);
            acc[0][t] = __builtin_amdgcn_mfma_f32_16x16x32_bf16(a0l, bh, acc[0][t], 0, 0, 0);
            acc[0][t] = __builtin_amdgcn_mfma_f32_16x16x32_bf16(a0h, bl, acc[0][t], 0, 0, 0);
            acc[1][t] = __builtin_amdgcn_mfma_f32_16x16x32_bf16(a1h, bh, acc[1][t], 0, 0, 0);
            acc[1][t] = __builtin_amdgcn_mfma_f32_16x16x32_bf16(a1l, bh, acc[1][t], 0, 0, 0);
            acc[1][t] = __builtin_amdgcn_mfma_f32_16x16x32_bf16(a1h, bl, acc[1][t], 0, 0, 0);
        }
    }
}

// bf16-A half-width core: 4 of 8 n-tiles (cols [half*64, half*64+64)).
__device__ __forceinline__ void mfma128_half_bfA(const unsigned short* __restrict__ A,
                                                 const unsigned short* __restrict__ Whi,
                                                 const unsigned short* __restrict__ Wlo,
                                                 ffrag (&acc)[2][4], int bx, int half)
{
    const int wave = threadIdx.x >> 6, lane = threadIdx.x & 63;
    const int mloc = lane & 15, quad = lane >> 4;
    const int row0w = bx * 128 + wave * 32;
    int r0 = row0w + mloc;      if (r0 >= N_) r0 = N_ - 1;
    int r1 = row0w + 16 + mloc; if (r1 >= N_) r1 = N_ - 1;
#pragma unroll
    for (int s = 0; s < 4; ++s) {
        bfrag a0 = *(const bfrag*)(A + (size_t)r0 * C_ + s * 32 + quad * 8);
        bfrag a1 = *(const bfrag*)(A + (size_t)r1 * C_ + s * 32 + quad * 8);
        const unsigned short* pBh = Whi + ((size_t)s * 512 + (size_t)half * 256 + lane) * 8;
        const unsigned short* pBl = Wlo + ((size_t)s * 512 + (size_t)half * 256 + lane) * 8;
#pragma unroll
        for (int t = 0; t < 4; ++t) {
            bfrag bh = *(const bfrag*)(pBh + (size_t)t * 512);
            bfrag bl = *(const bfrag*)(pBl + (size_t)t * 512);
            acc[0][t] = __builtin_amdgcn_mfma_f32_16x16x32_bf16(a0, bh, acc[0][t], 0, 0, 0);
            acc[0][t] = __builtin_amdgcn_mfma_f32_16x16x32_bf16(a0, bl, acc[0][t], 0, 0, 0);
            acc[1][t] = __builtin_amdgcn_mfma_f32_16x16x32_bf16(a1, bh, acc[1][t], 0, 0, 0);
            acc[1][t] = __builtin_amdgcn_mfma_f32_16x16x32_bf16(a1, bl, acc[1][t], 0, 0, 0);
        }
    }
}

// M=64 bf16-A core: D = A @ (Wh + Wl).
__device__ __forceinline__ void mfma64_bfA(const unsigned short* __restrict__ A,
                                           const unsigned short* __restrict__ Whi,
                                           const unsigned short* __restrict__ Wlo,
                                           ffrag (&acc)[8], int bx)
{
    const int wave = threadIdx.x >> 6, lane = threadIdx.x & 63;
    const int mloc = lane & 15, quad = lane >> 4;
    int r0 = bx * 64 + wave * 16 + mloc; if (r0 >= N_) r0 = N_ - 1;
#pragma unroll
    for (int s = 0; s < 4; ++s) {
        bfrag a0 = *(const bfrag*)(A + (size_t)r0 * C_ + s * 32 + quad * 8);
        const unsigned short* pBh = Whi + ((size_t)s * 512 + lane) * 8;
        const unsigned short* pBl = Wlo + ((size_t)s * 512 + lane) * 8;
#pragma unroll
        for (int t = 0; t < 8; ++t) {
            bfrag bh = *(const bfrag*)(pBh + (size_t)t * 512);
            bfrag bl = *(const bfrag*)(pBl + (size_t)t * 512);
            acc[t] = __builtin_amdgcn_mfma_f32_16x16x32_bf16(a0, bh, acc[t], 0, 0, 0);
            acc[t] = __builtin_amdgcn_mfma_f32_16x16x32_bf16(a0, bl, acc[t], 0, 0, 0);
        }
    }
}

#define ZN_ 81028   // count(40000) + cursor(40000) + colsum(1024) + done(4)

// setup: blocks [0,160) pack_w ; [160] pack_L ; [161,163) prep ; [163,243) zero
__global__ __launch_bounds__(256) void setup_kernel(
    const float* __restrict__ proj_w, const float* __restrict__ att_w,
    const float* __restrict__ agg_w, const float* __restrict__ klin_w,
    const float* __restrict__ lin_src, const float* __restrict__ lin_dst,
    const float* __restrict__ eproj_w, const float* __restrict__ eproj_b,
    const float* __restrict__ att_b,
    unsigned short* __restrict__ wh, unsigned short* __restrict__ wl,
    unsigned short* __restrict__ lph, unsigned short* __restrict__ lpl,
    float* __restrict__ v1, float* __restrict__ bias_i, int* __restrict__ zbase)
{
    int blk = blockIdx.x;
    if (blk < 160) {
        int wave = threadIdx.x >> 6, lane = threadIdx.x & 63;
        int unit = blk * 4 + wave;      // 0..639
        int id = unit >> 5;             // slot 0..19
        int st = unit & 31;
        int s = st >> 3, t = st & 7;
        const float* src;
        if (id < 2)       src = proj_w + (size_t)id * 16384;
        else if (id < 6)  src = att_w + (size_t)(id - 2) * 384 * C_;
        else if (id < 10) src = att_w + (size_t)(id - 6) * 384 * C_ + (size_t)128 * C_;
        else if (id < 14) src = agg_w + (size_t)(id - 10) * 256 * C_;
        else if (id < 18) src = agg_w + (size_t)(id - 14) * 256 * C_ + (size_t)128 * C_;
        else              src = klin_w + (size_t)(id - 18) * 16384;
        int mloc = lane & 15, quad = lane >> 4;
        size_t dbase = SLOT(id) + ((size_t)(s * 8 + t) * 64 + lane) * 8;
#pragma unroll
        for (int j = 0; j < 8; ++j) {
            float v = src[(size_t)(s * 32 + quad * 8 + j) * C_ + t * 16 + mloc];
            unsigned short h = f2bf(v);
            wh[dbase + j] = h;
            wl[dbase + j] = f2bf(v - bf2f(h));
        }
    } else if (blk == 160) {
        int s = threadIdx.x >> 6;       // wave = s (0..3)
        int lane = threadIdx.x & 63;
        int mloc = lane & 15, quad = lane >> 4;
        const float* vec = nullptr;
        if (mloc < 8) {
            int nt = mloc >> 2, idx = mloc & 3;
            if (idx == 0)      vec = lin_src + nt * C_;
            else if (idx == 1) vec = lin_src + (nt + 2) * C_;
            else if (idx == 2) vec = lin_dst + nt * C_;
            else               vec = lin_dst + (3 - nt) * C_;
        }
        size_t dbase = ((size_t)(s * 64) + lane) * 8;
#pragma unroll
        for (int j = 0; j < 8; ++j) {
            float v = vec ? vec[s * 32 + quad * 8 + j] : 0.f;
            unsigned short h = f2bf(v);
            lph[dbase + j] = h;
            lpl[dbase + j] = f2bf(v - bf2f(h));
        }
    } else if (blk < 163) {
        int et = (blk - 161) * 2 + (threadIdx.x >> 7);
        int c = threadIdx.x & 127;
        float s1 = 0.f, s0 = 0.f;
        for (int k = 0; k < 128; ++k) {
            float wv = att_w[(size_t)et * 384 * C_ + (size_t)(256 + k) * C_ + c];
            s1 = fmaf(eproj_w[et * C_ + k], wv, s1);
            s0 = fmaf(eproj_b[et * C_ + k], wv, s0);
        }
        v1[et * C_ + c] = s1;
        bias_i[et * C_ + c] = att_b[et * C_ + c] + s0;
    } else {
        int base = (blk - 163) * 1024 + threadIdx.x * 4;
#pragma unroll
        for (int j = 0; j < 4; ++j)
            if (base + j < ZN_) zbase[base + j] = 0;
    }
}

// count + proj(+nodedot) hybrid: blocks [0,512) count (XCD-pinned, 4 edges/thr) ;
// [512,672) proj (emits xnB bf16 + fused nodedot on fp32 accumulators)
__global__ __launch_bounds__(256) void cp_kernel(
    const int* __restrict__ eidx, int* __restrict__ count,
    const float* __restrict__ x,
    const unsigned short* __restrict__ wph, const unsigned short* __restrict__ wpl,
    const float* __restrict__ proj_b,
    const float* __restrict__ lin_src, const float* __restrict__ lin_dst,
    unsigned short* __restrict__ xnB, float* __restrict__ asrc, float* __restrict__ adst)
{
    int blk = blockIdx.x;
    if (blk < 512) {
        int be = blk & 7;             // XCD-pin: pair = b*4+et
        int et = be & 3, b = be >> 2;
        int t4 = (blk >> 3) * 256 + threadIdx.x;   // 0..16383
        size_t ebase = ((size_t)et * B_ + b) * 2 * E_;
        int4 d4 = *(const int4*)(eidx + ebase + E_ + 4 * t4);
        int* cp = count + (size_t)be * N_;
        atomicAdd(&cp[d4.x], 1);
        atomicAdd(&cp[d4.y], 1);
        atomicAdd(&cp[d4.z], 1);
        atomicAdd(&cp[d4.w], 1);
        return;
    }
    int pidx = blk - 512;             // 0..159
    int bx = pidx % 40;
    int nt = (pidx / 40) & 1;
    int b = pidx / 80;
    const float* A = x + ((size_t)b * TWO_N + (size_t)nt * N_) * C_;
    ffrag acc[2][8];
    zero_acc(acc);
    mfma128(A, wph + SLOT(nt), wpl + SLOT(nt), acc, bx);
    unsigned short* out = xnB + (size_t)(b * 2 + nt) * N_ * C_;
    const float* bias = proj_b + nt * C_;
    const int wave = threadIdx.x >> 6, lane = threadIdx.x & 63;
    const int mloc = lane & 15, quad = lane >> 4;
    const int rbase = bx * 128 + wave * 32 + quad * 4;
    // lin columns for the fused nodedot
    const float* lv0 = lin_src + nt * C_;
    const float* lv1 = lin_src + (2 + nt) * C_;
    const float* lv2 = lin_dst + nt * C_;
    const float* lv3 = lin_dst + (3 - nt) * C_;
    float linv[4][8];
#pragma unroll
    for (int t = 0; t < 8; ++t) {
        int col = t * 16 + mloc;
        linv[0][t] = lv0[col]; linv[1][t] = lv1[col];
        linv[2][t] = lv2[col]; linv[3][t] = lv3[col];
    }
    const int et0 = nt, et1 = 2 + nt, et2 = nt, et3 = 3 - nt;
#pragma unroll
    for (int h = 0; h < 2; ++h)
#pragma unroll
        for (int r = 0; r < 4; ++r) {
            int row = rbase + h * 16 + r;
            bool ok = (row < N_);
            float p0 = 0.f, p1 = 0.f, p2 = 0.f, p3 = 0.f;
#pragma unroll
            for (int t = 0; t < 8; ++t) {
                int col = t * 16 + mloc;
                float vv = acc[h][t][r] + bias[col];
                if (ok) out[(size_t)row * C_ + col] = f2bf(vv);
                p0 = fmaf(vv, linv[0][t], p0);
                p1 = fmaf(vv, linv[1][t], p1);
                p2 = fmaf(vv, linv[2][t], p2);
                p3 = fmaf(vv, linv[3][t], p3);
            }
#pragma unroll
            for (int m = 1; m < 16; m <<= 1) {
                p0 += __shfl_xor(p0, m);
                p1 += __shfl_xor(p1, m);
                p2 += __shfl_xor(p2, m);
                p3 += __shfl_xor(p3, m);
            }
            if (mloc == 0 && ok) {
                asrc[(size_t)(b * T_ + et0) * N_ + row] = p0;
                asrc[(size_t)(b * T_ + et1) * N_ + row] = p1;
                adst[(size_t)(b * T_ + et2) * N_ + row] = p2;
                adst[(size_t)(b * T_ + et3) * N_ + row] = p3;
            }
        }
}

// Exclusive scan of 4-aligned strides -> CSR offsets; zero pad slots.
__global__ __launch_bounds__(256) void scan_kernel(const int* __restrict__ count,
                                                   int* __restrict__ offs,
                                                   unsigned int* __restrict__ pwq)
{
    int be = blockIdx.x;
    const int* cnt = count + (size_t)be * N_;
    int* off = offs + (size_t)be * (N_ + 1);
    __shared__ int sums[256];
    int tid = threadIdx.x;
    const int chunk = (N_ + 255) / 256;  // 20
    int lo = tid * chunk, hi = min(lo + chunk, N_);
    int s = 0;
    for (int i = lo; i < hi; ++i) s += (cnt[i] + 3) & ~3;
    sums[tid] = s;
    __syncthreads();
    for (int d = 1; d < 256; d <<= 1) {
        int v = (tid >= d) ? sums[tid - d] : 0;
        __syncthreads();
        sums[tid] += v;
        __syncthreads();
    }
    int run = (tid > 0) ? sums[tid - 1] : 0;
    uint2* ep = (uint2*)pwq;
    for (int i = lo; i < hi; ++i) {
        off[i] = run;
        int c = cnt[i], pc = (c + 3) & ~3;
        for (int k = c; k < pc; ++k)
            ep[(size_t)be * EP_ + run + k] = make_uint2(0u, 0u);
        run += pc;
    }
    if (tid == 255) off[N_] = sums[255];
}

// scatter + yji hybrid: blocks [0,512) scatter (4 edges/thr) ; [512,1792) yji —
// both XCD-pinned by pair (blk & 7 == be).
// yji roles: 0 -> G = interleaved bf16 {Z=xs*(xs@Wj), xs} ; 1 -> Yi (bf16);
// each role split into col-halves (64 cols/block).
__global__ __launch_bounds__(256) void sy_kernel(
    const int* __restrict__ eidx, const float* __restrict__ ew,
    const float* __restrict__ asrc, const float* __restrict__ adst,
    const int* __restrict__ offs, int* __restrict__ cursor,
    unsigned int* __restrict__ pwq,
    const unsigned short* __restrict__ xnB,
    const unsigned short* __restrict__ wph, const unsigned short* __restrict__ wpl,
    const float* __restrict__ bias_i,
    unsigned short* __restrict__ G, unsigned short* __restrict__ YiB)
{
    int blk = blockIdx.x;
    if (blk < 512) {
        int be = blk & 7;             // XCD-pin
        int et = be & 3, b = be >> 2;
        int t4 = (blk >> 3) * 256 + threadIdx.x;   // 0..16383
        size_t ebase = ((size_t)et * B_ + b) * 2 * E_;
        int4 s4 = *(const int4*)(eidx + ebase + 4 * t4);
        int4 d4 = *(const int4*)(eidx + ebase + E_ + 4 * t4);
        float4 w4 = *(const float4*)(ew + ((size_t)et * B_ + b) * E_ + 4 * t4);
        const float* ap = asrc + (size_t)be * N_;
        const float* dp = adst + (size_t)be * N_;
        const int* op = offs + (size_t)be * (N_ + 1);
        int* cp = cursor + (size_t)be * N_;
        uint2* epb = (uint2*)pwq + (size_t)be * EP_;
#pragma unroll
        for (int j = 0; j < 4; ++j) {
            int src = (j == 0) ? s4.x : (j == 1) ? s4.y : (j == 2) ? s4.z : s4.w;
            int dst = (j == 0) ? d4.x : (j == 1) ? d4.y : (j == 2) ? d4.z : d4.w;
            float w = (j == 0) ? w4.x : (j == 1) ? w4.y : (j == 2) ? w4.z : w4.w;
            float al = ap[src] + dp[dst];
            al = (al > 0.f) ? al : 0.2f * al;
            float p = __expf(al);
            int pos = op[dst] + atomicAdd(&cp[dst], 1);
            unsigned int packed = (unsigned int)src | ((unsigned int)f2bf(p * w) << 16);
            epb[pos] = make_uint2(__float_as_uint(p), packed);
        }
        return;
    }
    int yidx = blk - 512;             // 0..1279 ; 512 % 8 == 0 keeps pin aligned
    int be = yidx & 7;                // XCD-pin
    int et = be & 3, b = be >> 2;
    int rest = yidx >> 3;             // 0..159
    int half = rest & 1;
    int role = (rest >> 1) & 1;
    int bx = rest >> 2;               // 0..39
    int s_t = et & 1, d_t = ((et + 1) >> 1) & 1;
    int ntsel = (role == 0) ? s_t : d_t;
    const unsigned short* A = xnB + (size_t)(b * 2 + ntsel) * N_ * C_;
    int slot = (role == 0) ? 2 + et : 6 + et;
    ffrag acc[2][4];
#pragma unroll
    for (int h = 0; h < 2; ++h)
#pragma unroll
        for (int t = 0; t < 4; ++t) acc[h][t] = (ffrag){0.f, 0.f, 0.f, 0.f};
    mfma128_half_bfA(A, wph + SLOT(slot), wpl + SLOT(slot), acc, bx, half);
    const float* bias = bias_i + et * C_;
    const int wave = threadIdx.x >> 6, lane = threadIdx.x & 63;
    const int mloc = lane & 15, quad = lane >> 4;
    const int rbase = bx * 128 + wave * 32 + quad * 4;
#pragma unroll
    for (int h = 0; h < 2; ++h)
#pragma unroll
        for (int r = 0; r < 4; ++r) {
            int row = rbase + h * 16 + r;
            if (row >= N_) continue;
#pragma unroll
            for (int t = 0; t < 4; ++t) {
                int col = (half * 4 + t) * 16 + mloc;
                float v = acc[h][t][r];
                if (role == 0) {
                    float xv = bf2f(A[(size_t)row * C_ + col]);
                    *(ushort2*)(G + ((size_t)be * N_ + row) * 256 + 2 * col) =
                        make_ushort2(f2bf(v * xv), f2bf(xv));
                } else {
                    YiB[((size_t)be * N_ + row) * C_ + col] = f2bf(v + bias[col]);
                }
            }
        }
}

// Segment-softmax aggregation, one wave per (node, et, b), XCD-pinned by pair.
// aggr = (Σ p·Z[s] + Yi'⊙Σ p·xs + v1⊙Σ q·xs) / Σ p, emitted as bf16.
__global__ __launch_bounds__(256) void aggregate_kernel(
    const unsigned short* __restrict__ G, const unsigned short* __restrict__ YiB,
    const float* __restrict__ v1, const unsigned int* __restrict__ pwq,
    const int* __restrict__ offs, unsigned short* __restrict__ aggrB)
{
    int pair = blockIdx.x & 7;                       // = b*T_+et (XCD-pin)
    int n = (blockIdx.x >> 3) * 4 + (threadIdx.x >> 6);
    int et = pair & 3;
    int be = pair;
    int l = threadIdx.x & 63;
    const unsigned short* Gp = G + (size_t)be * N_ * 256;
    int beg = offs[(size_t)be * (N_ + 1) + n];
    int end = offs[(size_t)be * (N_ + 1) + n + 1];
    const unsigned int* ep = pwq + ((size_t)be * EP_ + beg) * 2;
    float a1x = 0.f, a1y = 0.f, a2x = 0.f, a2y = 0.f, a3x = 0.f, a3y = 0.f, denom = 0.f;
    int cnt = end - beg;  // multiple of 4; pads have p=q=0, src=0
    for (int i = 0; i < cnt; i += 4) {
        uint4 u01 = *(const uint4*)(ep + 2 * i);      // entries i, i+1
        uint4 u23 = *(const uint4*)(ep + 2 * i + 4);  // entries i+2, i+3
        float p0 = __uint_as_float(u01.x), q0 = bf2f((unsigned short)(u01.y >> 16));
        float p1 = __uint_as_float(u01.z), q1 = bf2f((unsigned short)(u01.w >> 16));
        float p2 = __uint_as_float(u23.x), q2 = bf2f((unsigned short)(u23.y >> 16));
        float p3 = __uint_as_float(u23.z), q3 = bf2f((unsigned short)(u23.w >> 16));
        int s0 = u01.y & 0xffff, s1 = u01.w & 0xffff;
        int s2 = u23.y & 0xffff, s3 = u23.w & 0xffff;
        ushort4 g0 = *(const ushort4*)(Gp + (size_t)s0 * 256 + 4 * l);
        ushort4 g1 = *(const ushort4*)(Gp + (size_t)s1 * 256 + 4 * l);
        ushort4 g2 = *(const ushort4*)(Gp + (size_t)s2 * 256 + 4 * l);
        ushort4 g3 = *(const ushort4*)(Gp + (size_t)s3 * 256 + 4 * l);
        denom += p0 + p1 + p2 + p3;
        a1x = fmaf(p0, bf2f(g0.x), a1x); a2x = fmaf(p0, bf2f(g0.y), a2x);
        a3x = fmaf(q0, bf2f(g0.y), a3x);
        a1y = fmaf(p0, bf2f(g0.z), a1y); a2y = fmaf(p0, bf2f(g0.w), a2y);
        a3y = fmaf(q0, bf2f(g0.w), a3y);
        a1x = fmaf(p1, bf2f(g1.x), a1x); a2x = fmaf(p1, bf2f(g1.y), a2x);
        a3x = fmaf(q1, bf2f(g1.y), a3x);
        a1y = fmaf(p1, bf2f(g1.z), a1y); a2y = fmaf(p1, bf2f(g1.w), a2y);
        a3y = fmaf(q1, bf2f(g1.w), a3y);
        a1x = fmaf(p2, bf2f(g2.x), a1x); a2x = fmaf(p2, bf2f(g2.y), a2x);
        a3x = fmaf(q2, bf2f(g2.y), a3x);
        a1y = fmaf(p2, bf2f(g2.z), a1y); a2y = fmaf(p2, bf2f(g2.w), a2y);
        a3y = fmaf(q2, bf2f(g2.w), a3y);
        a1x = fmaf(p3, bf2f(g3.x), a1x); a2x = fmaf(p3, bf2f(g3.y), a2x);
        a3x = fmaf(q3, bf2f(g3.y), a3x);
        a1y = fmaf(p3, bf2f(g3.z), a1y); a2y = fmaf(p3, bf2f(g3.w), a2y);
        a3y = fmaf(q3, bf2f(g3.w), a3y);
    }
    ushort2 yiu = *(const ushort2*)(YiB + ((size_t)be * N_ + n) * C_ + 2 * l);
    float2 vv = *(const float2*)(v1 + et * C_ + 2 * l);
    float inv = (denom > 0.f) ? 1.f / denom : 0.f;
    float ox = (a1x + bf2f(yiu.x) * a2x + vv.x * a3x) * inv;
    float oy = (a1y + bf2f(yiu.y) * a2y + vv.y * a3y) * inv;
    *(ushort2*)(aggrB + ((size_t)be * N_ + n) * C_ + 2 * l) = make_ushort2(f2bf(ox), f2bf(oy));
}

#define AGGK_BLOCKS 640

// Fused (M=64 tiles): outs = tanh(relu(aggr@W1 + xnB[d_t]@W2 + agg_b)) -> outsB
// + LDS tile; then klin GEMM on the tile -> colsum; last block -> attn.
__global__ __launch_bounds__(256) void aggklin_kernel(
    const unsigned short* __restrict__ aggrB, const unsigned short* __restrict__ xnB,
    const unsigned short* __restrict__ wph, const unsigned short* __restrict__ wpl,
    const float* __restrict__ agg_b, const float* __restrict__ klin_b,
    const float* __restrict__ q, unsigned short* __restrict__ outsB,
    float* __restrict__ colsum, int* __restrict__ done, float* __restrict__ attn)
{
    int blk = blockIdx.x;
    int be = blk & 7, bx = blk >> 3;   // XCD-pin by pair; bx 0..79 (M=64 tiles)
    int et = be & 3, b = be >> 2;
    int d_t = ((et + 1) >> 1) & 1;
    size_t base = (size_t)be * N_ * C_;
    ffrag acc[8];
#pragma unroll
    for (int t = 0; t < 8; ++t) acc[t] = (ffrag){0.f, 0.f, 0.f, 0.f};
    mfma64_bfA(aggrB + base, wph + SLOT(10 + et), wpl + SLOT(10 + et), acc, bx);
    mfma64_bfA(xnB + (size_t)(b * 2 + d_t) * N_ * C_, wph + SLOT(14 + et),
               wpl + SLOT(14 + et), acc, bx);
    __shared__ unsigned short tile[64][136];   // 17.4 KB
    const float* bias = agg_b + et * C_;
    const int wave = threadIdx.x >> 6, lane = threadIdx.x & 63;
    const int mloc = lane & 15, quad = lane >> 4;
#pragma unroll
    for (int r = 0; r < 4; ++r) {
        int lrow = wave * 16 + quad * 4 + r;
        int row = bx * 64 + lrow;
#pragma unroll
        for (int t = 0; t < 8; ++t) {
            int col = t * 16 + mloc;
            float v = acc[t][r] + bias[col];
            v = (v > 0.f) ? tanhf(v) : 0.f;
            unsigned short hv = f2bf(v);
            tile[lrow][col] = hv;
            if (row < N_) outsB[base + (size_t)row * C_ + col] = hv;
        }
    }
    __syncthreads();
    // second GEMM: klin[nt] on the tile (nt == d_t ; tt = et>=2)
    int nt = d_t, tt = (et >= 2) ? 1 : 0;
    ffrag acc2[8];
#pragma unroll
    for (int t = 0; t < 8; ++t) acc2[t] = (ffrag){0.f, 0.f, 0.f, 0.f};
    const unsigned short* Kh = wph + SLOT(18 + nt);
    const unsigned short* Kl = wpl + SLOT(18 + nt);
    int lr = wave * 16 + mloc;
#pragma unroll
    for (int s = 0; s < 4; ++s) {
        bfrag a0 = *(const bfrag*)&tile[lr][s * 32 + quad * 8];
        const unsigned short* pBh = Kh + ((size_t)s * 512 + lane) * 8;
        const unsigned short* pBl = Kl + ((size_t)s * 512 + lane) * 8;
#pragma unroll
        for (int t = 0; t < 8; ++t) {
            bfrag bh = *(const bfrag*)(pBh + (size_t)t * 512);
            bfrag bl = *(const bfrag*)(pBl + (size_t)t * 512);
            acc2[t] = __builtin_amdgcn_mfma_f32_16x16x32_bf16(a0, bh, acc2[t], 0, 0, 0);
            acc2[t] = __builtin_amdgcn_mfma_f32_16x16x32_bf16(a0, bl, acc2[t], 0, 0, 0);
        }
    }
    __shared__ float cs[128];
    if (threadIdx.x < 128) cs[threadIdx.x] = 0.f;
    __syncthreads();
    const int rbase = bx * 64 + wave * 16 + quad * 4;
#pragma unroll
    for (int t = 0; t < 8; ++t) {
        int col = t * 16 + mloc;
        float bv = klin_b[nt * C_ + col];
        float s = 0.f;
#pragma unroll
        for (int r = 0; r < 4; ++r) {
            int row = rbase + r;
            if (row < N_) s += tanhf(acc2[t][r] + bv);
        }
        atomicAdd(&cs[col], s);
    }
    __syncthreads();
    if (threadIdx.x < 128)
        atomicAdd(&colsum[(size_t)((b * 2 + nt) * 2 + tt) * C_ + threadIdx.x], cs[threadIdx.x]);
    // last-block score fusion
    __shared__ int isLast;
    if (threadIdx.x == 0) {
        __threadfence();
        isLast = (atomicAdd(done, 1) == AGGK_BLOCKS - 1) ? 1 : 0;
    }
    __syncthreads();
    if (!isLast) return;
    __shared__ float red[2][2];
    for (int bnt = 0; bnt < 4; ++bnt) {
        int ntl = bnt & 1;
        float v0 = 0.f, v1l = 0.f;
        if (threadIdx.x < 128) {
            int c = threadIdx.x;
            float qc = q[ntl * C_ + c];
            float c0 = atomicAdd(&colsum[(size_t)(bnt * 2 + 0) * C_ + c], 0.f);
            float c1 = atomicAdd(&colsum[(size_t)(bnt * 2 + 1) * C_ + c], 0.f);
            v0 = qc * c0;
            v1l = qc * c1;
        }
#pragma unroll
        for (int m = 32; m > 0; m >>= 1) {
            v0 += __shfl_down(v0, m);
            v1l += __shfl_down(v1l, m);
        }
        if ((threadIdx.x & 63) == 0 && wave < 2) {
            red[wave][0] = v0;
            red[wave][1] = v1l;
        }
        __syncthreads();
        if (threadIdx.x == 0) {
            float s0 = (red[0][0] + red[1][0]) / (float)N_;
            float s1 = (red[0][1] + red[1][1]) / (float)N_;
            float mx = fmaxf(s0, s1);
            float e0 = __expf(s0 - mx), e1 = __expf(s1 - mx);
            float invd = 1.f / (e0 + e1);
            attn[bnt * 2 + 0] = e0 * invd;
            attn[bnt * 2 + 1] = e1 * invd;
        }
        __syncthreads();
    }
}

__global__ void output_kernel(const unsigned short* __restrict__ outsB,
                              const float* __restrict__ attn,
                              float* __restrict__ out)
{
    int idx = blockIdx.x * blockDim.x + threadIdx.x;
    int c4 = idx & 31;
    int row = idx >> 5;
    int b = row / TWO_N;
    int r = row % TWO_N;
    int nt = (r >= N_) ? 1 : 0;
    int n = r - nt * N_;
    int et0 = nt, et1 = 3 - nt;
    float a0 = attn[(b * 2 + nt) * 2 + 0];
    float a1 = attn[(b * 2 + nt) * 2 + 1];
    const ushort4* o0 = (const ushort4*)(outsB + ((size_t)(b * T_ + et0) * N_ + n) * C_);
    const ushort4* o1 = (const ushort4*)(outsB + ((size_t)(b * T_ + et1) * N_ + n) * C_);
    ushort4 u0 = o0[c4], u1 = o1[c4];
    float4 o;
    o.x = a0 * bf2f(u0.x) + a1 * bf2f(u1.x);
    o.y = a0 * bf2f(u0.y) + a1 * bf2f(u1.y);
    o.z = a0 * bf2f(u0.z) + a1 * bf2f(u1.z);
    o.w = a0 * bf2f(u0.w) + a1 * bf2f(u1.w);
    ((float4*)out)[idx] = o;
}

extern "C" void kernel_launch(void* const* d_in, const int* in_sizes, int n_in,
                              void* d_out, int out_size, void* d_ws, size_t ws_size,
                              hipStream_t stream)
{
    const float* x       = (const float*)d_in[0];
    const int*   eidx    = (const int*)d_in[1];
    const float* ew      = (const float*)d_in[2];
    const float* proj_w  = (const float*)d_in[3];
    const float* proj_b  = (const float*)d_in[4];
    const float* q       = (const float*)d_in[5];
    const float* klin_w  = (const float*)d_in[6];
    const float* klin_b  = (const float*)d_in[7];
    const float* lin_src = (const float*)d_in[8];
    const float* lin_dst = (const float*)d_in[9];
    const float* eproj_w = (const float*)d_in[10];
    const float* eproj_b = (const float*)d_in[11];
    const float* agg_w   = (const float*)d_in[12];
    const float* agg_b   = (const float*)d_in[13];
    const float* att_w   = (const float*)d_in[14];
    const float* att_b   = (const float*)d_in[15];

    float* ws = (float*)d_ws;
    size_t o = 0;
    float* xnBf   = ws + o; o += 1280000;   // xn bf16, live proj -> aggklin
    float* GU     = ws + o; o += 5120000;   // G (bf16, sy->aggregate) ∪ outsB (bf16)
    float* YiBf   = ws + o; o += 2560000;   // Yi bf16
    float* aggrBf = ws + o; o += 2560000;   // bf16 aggr
    float* pwqf   = ws + o; o += 2 * 8 * EP_;      // 1,310,720 (uint2 CSR entries)
    float* asrc   = ws + o; o += 40000;
    float* adst   = ws + o; o += 40000;
    float* v1     = ws + o; o += 512;
    float* bias_i = ws + o; o += 512;
    float* attn   = ws + o; o += 16;
    // zeroed-by-setup region (contiguous ints): count, cursor, colsum, done
    int*   count  = (int*)(ws + o); o += 40000;
    int*   cursor = (int*)(ws + o); o += 40000;
    float* colsum = ws + o; o += 1024;
    int*   done   = (int*)(ws + o); o += 4;
    int*   offs   = (int*)(ws + o); o += 40008;
    unsigned short* wph = (unsigned short*)(ws + o); o += 163840;
    unsigned short* wpl = (unsigned short*)(ws + o); o += 163840;
    unsigned short* lph = (unsigned short*)(ws + o); o += 1024;
    unsigned short* lpl = (unsigned short*)(ws + o); o += 1024;
    // total ≈ 13.4M floats ≈ 54 MB

    unsigned short* xnB   = (unsigned short*)xnBf;
    unsigned short* G     = (unsigned short*)GU;
    unsigned short* outsB = (unsigned short*)GU;
    unsigned short* YiB   = (unsigned short*)YiBf;
    unsigned short* aggrB = (unsigned short*)aggrBf;
    unsigned int*   pwq   = (unsigned int*)pwqf;

    setup_kernel<<<dim3(243), 256, 0, stream>>>(proj_w, att_w, agg_w, klin_w,
                                                lin_src, lin_dst, eproj_w, eproj_b,
                                                att_b, wph, wpl, lph, lpl,
                                                v1, bias_i, count);
    cp_kernel<<<dim3(672), 256, 0, stream>>>(eidx, count, x, wph, wpl, proj_b,
                                             lin_src, lin_dst, xnB, asrc, adst);
    scan_kernel<<<dim3(B_ * T_), 256, 0, stream>>>(count, offs, pwq);
    sy_kernel<<<dim3(1792), 256, 0, stream>>>(eidx, ew, asrc, adst, offs, cursor,
                                              pwq, xnB, wph, wpl, bias_i, G, YiB);
    aggregate_kernel<<<dim3(10000), 256, 0, stream>>>(G, YiB, v1, pwq, offs, aggrB);
    aggklin_kernel<<<dim3(AGGK_BLOCKS), 256, 0, stream>>>(aggrB, xnB, wph, wpl, agg_b,
                                                          klin_b, q, outsB, colsum,
                                                          done, attn);
    output_kernel<<<dim3(2500), 256, 0, stream>>>(outsB, attn, (float*)d_out);
}

// Round 12
// 267.266 us; speedup vs baseline: 1.9516x; 1.0200x over previous
//
#include <hip/hip_runtime.h>
#include <math.h>

// Problem constants (from reference setup_inputs)
#define B_    2
#define N_    5000
#define C_    128
#define E_    65536
#define T_    4
#define TWO_N 10000
#define EP_   81920   // padded CSR capacity per (et,b)

// edge types: (src,dst) node types = (0,0),(1,1),(0,1),(1,0)
// s_t = et & 1 ; d_t = ((et+1)>>1) & 1
// XCD-pin convention: pair be = b*4+et == blockIdx.x & 7 for every kernel
// touching per-pair edge data (count, scatter, yji, aggregate, aggklin).
// CSR entry (8 B): uint2 { p fp32 ; (q_bf16 << 16) | src_u16 }
// xn is kept ONLY as bf16 (xnB): all consumers (yji GEMMs, aggklin W2, G.xs)
// quantize to bf16 anyway; nodedot is fused on the fp32 accumulators in cp.

__device__ __forceinline__ unsigned short f2bf(float f) {
    unsigned u = __float_as_uint(f);
    u += 0x7fffu + ((u >> 16) & 1u);   // RNE
    return (unsigned short)(u >> 16);
}
__device__ __forceinline__ float bf2f(unsigned short h) {
    return __uint_as_float(((unsigned)h) << 16);
}
// fast tanh via hw exp: ~6 ops vs ~25 for libm tanhf; error ~1e-6 (<< bf16 ulp)
__device__ __forceinline__ float fast_tanh_pos(float x) {   // x >= 0
    float e = __expf(-2.f * x);
    return __fdividef(1.f - e, 1.f + e);
}
__device__ __forceinline__ float fast_tanh(float x) {
    float a = fabsf(x);
    float e = __expf(-2.f * a);
    float t = __fdividef(1.f - e, 1.f + e);
    return copysignf(t, x);
}

typedef __attribute__((ext_vector_type(8))) short bfrag;   // 8 bf16
typedef __attribute__((ext_vector_type(4))) float ffrag;   // 4 fp32 acc
typedef __attribute__((ext_vector_type(8))) unsigned short us8;  // 16B bf16 chunk

__device__ __forceinline__ void split8(const float* __restrict__ p, bfrag& hi, bfrag& lo) {
#pragma unroll
    for (int j = 0; j < 8; ++j) {
        float v = p[j];
        unsigned short h = f2bf(v);
        hi[j] = (short)h;
        lo[j] = (short)f2bf(v - bf2f(h));
    }
}

// Weight slots (each 128x128, B-fragment packed):
// 0-1: proj ; 2-5: Wj[et] ; 6-9: Wi[et] ; 10-13: W1[et] ; 14-17: W2[et] ; 18-19: klin[nt]
#define SLOT(i) ((size_t)(i) * 16384)

__device__ __forceinline__ void zero_acc(ffrag (&acc)[2][8]) {
#pragma unroll
    for (int h = 0; h < 2; ++h)
#pragma unroll
        for (int t = 0; t < 8; ++t) acc[h][t] = (ffrag){0.f, 0.f, 0.f, 0.f};
}

// Split-bf16 MFMA GEMM core, K=128, 4 waves x 32 rows, N=128. fp32 A (cp only).
__device__ __forceinline__ void mfma128(const float* __restrict__ A,
                                        const unsigned short* __restrict__ Whi,
                                        const unsigned short* __restrict__ Wlo,
                                        ffrag (&acc)[2][8], int bx)
{
    const int wave = threadIdx.x >> 6, lane = threadIdx.x & 63;
    const int mloc = lane & 15, quad = lane >> 4;
    const int row0w = bx * 128 + wave * 32;
    int r0 = row0w + mloc;      if (r0 >= N_) r0 = N_ - 1;  // clamp, stores guarded
    int r1 = row0w + 16 + mloc; if (r1 >= N_) r1 = N_ - 1;
#pragma unroll
    for (int s = 0; s < 4; ++s) {
        bfrag a0h, a0l, a1h, a1l;
        split8(A + (size_t)r0 * C_ + s * 32 + quad * 8, a0h, a0l);
        split8(A + (size_t)r1 * C_ + s * 32 + quad * 8, a1h, a1l);
        const unsigned short* pBh = Whi + ((size_t)s * 512 + lane) * 8;
        const unsigned short* pBl = Wlo + ((size_t)s * 512 + lane) * 8;
#pragma unroll
        for (int t = 0; t < 8; ++t) {
            bfrag bh = *(const bfrag*)(pBh + (size_t)t * 512);
            bfrag bl = *(const bfrag*)(pBl + (size_t)t * 512);
            acc[0][t] = __builtin_amdgcn_mfma_f32_16x16x32_bf16(a0h, bh, acc[0][t], 0, 0, 0);
            acc[0][t] = __builtin_amdgcn_mfma_f32_16x16x32_bf16(a0l, bh, acc[0][t], 0, 0, 0);
            acc[0][t] = __builtin_amdgcn_mfma_f32_16x16x32_bf16(a0h, bl, acc[0][t], 0, 0, 0);
            acc[1][t] = __builtin_amdgcn_mfma_f32_16x16x32_bf16(a1h, bh, acc[1][t], 0, 0, 0);
            acc[1][t] = __builtin_amdgcn_mfma_f32_16x16x32_bf16(a1l, bh, acc[1][t], 0, 0, 0);
            acc[1][t] = __builtin_amdgcn_mfma_f32_16x16x32_bf16(a1h, bl, acc[1][t], 0, 0, 0);
        }
    }
}

// bf16-A half-width core: 4 of 8 n-tiles (cols [half*64, half*64+64)).
__device__ __forceinline__ void mfma128_half_bfA(const unsigned short* __restrict__ A,
                                                 const unsigned short* __restrict__ Whi,
                                                 const unsigned short* __restrict__ Wlo,
                                                 ffrag (&acc)[2][4], int bx, int half)
{
    const int wave = threadIdx.x >> 6, lane = threadIdx.x & 63;
    const int mloc = lane & 15, quad = lane >> 4;
    const int row0w = bx * 128 + wave * 32;
    int r0 = row0w + mloc;      if (r0 >= N_) r0 = N_ - 1;
    int r1 = row0w + 16 + mloc; if (r1 >= N_) r1 = N_ - 1;
#pragma unroll
    for (int s = 0; s < 4; ++s) {
        bfrag a0 = *(const bfrag*)(A + (size_t)r0 * C_ + s * 32 + quad * 8);
        bfrag a1 = *(const bfrag*)(A + (size_t)r1 * C_ + s * 32 + quad * 8);
        const unsigned short* pBh = Whi + ((size_t)s * 512 + (size_t)half * 256 + lane) * 8;
        const unsigned short* pBl = Wlo + ((size_t)s * 512 + (size_t)half * 256 + lane) * 8;
#pragma unroll
        for (int t = 0; t < 4; ++t) {
            bfrag bh = *(const bfrag*)(pBh + (size_t)t * 512);
            bfrag bl = *(const bfrag*)(pBl + (size_t)t * 512);
            acc[0][t] = __builtin_amdgcn_mfma_f32_16x16x32_bf16(a0, bh, acc[0][t], 0, 0, 0);
            acc[0][t] = __builtin_amdgcn_mfma_f32_16x16x32_bf16(a0, bl, acc[0][t], 0, 0, 0);
            acc[1][t] = __builtin_amdgcn_mfma_f32_16x16x32_bf16(a1, bh, acc[1][t], 0, 0, 0);
            acc[1][t] = __builtin_amdgcn_mfma_f32_16x16x32_bf16(a1, bl, acc[1][t], 0, 0, 0);
        }
    }
}

// M=64 bf16-A core: D = A @ (Wh + Wl).
__device__ __forceinline__ void mfma64_bfA(const unsigned short* __restrict__ A,
                                           const unsigned short* __restrict__ Whi,
                                           const unsigned short* __restrict__ Wlo,
                                           ffrag (&acc)[8], int bx)
{
    const int wave = threadIdx.x >> 6, lane = threadIdx.x & 63;
    const int mloc = lane & 15, quad = lane >> 4;
    int r0 = bx * 64 + wave * 16 + mloc; if (r0 >= N_) r0 = N_ - 1;
#pragma unroll
    for (int s = 0; s < 4; ++s) {
        bfrag a0 = *(const bfrag*)(A + (size_t)r0 * C_ + s * 32 + quad * 8);
        const unsigned short* pBh = Whi + ((size_t)s * 512 + lane) * 8;
        const unsigned short* pBl = Wlo + ((size_t)s * 512 + lane) * 8;
#pragma unroll
        for (int t = 0; t < 8; ++t) {
            bfrag bh = *(const bfrag*)(pBh + (size_t)t * 512);
            bfrag bl = *(const bfrag*)(pBl + (size_t)t * 512);
            acc[t] = __builtin_amdgcn_mfma_f32_16x16x32_bf16(a0, bh, acc[t], 0, 0, 0);
            acc[t] = __builtin_amdgcn_mfma_f32_16x16x32_bf16(a0, bl, acc[t], 0, 0, 0);
        }
    }
}

#define ZN_ 81028   // count(40000) + cursor(40000) + colsum(1024) + done(4)

// setup: blocks [0,160) pack_w ; [160] pack_L ; [161,163) prep ; [163,243) zero
__global__ __launch_bounds__(256) void setup_kernel(
    const float* __restrict__ proj_w, const float* __restrict__ att_w,
    const float* __restrict__ agg_w, const float* __restrict__ klin_w,
    const float* __restrict__ lin_src, const float* __restrict__ lin_dst,
    const float* __restrict__ eproj_w, const float* __restrict__ eproj_b,
    const float* __restrict__ att_b,
    unsigned short* __restrict__ wh, unsigned short* __restrict__ wl,
    unsigned short* __restrict__ lph, unsigned short* __restrict__ lpl,
    float* __restrict__ v1, float* __restrict__ bias_i, int* __restrict__ zbase)
{
    int blk = blockIdx.x;
    if (blk < 160) {
        int wave = threadIdx.x >> 6, lane = threadIdx.x & 63;
        int unit = blk * 4 + wave;      // 0..639
        int id = unit >> 5;             // slot 0..19
        int st = unit & 31;
        int s = st >> 3, t = st & 7;
        const float* src;
        if (id < 2)       src = proj_w + (size_t)id * 16384;
        else if (id < 6)  src = att_w + (size_t)(id - 2) * 384 * C_;
        else if (id < 10) src = att_w + (size_t)(id - 6) * 384 * C_ + (size_t)128 * C_;
        else if (id < 14) src = agg_w + (size_t)(id - 10) * 256 * C_;
        else if (id < 18) src = agg_w + (size_t)(id - 14) * 256 * C_ + (size_t)128 * C_;
        else              src = klin_w + (size_t)(id - 18) * 16384;
        int mloc = lane & 15, quad = lane >> 4;
        size_t dbase = SLOT(id) + ((size_t)(s * 8 + t) * 64 + lane) * 8;
#pragma unroll
        for (int j = 0; j < 8; ++j) {
            float v = src[(size_t)(s * 32 + quad * 8 + j) * C_ + t * 16 + mloc];
            unsigned short h = f2bf(v);
            wh[dbase + j] = h;
            wl[dbase + j] = f2bf(v - bf2f(h));
        }
    } else if (blk == 160) {
        int s = threadIdx.x >> 6;       // wave = s (0..3)
        int lane = threadIdx.x & 63;
        int mloc = lane & 15, quad = lane >> 4;
        const float* vec = nullptr;
        if (mloc < 8) {
            int nt = mloc >> 2, idx = mloc & 3;
            if (idx == 0)      vec = lin_src + nt * C_;
            else if (idx == 1) vec = lin_src + (nt + 2) * C_;
            else if (idx == 2) vec = lin_dst + nt * C_;
            else               vec = lin_dst + (3 - nt) * C_;
        }
        size_t dbase = ((size_t)(s * 64) + lane) * 8;
#pragma unroll
        for (int j = 0; j < 8; ++j) {
            float v = vec ? vec[s * 32 + quad * 8 + j] : 0.f;
            unsigned short h = f2bf(v);
            lph[dbase + j] = h;
            lpl[dbase + j] = f2bf(v - bf2f(h));
        }
    } else if (blk < 163) {
        int et = (blk - 161) * 2 + (threadIdx.x >> 7);
        int c = threadIdx.x & 127;
        float s1 = 0.f, s0 = 0.f;
        for (int k = 0; k < 128; ++k) {
            float wv = att_w[(size_t)et * 384 * C_ + (size_t)(256 + k) * C_ + c];
            s1 = fmaf(eproj_w[et * C_ + k], wv, s1);
            s0 = fmaf(eproj_b[et * C_ + k], wv, s0);
        }
        v1[et * C_ + c] = s1;
        bias_i[et * C_ + c] = att_b[et * C_ + c] + s0;
    } else {
        int base = (blk - 163) * 1024 + threadIdx.x * 4;
#pragma unroll
        for (int j = 0; j < 4; ++j)
            if (base + j < ZN_) zbase[base + j] = 0;
    }
}

// count + proj(+nodedot) hybrid: blocks [0,512) count (XCD-pinned, 4 edges/thr) ;
// [512,672) proj (emits xnB bf16 + fused nodedot on fp32 accumulators)
__global__ __launch_bounds__(256) void cp_kernel(
    const int* __restrict__ eidx, int* __restrict__ count,
    const float* __restrict__ x,
    const unsigned short* __restrict__ wph, const unsigned short* __restrict__ wpl,
    const float* __restrict__ proj_b,
    const float* __restrict__ lin_src, const float* __restrict__ lin_dst,
    unsigned short* __restrict__ xnB, float* __restrict__ asrc, float* __restrict__ adst)
{
    int blk = blockIdx.x;
    if (blk < 512) {
        int be = blk & 7;             // XCD-pin: pair = b*4+et
        int et = be & 3, b = be >> 2;
        int t4 = (blk >> 3) * 256 + threadIdx.x;   // 0..16383
        size_t ebase = ((size_t)et * B_ + b) * 2 * E_;
        int4 d4 = *(const int4*)(eidx + ebase + E_ + 4 * t4);
        int* cp = count + (size_t)be * N_;
        atomicAdd(&cp[d4.x], 1);
        atomicAdd(&cp[d4.y], 1);
        atomicAdd(&cp[d4.z], 1);
        atomicAdd(&cp[d4.w], 1);
        return;
    }
    int pidx = blk - 512;             // 0..159
    int bx = pidx % 40;
    int nt = (pidx / 40) & 1;
    int b = pidx / 80;
    const float* A = x + ((size_t)b * TWO_N + (size_t)nt * N_) * C_;
    ffrag acc[2][8];
    zero_acc(acc);
    mfma128(A, wph + SLOT(nt), wpl + SLOT(nt), acc, bx);
    unsigned short* out = xnB + (size_t)(b * 2 + nt) * N_ * C_;
    const float* bias = proj_b + nt * C_;
    const int wave = threadIdx.x >> 6, lane = threadIdx.x & 63;
    const int mloc = lane & 15, quad = lane >> 4;
    const int rbase = bx * 128 + wave * 32 + quad * 4;
    // lin columns for the fused nodedot
    const float* lv0 = lin_src + nt * C_;
    const float* lv1 = lin_src + (2 + nt) * C_;
    const float* lv2 = lin_dst + nt * C_;
    const float* lv3 = lin_dst + (3 - nt) * C_;
    float linv[4][8];
#pragma unroll
    for (int t = 0; t < 8; ++t) {
        int col = t * 16 + mloc;
        linv[0][t] = lv0[col]; linv[1][t] = lv1[col];
        linv[2][t] = lv2[col]; linv[3][t] = lv3[col];
    }
    const int et0 = nt, et1 = 2 + nt, et2 = nt, et3 = 3 - nt;
#pragma unroll
    for (int h = 0; h < 2; ++h)
#pragma unroll
        for (int r = 0; r < 4; ++r) {
            int row = rbase + h * 16 + r;
            bool ok = (row < N_);
            float p0 = 0.f, p1 = 0.f, p2 = 0.f, p3 = 0.f;
#pragma unroll
            for (int t = 0; t < 8; ++t) {
                int col = t * 16 + mloc;
                float vv = acc[h][t][r] + bias[col];
                if (ok) out[(size_t)row * C_ + col] = f2bf(vv);
                p0 = fmaf(vv, linv[0][t], p0);
                p1 = fmaf(vv, linv[1][t], p1);
                p2 = fmaf(vv, linv[2][t], p2);
                p3 = fmaf(vv, linv[3][t], p3);
            }
#pragma unroll
            for (int m = 1; m < 16; m <<= 1) {
                p0 += __shfl_xor(p0, m);
                p1 += __shfl_xor(p1, m);
                p2 += __shfl_xor(p2, m);
                p3 += __shfl_xor(p3, m);
            }
            if (mloc == 0 && ok) {
                asrc[(size_t)(b * T_ + et0) * N_ + row] = p0;
                asrc[(size_t)(b * T_ + et1) * N_ + row] = p1;
                adst[(size_t)(b * T_ + et2) * N_ + row] = p2;
                adst[(size_t)(b * T_ + et3) * N_ + row] = p3;
            }
        }
}

// Exclusive scan of 4-aligned strides -> CSR offsets; zero pad slots.
__global__ __launch_bounds__(256) void scan_kernel(const int* __restrict__ count,
                                                   int* __restrict__ offs,
                                                   unsigned int* __restrict__ pwq)
{
    int be = blockIdx.x;
    const int* cnt = count + (size_t)be * N_;
    int* off = offs + (size_t)be * (N_ + 1);
    __shared__ int sums[256];
    int tid = threadIdx.x;
    const int chunk = (N_ + 255) / 256;  // 20
    int lo = tid * chunk, hi = min(lo + chunk, N_);
    int s = 0;
    for (int i = lo; i < hi; ++i) s += (cnt[i] + 3) & ~3;
    sums[tid] = s;
    __syncthreads();
    for (int d = 1; d < 256; d <<= 1) {
        int v = (tid >= d) ? sums[tid - d] : 0;
        __syncthreads();
        sums[tid] += v;
        __syncthreads();
    }
    int run = (tid > 0) ? sums[tid - 1] : 0;
    uint2* ep = (uint2*)pwq;
    for (int i = lo; i < hi; ++i) {
        off[i] = run;
        int c = cnt[i], pc = (c + 3) & ~3;
        for (int k = c; k < pc; ++k)
            ep[(size_t)be * EP_ + run + k] = make_uint2(0u, 0u);
        run += pc;
    }
    if (tid == 255) off[N_] = sums[255];
}

// scatter + yji hybrid: blocks [0,512) scatter (4 edges/thr) ; [512,1792) yji —
// both XCD-pinned by pair (blk & 7 == be).
// yji roles: 0 -> G = interleaved bf16 {Z=xs*(xs@Wj), xs} ; 1 -> Yi (bf16);
// each role split into col-halves (64 cols/block).
__global__ __launch_bounds__(256) void sy_kernel(
    const int* __restrict__ eidx, const float* __restrict__ ew,
    const float* __restrict__ asrc, const float* __restrict__ adst,
    const int* __restrict__ offs, int* __restrict__ cursor,
    unsigned int* __restrict__ pwq,
    const unsigned short* __restrict__ xnB,
    const unsigned short* __restrict__ wph, const unsigned short* __restrict__ wpl,
    const float* __restrict__ bias_i,
    unsigned short* __restrict__ G, unsigned short* __restrict__ YiB)
{
    int blk = blockIdx.x;
    if (blk < 512) {
        int be = blk & 7;             // XCD-pin
        int et = be & 3, b = be >> 2;
        int t4 = (blk >> 3) * 256 + threadIdx.x;   // 0..16383
        size_t ebase = ((size_t)et * B_ + b) * 2 * E_;
        int4 s4 = *(const int4*)(eidx + ebase + 4 * t4);
        int4 d4 = *(const int4*)(eidx + ebase + E_ + 4 * t4);
        float4 w4 = *(const float4*)(ew + ((size_t)et * B_ + b) * E_ + 4 * t4);
        const float* ap = asrc + (size_t)be * N_;
        const float* dp = adst + (size_t)be * N_;
        const int* op = offs + (size_t)be * (N_ + 1);
        int* cp = cursor + (size_t)be * N_;
        uint2* epb = (uint2*)pwq + (size_t)be * EP_;
#pragma unroll
        for (int j = 0; j < 4; ++j) {
            int src = (j == 0) ? s4.x : (j == 1) ? s4.y : (j == 2) ? s4.z : s4.w;
            int dst = (j == 0) ? d4.x : (j == 1) ? d4.y : (j == 2) ? d4.z : d4.w;
            float w = (j == 0) ? w4.x : (j == 1) ? w4.y : (j == 2) ? w4.z : w4.w;
            float al = ap[src] + dp[dst];
            al = (al > 0.f) ? al : 0.2f * al;
            float p = __expf(al);
            int pos = op[dst] + atomicAdd(&cp[dst], 1);
            unsigned int packed = (unsigned int)src | ((unsigned int)f2bf(p * w) << 16);
            epb[pos] = make_uint2(__float_as_uint(p), packed);
        }
        return;
    }
    int yidx = blk - 512;             // 0..1279 ; 512 % 8 == 0 keeps pin aligned
    int be = yidx & 7;                // XCD-pin
    int et = be & 3, b = be >> 2;
    int rest = yidx >> 3;             // 0..159
    int half = rest & 1;
    int role = (rest >> 1) & 1;
    int bx = rest >> 2;               // 0..39
    int s_t = et & 1, d_t = ((et + 1) >> 1) & 1;
    int ntsel = (role == 0) ? s_t : d_t;
    const unsigned short* A = xnB + (size_t)(b * 2 + ntsel) * N_ * C_;
    int slot = (role == 0) ? 2 + et : 6 + et;
    ffrag acc[2][4];
#pragma unroll
    for (int h = 0; h < 2; ++h)
#pragma unroll
        for (int t = 0; t < 4; ++t) acc[h][t] = (ffrag){0.f, 0.f, 0.f, 0.f};
    mfma128_half_bfA(A, wph + SLOT(slot), wpl + SLOT(slot), acc, bx, half);
    const float* bias = bias_i + et * C_;
    const int wave = threadIdx.x >> 6, lane = threadIdx.x & 63;
    const int mloc = lane & 15, quad = lane >> 4;
    const int rbase = bx * 128 + wave * 32 + quad * 4;
#pragma unroll
    for (int h = 0; h < 2; ++h)
#pragma unroll
        for (int r = 0; r < 4; ++r) {
            int row = rbase + h * 16 + r;
            if (row >= N_) continue;
#pragma unroll
            for (int t = 0; t < 4; ++t) {
                int col = (half * 4 + t) * 16 + mloc;
                float v = acc[h][t][r];
                if (role == 0) {
                    float xv = bf2f(A[(size_t)row * C_ + col]);
                    *(ushort2*)(G + ((size_t)be * N_ + row) * 256 + 2 * col) =
                        make_ushort2(f2bf(v * xv), f2bf(xv));
                } else {
                    YiB[((size_t)be * N_ + row) * C_ + col] = f2bf(v + bias[col]);
                }
            }
        }
}

// Segment-softmax aggregation, one wave per (node, et, b), XCD-pinned by pair.
// aggr = (Σ p·Z[s] + Yi'⊙Σ p·xs + v1⊙Σ q·xs) / Σ p, emitted as bf16.
__global__ __launch_bounds__(256) void aggregate_kernel(
    const unsigned short* __restrict__ G, const unsigned short* __restrict__ YiB,
    const float* __restrict__ v1, const unsigned int* __restrict__ pwq,
    const int* __restrict__ offs, unsigned short* __restrict__ aggrB)
{
    int pair = blockIdx.x & 7;                       // = b*T_+et (XCD-pin)
    int n = (blockIdx.x >> 3) * 4 + (threadIdx.x >> 6);
    int et = pair & 3;
    int be = pair;
    int l = threadIdx.x & 63;
    const unsigned short* Gp = G + (size_t)be * N_ * 256;
    int beg = offs[(size_t)be * (N_ + 1) + n];
    int end = offs[(size_t)be * (N_ + 1) + n + 1];
    const unsigned int* ep = pwq + ((size_t)be * EP_ + beg) * 2;
    float a1x = 0.f, a1y = 0.f, a2x = 0.f, a2y = 0.f, a3x = 0.f, a3y = 0.f, denom = 0.f;
    int cnt = end - beg;  // multiple of 4; pads have p=q=0, src=0
    for (int i = 0; i < cnt; i += 4) {
        uint4 u01 = *(const uint4*)(ep + 2 * i);      // entries i, i+1
        uint4 u23 = *(const uint4*)(ep + 2 * i + 4);  // entries i+2, i+3
        float p0 = __uint_as_float(u01.x), q0 = bf2f((unsigned short)(u01.y >> 16));
        float p1 = __uint_as_float(u01.z), q1 = bf2f((unsigned short)(u01.w >> 16));
        float p2 = __uint_as_float(u23.x), q2 = bf2f((unsigned short)(u23.y >> 16));
        float p3 = __uint_as_float(u23.z), q3 = bf2f((unsigned short)(u23.w >> 16));
        int s0 = u01.y & 0xffff, s1 = u01.w & 0xffff;
        int s2 = u23.y & 0xffff, s3 = u23.w & 0xffff;
        ushort4 g0 = *(const ushort4*)(Gp + (size_t)s0 * 256 + 4 * l);
        ushort4 g1 = *(const ushort4*)(Gp + (size_t)s1 * 256 + 4 * l);
        ushort4 g2 = *(const ushort4*)(Gp + (size_t)s2 * 256 + 4 * l);
        ushort4 g3 = *(const ushort4*)(Gp + (size_t)s3 * 256 + 4 * l);
        denom += p0 + p1 + p2 + p3;
        a1x = fmaf(p0, bf2f(g0.x), a1x); a2x = fmaf(p0, bf2f(g0.y), a2x);
        a3x = fmaf(q0, bf2f(g0.y), a3x);
        a1y = fmaf(p0, bf2f(g0.z), a1y); a2y = fmaf(p0, bf2f(g0.w), a2y);
        a3y = fmaf(q0, bf2f(g0.w), a3y);
        a1x = fmaf(p1, bf2f(g1.x), a1x); a2x = fmaf(p1, bf2f(g1.y), a2x);
        a3x = fmaf(q1, bf2f(g1.y), a3x);
        a1y = fmaf(p1, bf2f(g1.z), a1y); a2y = fmaf(p1, bf2f(g1.w), a2y);
        a3y = fmaf(q1, bf2f(g1.w), a3y);
        a1x = fmaf(p2, bf2f(g2.x), a1x); a2x = fmaf(p2, bf2f(g2.y), a2x);
        a3x = fmaf(q2, bf2f(g2.y), a3x);
        a1y = fmaf(p2, bf2f(g2.z), a1y); a2y = fmaf(p2, bf2f(g2.w), a2y);
        a3y = fmaf(q2, bf2f(g2.w), a3y);
        a1x = fmaf(p3, bf2f(g3.x), a1x); a2x = fmaf(p3, bf2f(g3.y), a2x);
        a3x = fmaf(q3, bf2f(g3.y), a3x);
        a1y = fmaf(p3, bf2f(g3.z), a1y); a2y = fmaf(p3, bf2f(g3.w), a2y);
        a3y = fmaf(q3, bf2f(g3.w), a3y);
    }
    ushort2 yiu = *(const ushort2*)(YiB + ((size_t)be * N_ + n) * C_ + 2 * l);
    float2 vv = *(const float2*)(v1 + et * C_ + 2 * l);
    float inv = (denom > 0.f) ? 1.f / denom : 0.f;
    float ox = (a1x + bf2f(yiu.x) * a2x + vv.x * a3x) * inv;
    float oy = (a1y + bf2f(yiu.y) * a2y + vv.y * a3y) * inv;
    *(ushort2*)(aggrB + ((size_t)be * N_ + n) * C_ + 2 * l) = make_ushort2(f2bf(ox), f2bf(oy));
}

#define AGGK_BLOCKS 640

// Fused (M=64 tiles): outs = tanh(relu(aggr@W1 + xnB[d_t]@W2 + agg_b)) -> LDS tile
// -> vectorized copy to outsB; then klin GEMM on the tile -> colsum (quad-reduced);
// last block -> attn.
__global__ __launch_bounds__(256) void aggklin_kernel(
    const unsigned short* __restrict__ aggrB, const unsigned short* __restrict__ xnB,
    const unsigned short* __restrict__ wph, const unsigned short* __restrict__ wpl,
    const float* __restrict__ agg_b, const float* __restrict__ klin_b,
    const float* __restrict__ q, unsigned short* __restrict__ outsB,
    float* __restrict__ colsum, int* __restrict__ done, float* __restrict__ attn)
{
    int blk = blockIdx.x;
    int be = blk & 7, bx = blk >> 3;   // XCD-pin by pair; bx 0..79 (M=64 tiles)
    int et = be & 3, b = be >> 2;
    int d_t = ((et + 1) >> 1) & 1;
    size_t base = (size_t)be * N_ * C_;
    ffrag acc[8];
#pragma unroll
    for (int t = 0; t < 8; ++t) acc[t] = (ffrag){0.f, 0.f, 0.f, 0.f};
    mfma64_bfA(aggrB + base, wph + SLOT(10 + et), wpl + SLOT(10 + et), acc, bx);
    mfma64_bfA(xnB + (size_t)(b * 2 + d_t) * N_ * C_, wph + SLOT(14 + et),
               wpl + SLOT(14 + et), acc, bx);
    __shared__ unsigned short tile[64][136];   // 17.4 KB, +8 pad
    const float* bias = agg_b + et * C_;
    const int wave = threadIdx.x >> 6, lane = threadIdx.x & 63;
    const int mloc = lane & 15, quad = lane >> 4;
#pragma unroll
    for (int r = 0; r < 4; ++r) {
        int lrow = wave * 16 + quad * 4 + r;
#pragma unroll
        for (int t = 0; t < 8; ++t) {
            int col = t * 16 + mloc;
            float v = acc[t][r] + bias[col];
            v = (v > 0.f) ? fast_tanh_pos(v) : 0.f;
            tile[lrow][col] = f2bf(v);
        }
    }
    __syncthreads();
    // vectorized tile -> outsB copy (16B coalesced stores)
    {
        int row0 = bx * 64;
#pragma unroll
        for (int it = 0; it < 4; ++it) {
            int chunk = it * 256 + threadIdx.x;       // 0..1023
            int row = chunk >> 4, c8 = (chunk & 15) * 8;
            int grow = row0 + row;
            if (grow < N_)
                *(us8*)(outsB + base + (size_t)grow * C_ + c8) = *(const us8*)&tile[row][c8];
        }
    }
    // second GEMM: klin[nt] on the tile (nt == d_t ; tt = et>=2)
    int nt = d_t, tt = (et >= 2) ? 1 : 0;
    ffrag acc2[8];
#pragma unroll
    for (int t = 0; t < 8; ++t) acc2[t] = (ffrag){0.f, 0.f, 0.f, 0.f};
    const unsigned short* Kh = wph + SLOT(18 + nt);
    const unsigned short* Kl = wpl + SLOT(18 + nt);
    int lr = wave * 16 + mloc;
#pragma unroll
    for (int s = 0; s < 4; ++s) {
        bfrag a0 = *(const bfrag*)&tile[lr][s * 32 + quad * 8];
        const unsigned short* pBh = Kh + ((size_t)s * 512 + lane) * 8;
        const unsigned short* pBl = Kl + ((size_t)s * 512 + lane) * 8;
#pragma unroll
        for (int t = 0; t < 8; ++t) {
            bfrag bh = *(const bfrag*)(pBh + (size_t)t * 512);
            bfrag bl = *(const bfrag*)(pBl + (size_t)t * 512);
            acc2[t] = __builtin_amdgcn_mfma_f32_16x16x32_bf16(a0, bh, acc2[t], 0, 0, 0);
            acc2[t] = __builtin_amdgcn_mfma_f32_16x16x32_bf16(a0, bl, acc2[t], 0, 0, 0);
        }
    }
    __shared__ float cs[128];
    if (threadIdx.x < 128) cs[threadIdx.x] = 0.f;
    __syncthreads();
    const int rbase = bx * 64 + wave * 16 + quad * 4;
#pragma unroll
    for (int t = 0; t < 8; ++t) {
        int col = t * 16 + mloc;
        float bv = klin_b[nt * C_ + col];
        float s = 0.f;
#pragma unroll
        for (int r = 0; r < 4; ++r) {
            int row = rbase + r;
            if (row < N_) s += fast_tanh(acc2[t][r] + bv);
        }
        s += __shfl_xor(s, 16);
        s += __shfl_xor(s, 32);
        if (quad == 0) atomicAdd(&cs[col], s);
    }
    __syncthreads();
    if (threadIdx.x < 128)
        atomicAdd(&colsum[(size_t)((b * 2 + nt) * 2 + tt) * C_ + threadIdx.x], cs[threadIdx.x]);
    // last-block score fusion
    __shared__ int isLast;
    if (threadIdx.x == 0) {
        __threadfence();
        isLast = (atomicAdd(done, 1) == AGGK_BLOCKS - 1) ? 1 : 0;
    }
    __syncthreads();
    if (!isLast) return;
    __shared__ float red[2][2];
    for (int bnt = 0; bnt < 4; ++bnt) {
        int ntl = bnt & 1;
        float v0 = 0.f, v1l = 0.f;
        if (threadIdx.x < 128) {
            int c = threadIdx.x;
            float qc = q[ntl * C_ + c];
            float c0 = atomicAdd(&colsum[(size_t)(bnt * 2 + 0) * C_ + c], 0.f);
            float c1 = atomicAdd(&colsum[(size_t)(bnt * 2 + 1) * C_ + c], 0.f);
            v0 = qc * c0;
            v1l = qc * c1;
        }
#pragma unroll
        for (int m = 32; m > 0; m >>= 1) {
            v0 += __shfl_down(v0, m);
            v1l += __shfl_down(v1l, m);
        }
        if ((threadIdx.x & 63) == 0 && wave < 2) {
            red[wave][0] = v0;
            red[wave][1] = v1l;
        }
        __syncthreads();
        if (threadIdx.x == 0) {
            float s0 = (red[0][0] + red[1][0]) / (float)N_;
            float s1 = (red[0][1] + red[1][1]) / (float)N_;
            float mx = fmaxf(s0, s1);
            float e0 = __expf(s0 - mx), e1 = __expf(s1 - mx);
            float invd = 1.f / (e0 + e1);
            attn[bnt * 2 + 0] = e0 * invd;
            attn[bnt * 2 + 1] = e1 * invd;
        }
        __syncthreads();
    }
}

__global__ void output_kernel(const unsigned short* __restrict__ outsB,
                              const float* __restrict__ attn,
                              float* __restrict__ out)
{
    int idx = blockIdx.x * blockDim.x + threadIdx.x;
    int c4 = idx & 31;
    int row = idx >> 5;
    int b = row / TWO_N;
    int r = row % TWO_N;
    int nt = (r >= N_) ? 1 : 0;
    int n = r - nt * N_;
    int et0 = nt, et1 = 3 - nt;
    float a0 = attn[(b * 2 + nt) * 2 + 0];
    float a1 = attn[(b * 2 + nt) * 2 + 1];
    const ushort4* o0 = (const ushort4*)(outsB + ((size_t)(b * T_ + et0) * N_ + n) * C_);
    const ushort4* o1 = (const ushort4*)(outsB + ((size_t)(b * T_ + et1) * N_ + n) * C_);
    ushort4 u0 = o0[c4], u1 = o1[c4];
    float4 o;
    o.x = a0 * bf2f(u0.x) + a1 * bf2f(u1.x);
    o.y = a0 * bf2f(u0.y) + a1 * bf2f(u1.y);
    o.z = a0 * bf2f(u0.z) + a1 * bf2f(u1.z);
    o.w = a0 * bf2f(u0.w) + a1 * bf2f(u1.w);
    ((float4*)out)[idx] = o;
}

extern "C" void kernel_launch(void* const* d_in, const int* in_sizes, int n_in,
                              void* d_out, int out_size, void* d_ws, size_t ws_size,
                              hipStream_t stream)
{
    const float* x       = (const float*)d_in[0];
    const int*   eidx    = (const int*)d_in[1];
    const float* ew      = (const float*)d_in[2];
    const float* proj_w  = (const float*)d_in[3];
    const float* proj_b  = (const float*)d_in[4];
    const float* q       = (const float*)d_in[5];
    const float* klin_w  = (const float*)d_in[6];
    const float* klin_b  = (const float*)d_in[7];
    const float* lin_src = (const float*)d_in[8];
    const float* lin_dst = (const float*)d_in[9];
    const float* eproj_w = (const float*)d_in[10];
    const float* eproj_b = (const float*)d_in[11];
    const float* agg_w   = (const float*)d_in[12];
    const float* agg_b   = (const float*)d_in[13];
    const float* att_w   = (const float*)d_in[14];
    const float* att_b   = (const float*)d_in[15];

    float* ws = (float*)d_ws;
    size_t o = 0;
    float* xnBf   = ws + o; o += 1280000;   // xn bf16, live proj -> aggklin
    float* GU     = ws + o; o += 5120000;   // G (bf16, sy->aggregate) ∪ outsB (bf16)
    float* YiBf   = ws + o; o += 2560000;   // Yi bf16
    float* aggrBf = ws + o; o += 2560000;   // bf16 aggr
    float* pwqf   = ws + o; o += 2 * 8 * EP_;      // 1,310,720 (uint2 CSR entries)
    float* asrc   = ws + o; o += 40000;
    float* adst   = ws + o; o += 40000;
    float* v1     = ws + o; o += 512;
    float* bias_i = ws + o; o += 512;
    float* attn   = ws + o; o += 16;
    // zeroed-by-setup region (contiguous ints): count, cursor, colsum, done
    int*   count  = (int*)(ws + o); o += 40000;
    int*   cursor = (int*)(ws + o); o += 40000;
    float* colsum = ws + o; o += 1024;
    int*   done   = (int*)(ws + o); o += 4;
    int*   offs   = (int*)(ws + o); o += 40008;
    unsigned short* wph = (unsigned short*)(ws + o); o += 163840;
    unsigned short* wpl = (unsigned short*)(ws + o); o += 163840;
    unsigned short* lph = (unsigned short*)(ws + o); o += 1024;
    unsigned short* lpl = (unsigned short*)(ws + o); o += 1024;
    // total ≈ 13.4M floats ≈ 54 MB

    unsigned short* xnB   = (unsigned short*)xnBf;
    unsigned short* G     = (unsigned short*)GU;
    unsigned short* outsB = (unsigned short*)GU;
    unsigned short* YiB   = (unsigned short*)YiBf;
    unsigned short* aggrB = (unsigned short*)aggrBf;
    unsigned int*   pwq   = (unsigned int*)pwqf;

    setup_kernel<<<dim3(243), 256, 0, stream>>>(proj_w, att_w, agg_w, klin_w,
                                                lin_src, lin_dst, eproj_w, eproj_b,
                                                att_b, wph, wpl, lph, lpl,
                                                v1, bias_i, count);
    cp_kernel<<<dim3(672), 256, 0, stream>>>(eidx, count, x, wph, wpl, proj_b,
                                             lin_src, lin_dst, xnB, asrc, adst);
    scan_kernel<<<dim3(B_ * T_), 256, 0, stream>>>(count, offs, pwq);
    sy_kernel<<<dim3(1792), 256, 0, stream>>>(eidx, ew, asrc, adst, offs, cursor,
                                              pwq, xnB, wph, wpl, bias_i, G, YiB);
    aggregate_kernel<<<dim3(10000), 256, 0, stream>>>(G, YiB, v1, pwq, offs, aggrB);
    aggklin_kernel<<<dim3(AGGK_BLOCKS), 256, 0, stream>>>(aggrB, xnB, wph, wpl, agg_b,
                                                          klin_b, q, outsB, colsum,
                                                          done, attn);
    output_kernel<<<dim3(2500), 256, 0, stream>>>(outsB, attn, (float*)d_out);
}